// Round 1
// baseline (2174.581 us; speedup 1.0000x reference)
//
#include <hip/hip_runtime.h>
#include <math.h>

#define NN 10000
#define EE 160000
#define KK 128
#define GG 16
#define SQ3F 1.7320508075688772f
#define INV_SQ3 0.57735026918962576f
#define INV_AVG 0.0625f
#define RMAXI 0.2f

__device__ __forceinline__ void atomAddF(float* p, float v) { unsafeAtomicAdd(p, v); }

__device__ __forceinline__ float waveRed(float v) {
#pragma unroll
    for (int m = 32; m >= 1; m >>= 1) v += __shfl_xor(v, m);
    return v;
}

// ---------------- edge geometry: r, Y1, ef(bessel*fcut), d(ef)/dr ----------------
__global__ void k_edge_geom(const float* __restrict__ pos, const float* __restrict__ shifts,
                            const int* __restrict__ ei,
                            float* __restrict__ ef, float* __restrict__ defdr,
                            float* __restrict__ Y1, float* __restrict__ rr) {
    int e = blockIdx.x * blockDim.x + threadIdx.x;
    if (e >= EE) return;
    int sn = ei[e], rv = ei[EE + e];
    float vx = pos[rv*3+0] - pos[sn*3+0] + shifts[e*3+0];
    float vy = pos[rv*3+1] - pos[sn*3+1] + shifts[e*3+1];
    float vz = pos[rv*3+2] - pos[sn*3+2] + shifts[e*3+2];
    float r = sqrtf(vx*vx + vy*vy + vz*vz + 1e-12f);
    float ir = 1.0f / r;
    rr[e] = r;
    Y1[e*3+0] = SQ3F*vx*ir; Y1[e*3+1] = SQ3F*vy*ir; Y1[e*3+2] = SQ3F*vz*ir;
    float x = r * RMAXI;
    float fc = 0.f, dfc = 0.f;
    if (x < 1.0f) {
        float x2 = x*x, x4 = x2*x2, x5 = x4*x, x6 = x5*x, x7 = x6*x;
        fc  = 1.0f - 21.0f*x5 + 35.0f*x6 - 15.0f*x7;
        dfc = (-105.0f*x4 + 210.0f*x5 - 105.0f*x6) * RMAXI;
    }
    const float C = 0.63245553203367587f; // sqrt(2/5)
#pragma unroll
    for (int b = 0; b < 8; b++) {
        float kb = (float)(b + 1) * 0.62831853071795865f; // (b+1)*pi/5
        float sb, cb;
        sincosf(kb * r, &sb, &cb);
        float bess  = C * sb * ir;
        float dbess = C * ir * (kb * cb - sb * ir);
        ef[e*8+b]    = bess * fc;
        defdr[e*8+b] = dbess * fc + bess * dfc;
    }
}

// ---------------- node embedding + e0 ----------------
__global__ void k_embed(const int* __restrict__ z, const int* __restrict__ batch,
                        const float* __restrict__ W_embed, const float* __restrict__ ae,
                        float* __restrict__ s, float* __restrict__ out) {
    int i = blockIdx.x * blockDim.x + threadIdx.x;
    if (i >= NN * KK) return;
    int n = i >> 7, d = i & 127;
    int zz = z[n];
    s[i] = W_embed[zz * KK + d];
    if (d == 0) {
        float v = ae[zz];
        int b = batch[n];
        atomAddF(&out[b], v);
        atomAddF(&out[GG + b*3 + 0], v);
    }
}

// ---------------- generic K x K GEMM over rows: out[row,j] (=|+=) alpha * sum_i in[row,i]*Wd(i,j)
// TRANS=0: Wd(i,j)=W[i*K+j];  TRANS=1: Wd(i,j)=W[j*K+i]
// W cached in LDS with rotate-swizzle: WL[i*128 + ((i+j)&127)] -> conflict-free both phases.
template <int TRANS>
__global__ __launch_bounds__(256) void k_gemm(const float* __restrict__ in, const float* __restrict__ W,
                                              float* __restrict__ out, int rows, float alpha, int accum) {
    __shared__ float WL[KK * KK];
    int t = threadIdx.x;
    int lane = t & 127, slot = t >> 7;
    for (int a = slot; a < KK; a += 2) {
        float v = W[a * KK + lane];
        if (!TRANS) WL[a * KK + ((a + lane) & 127)] = v;      // i=a, j=lane
        else        WL[lane * KK + ((lane + a) & 127)] = v;   // j=a, i=lane
    }
    __syncthreads();
    for (int row = blockIdx.x * 2 + slot; row < rows; row += gridDim.x * 2) {
        const float4* inr4 = (const float4*)(in + (size_t)row * KK);
        float acc = 0.f;
#pragma unroll
        for (int i0 = 0; i0 < KK; i0 += 4) {
            float4 v = inr4[i0 >> 2];
            acc += v.x * WL[(i0+0)*KK + ((i0+0+lane)&127)];
            acc += v.y * WL[(i0+1)*KK + ((i0+1+lane)&127)];
            acc += v.z * WL[(i0+2)*KK + ((i0+2+lane)&127)];
            acc += v.w * WL[(i0+3)*KK + ((i0+3+lane)&127)];
        }
        acc *= alpha;
        float* o = out + (size_t)row * KK + lane;
        if (accum) *o += acc; else *o = acc;
    }
}

// ---------------- per-z skip: out[n,d] += sum_c in[n,c]*Wz[z_n][c,d] ----------------
__global__ __launch_bounds__(256) void k_skip_fwd(const float* __restrict__ in, const float* __restrict__ Wall,
                                                  const int* __restrict__ z, float* __restrict__ out) {
    int wv = (blockIdx.x * 256 + threadIdx.x) >> 6;
    int lane = threadIdx.x & 63;
    int nw = gridDim.x * 4;
    for (int n = wv; n < NN; n += nw) {
        const float* Wz = Wall + (size_t)z[n] * (KK * KK);
        const float* inr = in + (size_t)n * KK;
        float a0 = 0.f, a1 = 0.f;
        for (int c = 0; c < KK; c++) {
            float v = inr[c];
            a0 += v * Wz[c * KK + lane];
            a1 += v * Wz[c * KK + 64 + lane];
        }
        out[n * KK + lane] += a0;
        out[n * KK + 64 + lane] += a1;
    }
}

// per-z skip backward: gout[n,c] += sum_d gin[n,d]*Wz[z_n][c,d]
__global__ __launch_bounds__(256) void k_skip_bwd(const float* __restrict__ gin, const float* __restrict__ Wall,
                                                  const int* __restrict__ z, float* __restrict__ gout) {
    int wv = (blockIdx.x * 256 + threadIdx.x) >> 6;
    int lane = threadIdx.x & 63;
    int nw = gridDim.x * 4;
    for (int n = wv; n < NN; n += nw) {
        const float* Wz = Wall + (size_t)z[n] * (KK * KK);
        const float4* g4 = (const float4*)(gin + (size_t)n * KK);
        const float4* w0 = (const float4*)(Wz + lane * KK);
        const float4* w1 = (const float4*)(Wz + (64 + lane) * KK);
        float a0 = 0.f, a1 = 0.f;
#pragma unroll 8
        for (int d0 = 0; d0 < 32; d0++) {
            float4 g = g4[d0];
            float4 u = w0[d0]; a0 += g.x*u.x + g.y*u.y + g.z*u.z + g.w*u.w;
            float4 w = w1[d0]; a1 += g.x*w.x + g.y*w.y + g.z*w.z + g.w*w.w;
        }
        gout[n * KK + lane] += a0;
        gout[n * KK + 64 + lane] += a1;
    }
}

// ---------------- e1 = seg(s1 @ w_r1, batch) ----------------
__global__ __launch_bounds__(256) void k_e1(const float* __restrict__ s1, const float* __restrict__ w_r1,
                                            const int* __restrict__ batch, float* __restrict__ out) {
    int wv = (blockIdx.x * 256 + threadIdx.x) >> 6;
    int lane = threadIdx.x & 63;
    int nw = gridDim.x * 4;
    for (int n = wv; n < NN; n += nw) {
        float a = s1[n*KK + lane] * w_r1[lane] + s1[n*KK + 64 + lane] * w_r1[64 + lane];
        a = waveRed(a);
        if (lane == 0) {
            int b = batch[n];
            atomAddF(&out[b], a);
            atomAddF(&out[GG + b*3 + 1], a);
        }
    }
}

// ---------------- edge pass 1: scatter m0 -> A0, m1 -> A1 (wave per edge) ----------------
__global__ __launch_bounds__(256) void k_edge1(const float* __restrict__ ef, const float* __restrict__ Y1,
                                               const int* __restrict__ ei, const float* __restrict__ R1,
                                               const float* __restrict__ su1,
                                               float* __restrict__ A0, float* __restrict__ A1) {
    __shared__ float RL[2048];
    for (int i = threadIdx.x; i < 2048; i += 256) RL[i] = R1[i];
    __syncthreads();
    int lane = threadIdx.x & 63;
    int wv = (blockIdx.x * 256 + threadIdx.x) >> 6;
    int nw = gridDim.x * 4;
    for (int e = wv; e < EE; e += nw) {
        int sn = ei[e], rv = ei[EE + e];
        float y0 = Y1[e*3+0], y1 = Y1[e*3+1], y2 = Y1[e*3+2];
        float efb[8];
#pragma unroll
        for (int b = 0; b < 8; b++) efb[b] = ef[e*8+b];
        int c0 = lane, c1 = lane + 64;
        float wa0 = 0, wa1 = 0, wb0 = 0, wb1 = 0;
#pragma unroll
        for (int b = 0; b < 8; b++) {
            wa0 += efb[b] * RL[b*256 + c0];       wb0 += efb[b] * RL[b*256 + 128 + c0];
            wa1 += efb[b] * RL[b*256 + c1];       wb1 += efb[b] * RL[b*256 + 128 + c1];
        }
        float sj0 = su1[sn*KK + c0], sj1 = su1[sn*KK + c1];
        float m00 = wa0 * sj0, m01 = wa1 * sj1;
        float mb0 = wb0 * sj0, mb1 = wb1 * sj1;
        float* A0r = A0 + (size_t)rv * KK;
        float* A1r = A1 + (size_t)rv * 384;
        atomAddF(A0r + c0, m00);            atomAddF(A0r + c1, m01);
        atomAddF(A1r + c0, mb0*y0);         atomAddF(A1r + c1, mb1*y0);
        atomAddF(A1r + 128 + c0, mb0*y1);   atomAddF(A1r + 128 + c1, mb1*y1);
        atomAddF(A1r + 256 + c0, mb0*y2);   atomAddF(A1r + 256 + c1, mb1*y2);
    }
}

// ---------------- edge pass 2: m02 -> A2 (w01/w10 branch is dead code in the reference) ----------------
__global__ __launch_bounds__(256) void k_edge2(const float* __restrict__ ef, const float* __restrict__ Y1,
                                               const int* __restrict__ ei, const float* __restrict__ R2,
                                               const float* __restrict__ s1u2, const float* __restrict__ vup,
                                               float* __restrict__ A2) {
    __shared__ float RL[2048];
    for (int i = threadIdx.x; i < 2048; i += 256) RL[i] = R2[(i >> 8) * 512 + (i & 255)];
    __syncthreads();
    int lane = threadIdx.x & 63;
    int wv = (blockIdx.x * 256 + threadIdx.x) >> 6;
    int nw = gridDim.x * 4;
    for (int e = wv; e < EE; e += nw) {
        int sn = ei[e], rv = ei[EE + e];
        float y0 = Y1[e*3+0], y1 = Y1[e*3+1], y2 = Y1[e*3+2];
        float efb[8];
#pragma unroll
        for (int b = 0; b < 8; b++) efb[b] = ef[e*8+b];
        int c0 = lane, c1 = lane + 64;
        float w00_0 = 0, w00_1 = 0, w110_0 = 0, w110_1 = 0;
#pragma unroll
        for (int b = 0; b < 8; b++) {
            w00_0  += efb[b] * RL[b*256 + c0];      w110_0 += efb[b] * RL[b*256 + 128 + c0];
            w00_1  += efb[b] * RL[b*256 + c1];      w110_1 += efb[b] * RL[b*256 + 128 + c1];
        }
        float sj0 = s1u2[sn*KK + c0], sj1 = s1u2[sn*KK + c1];
        const float* vu = vup + (size_t)sn * 384;
        float tt0 = (vu[c0]*y0 + vu[128 + c0]*y1 + vu[256 + c0]*y2) * INV_SQ3;
        float tt1 = (vu[c1]*y0 + vu[128 + c1]*y1 + vu[256 + c1]*y2) * INV_SQ3;
        float m0 = w00_0 * sj0 + w110_0 * tt0;
        float m1 = w00_1 * sj1 + w110_1 * tt1;
        atomAddF(&A2[(size_t)rv*KK + c0], m0);
        atomAddF(&A2[(size_t)rv*KK + c1], m1);
    }
}

// ---------------- MLP energy + seed backward (g_s2, g_s1 := w_r1) ----------------
__global__ __launch_bounds__(128) void k_mlp(const float* __restrict__ s2, const float* __restrict__ W_mlp,
                                             const float* __restrict__ w_out, const float* __restrict__ w_r1,
                                             const int* __restrict__ batch,
                                             float* __restrict__ out, float* __restrict__ g_s2,
                                             float* __restrict__ g_s1) {
    __shared__ float WmL[KK * 17];
    __shared__ float s2L[KK];
    __shared__ float ghL[16];
    __shared__ float eL[16];
    int n = blockIdx.x, t = threadIdx.x;
    for (int i = t; i < KK * 16; i += 128) WmL[(i >> 4) * 17 + (i & 15)] = W_mlp[i];
    s2L[t] = s2[(size_t)n * KK + t];
    __syncthreads();
    if (t < 16) {
        float h = 0.f;
        for (int c = 0; c < KK; c++) h += s2L[c] * WmL[c * 17 + t];
        float sg = 1.f / (1.f + expf(-h));
        eL[t]  = h * sg * w_out[t];
        ghL[t] = w_out[t] * sg * (1.f + h * (1.f - sg));
    }
    __syncthreads();
    if (t == 0) {
        float e = 0.f;
#pragma unroll
        for (int j = 0; j < 16; j++) e += eL[j];
        int b = batch[n];
        atomAddF(&out[b], e);
        atomAddF(&out[GG + b*3 + 2], e);
    }
    float g = 0.f;
#pragma unroll
    for (int j = 0; j < 16; j++) g += ghL[j] * WmL[t * 17 + j];
    g_s2[(size_t)n * KK + t] = g;
    g_s1[(size_t)n * KK + t] = w_r1[t];
}

// ---------------- backward edge pass A (layer 2): G_sj2, G_vj scatters; gef/gy1 write ----------------
__global__ __launch_bounds__(256) void k_bwdA(const float* __restrict__ ef, const float* __restrict__ Y1,
                                              const int* __restrict__ ei, const float* __restrict__ R2,
                                              const float* __restrict__ gA2, const float* __restrict__ s1u2,
                                              const float* __restrict__ vup,
                                              float* __restrict__ Gsj2, float* __restrict__ Gvj,
                                              float* __restrict__ gef, float* __restrict__ gy1) {
    __shared__ float RL[2048];
    for (int i = threadIdx.x; i < 2048; i += 256) RL[i] = R2[(i >> 8) * 512 + (i & 255)];
    __syncthreads();
    int lane = threadIdx.x & 63;
    int wv = (blockIdx.x * 256 + threadIdx.x) >> 6;
    int nw = gridDim.x * 4;
    for (int e = wv; e < EE; e += nw) {
        int sn = ei[e], rv = ei[EE + e];
        float y0 = Y1[e*3+0], y1 = Y1[e*3+1], y2 = Y1[e*3+2];
        float efb[8];
#pragma unroll
        for (int b = 0; b < 8; b++) efb[b] = ef[e*8+b];
        int c0 = lane, c1 = lane + 64;
        float w00_0 = 0, w00_1 = 0, w110_0 = 0, w110_1 = 0;
#pragma unroll
        for (int b = 0; b < 8; b++) {
            w00_0  += efb[b] * RL[b*256 + c0];      w110_0 += efb[b] * RL[b*256 + 128 + c0];
            w00_1  += efb[b] * RL[b*256 + c1];      w110_1 += efb[b] * RL[b*256 + 128 + c1];
        }
        float ga0 = gA2[(size_t)rv*KK + c0], ga1 = gA2[(size_t)rv*KK + c1];
        float sj0 = s1u2[sn*KK + c0], sj1 = s1u2[sn*KK + c1];
        const float* vu = vup + (size_t)sn * 384;
        float vj00 = vu[c0], vj01 = vu[c1];
        float vj10 = vu[128 + c0], vj11 = vu[128 + c1];
        float vj20 = vu[256 + c0], vj21 = vu[256 + c1];
        float tt0 = (vj00*y0 + vj10*y1 + vj20*y2) * INV_SQ3;
        float tt1 = (vj01*y0 + vj11*y1 + vj21*y2) * INV_SQ3;
        // g w.r.t. sj2 -> scatter to snd
        atomAddF(&Gsj2[(size_t)sn*KK + c0], ga0 * w00_0);
        atomAddF(&Gsj2[(size_t)sn*KK + c1], ga1 * w00_1);
        float gt0 = ga0 * w110_0, gt1 = ga1 * w110_1;
        float gts0 = gt0 * INV_SQ3, gts1 = gt1 * INV_SQ3;
        float* Gv = Gvj + (size_t)sn * 384;
        atomAddF(Gv + c0, gts0*y0);        atomAddF(Gv + c1, gts1*y0);
        atomAddF(Gv + 128 + c0, gts0*y1);  atomAddF(Gv + 128 + c1, gts1*y1);
        atomAddF(Gv + 256 + c0, gts0*y2);  atomAddF(Gv + 256 + c1, gts1*y2);
        // g w.r.t. ef (8 dots over c) and Y1 (3 dots)
        float gw00_0 = ga0 * sj0, gw00_1 = ga1 * sj1;
        float gw110_0 = ga0 * tt0, gw110_1 = ga1 * tt1;
#pragma unroll
        for (int b = 0; b < 8; b++) {
            float pb = gw00_0 * RL[b*256 + c0] + gw00_1 * RL[b*256 + c1]
                     + gw110_0 * RL[b*256 + 128 + c0] + gw110_1 * RL[b*256 + 128 + c1];
            pb = waveRed(pb);
            if (lane == 0) gef[e*8 + b] = pb;
        }
        float p0 = waveRed((gt0*vj00 + gt1*vj01) * INV_SQ3);
        float p1 = waveRed((gt0*vj10 + gt1*vj11) * INV_SQ3);
        float p2 = waveRed((gt0*vj20 + gt1*vj21) * INV_SQ3);
        if (lane == 0) { gy1[e*3+0] = p0; gy1[e*3+1] = p1; gy1[e*3+2] = p2; }
    }
}

// ---------------- backward edge pass B (layer 1): accumulate into gef/gy1 ----------------
__global__ __launch_bounds__(256) void k_bwdB(const float* __restrict__ ef, const float* __restrict__ Y1,
                                              const int* __restrict__ ei, const float* __restrict__ R1,
                                              const float* __restrict__ su1, const float* __restrict__ gA0,
                                              const float* __restrict__ gA1,
                                              float* __restrict__ gef, float* __restrict__ gy1) {
    __shared__ float RL[2048];
    for (int i = threadIdx.x; i < 2048; i += 256) RL[i] = R1[i];
    __syncthreads();
    int lane = threadIdx.x & 63;
    int wv = (blockIdx.x * 256 + threadIdx.x) >> 6;
    int nw = gridDim.x * 4;
    for (int e = wv; e < EE; e += nw) {
        int sn = ei[e], rv = ei[EE + e];
        float y0 = Y1[e*3+0], y1 = Y1[e*3+1], y2 = Y1[e*3+2];
        float efb[8];
#pragma unroll
        for (int b = 0; b < 8; b++) efb[b] = ef[e*8+b];
        int c0 = lane, c1 = lane + 64;
        float wb0 = 0, wb1 = 0;
#pragma unroll
        for (int b = 0; b < 8; b++) {
            wb0 += efb[b] * RL[b*256 + 128 + c0];
            wb1 += efb[b] * RL[b*256 + 128 + c1];
        }
        float sj0 = su1[sn*KK + c0], sj1 = su1[sn*KK + c1];
        float gm00 = gA0[(size_t)rv*KK + c0], gm01 = gA0[(size_t)rv*KK + c1];
        const float* gA1r = gA1 + (size_t)rv * 384;
        float g10 = gA1r[c0], g11 = gA1r[c1];
        float g20 = gA1r[128 + c0], g21 = gA1r[128 + c1];
        float g30 = gA1r[256 + c0], g31 = gA1r[256 + c1];
        float gwa0 = gm00 * sj0, gwa1 = gm01 * sj1;
        float q0 = g10*y0 + g20*y1 + g30*y2;
        float q1 = g11*y0 + g21*y1 + g31*y2;
        float gwb0 = q0 * sj0, gwb1 = q1 * sj1;
#pragma unroll
        for (int b = 0; b < 8; b++) {
            float pb = gwa0 * RL[b*256 + c0] + gwa1 * RL[b*256 + c1]
                     + gwb0 * RL[b*256 + 128 + c0] + gwb1 * RL[b*256 + 128 + c1];
            pb = waveRed(pb);
            if (lane == 0) gef[e*8 + b] += pb;
        }
        float w0s = wb0 * sj0, w1s = wb1 * sj1;
        float p0 = waveRed(g10 * w0s + g11 * w1s);
        float p1 = waveRed(g20 * w0s + g21 * w1s);
        float p2 = waveRed(g30 * w0s + g31 * w1s);
        if (lane == 0) { gy1[e*3+0] += p0; gy1[e*3+1] += p1; gy1[e*3+2] += p2; }
    }
}

// ---------------- final: per-edge g_vec -> forces ----------------
__global__ void k_force(const float* __restrict__ gef, const float* __restrict__ defdr,
                        const float* __restrict__ gy1, const float* __restrict__ Y1,
                        const float* __restrict__ rr, const int* __restrict__ ei,
                        float* __restrict__ forces) {
    int e = blockIdx.x * blockDim.x + threadIdx.x;
    if (e >= EE) return;
    float gr = 0.f;
#pragma unroll
    for (int b = 0; b < 8; b++) gr += gef[e*8+b] * defdr[e*8+b];
    float y0 = Y1[e*3+0], y1 = Y1[e*3+1], y2 = Y1[e*3+2];
    float g0 = gy1[e*3+0], g1 = gy1[e*3+1], g2 = gy1[e*3+2];
    float ir = 1.f / rr[e];
    float dot = g0*y0 + g1*y1 + g2*y2;
    float a = gr * INV_SQ3;
    float b2 = SQ3F * ir;
    float c = b2 * dot * (1.f / 3.f);
    float gv0 = a*y0 + b2*g0 - c*y0;
    float gv1 = a*y1 + b2*g1 - c*y1;
    float gv2 = a*y2 + b2*g2 - c*y2;
    int sn = ei[e], rv = ei[EE + e];
    atomAddF(&forces[rv*3+0], -gv0); atomAddF(&forces[rv*3+1], -gv1); atomAddF(&forces[rv*3+2], -gv2);
    atomAddF(&forces[sn*3+0],  gv0); atomAddF(&forces[sn*3+1],  gv1); atomAddF(&forces[sn*3+2],  gv2);
}

extern "C" void kernel_launch(void* const* d_in, const int* in_sizes, int n_in,
                              void* d_out, int out_size, void* d_ws, size_t ws_size,
                              hipStream_t stream) {
    const float* positions  = (const float*)d_in[0];
    const float* shifts     = (const float*)d_in[1];
    const int*   edge_index = (const int*)d_in[2];
    const int*   node_z     = (const int*)d_in[3];
    const int*   batch      = (const int*)d_in[4];
    const float* atomic_e   = (const float*)d_in[5];
    const float* W_embed    = (const float*)d_in[6];
    const float* R1         = (const float*)d_in[7];
    const float* W_up1      = (const float*)d_in[8];
    const float* W_mix_s1   = (const float*)d_in[9];
    const float* W_mix_v1   = (const float*)d_in[10];
    const float* W_sk_s1    = (const float*)d_in[11];
    const float* w_r1       = (const float*)d_in[12];
    const float* R2         = (const float*)d_in[13];
    const float* W_up2s     = (const float*)d_in[14];
    const float* W_up2v     = (const float*)d_in[15];
    const float* W_mix_s2   = (const float*)d_in[16];
    const float* W_sk_s2    = (const float*)d_in[17];
    const float* W_mlp      = (const float*)d_in[18];
    const float* w_out      = (const float*)d_in[19];

    float* out = (float*)d_out;
    float* ws = (float*)d_ws;
    size_t off = 0;
    float* ef    = ws + off; off += (size_t)EE * 8;
    float* defdr = ws + off; off += (size_t)EE * 8;
    float* Y1    = ws + off; off += (size_t)EE * 3;
    float* rr    = ws + off; off += (size_t)EE;
    float* gef   = ws + off; off += (size_t)EE * 8;
    float* gy1   = ws + off; off += (size_t)EE * 3;
    float* s     = ws + off; off += (size_t)NN * KK;
    float* su1   = ws + off; off += (size_t)NN * KK;
    float* s1    = ws + off; off += (size_t)NN * KK;
    float* s1u2  = ws + off; off += (size_t)NN * KK;
    float* s2    = ws + off; off += (size_t)NN * KK;
    float* g_s2  = ws + off; off += (size_t)NN * KK;
    float* g_s1  = ws + off; off += (size_t)NN * KK;
    float* v1    = ws + off; off += (size_t)NN * KK * 3;   // later reused as g_v1
    float* vup   = ws + off; off += (size_t)NN * KK * 3;
    float* zblk  = ws + off;                               // contiguous atomic-target block
    float* A0    = ws + off; off += (size_t)NN * KK;       // later g_A0
    float* A2    = ws + off; off += (size_t)NN * KK;       // later g_A2
    float* Gsj2  = ws + off; off += (size_t)NN * KK;
    float* A1    = ws + off; off += (size_t)NN * KK * 3;   // later g_A1
    float* Gvj   = ws + off; off += (size_t)NN * KK * 3;
    size_t zcount = (size_t)NN * KK * 9;

    hipMemsetAsync(out, 0, (size_t)out_size * sizeof(float), stream);
    hipMemsetAsync(zblk, 0, zcount * sizeof(float), stream);

    // ---- forward ----
    k_edge_geom<<<(EE + 255) / 256, 256, 0, stream>>>(positions, shifts, edge_index, ef, defdr, Y1, rr);
    k_embed<<<(NN * KK + 255) / 256, 256, 0, stream>>>(node_z, batch, W_embed, atomic_e, s, out);
    k_gemm<0><<<512, 256, 0, stream>>>(s, W_up1, su1, NN, 1.f, 0);
    k_edge1<<<1024, 256, 0, stream>>>(ef, Y1, edge_index, R1, su1, A0, A1);
    k_gemm<0><<<512, 256, 0, stream>>>(A0, W_mix_s1, s1, NN, INV_AVG, 0);
    k_skip_fwd<<<512, 256, 0, stream>>>(s, W_sk_s1, node_z, s1);
    k_gemm<0><<<512, 256, 0, stream>>>(A1, W_mix_v1, v1, NN * 3, INV_AVG, 0);
    k_e1<<<256, 256, 0, stream>>>(s1, w_r1, batch, out);
    k_gemm<0><<<512, 256, 0, stream>>>(s1, W_up2s, s1u2, NN, 1.f, 0);
    k_gemm<0><<<512, 256, 0, stream>>>(v1, W_up2v, vup, NN * 3, 1.f, 0);
    k_edge2<<<1024, 256, 0, stream>>>(ef, Y1, edge_index, R2, s1u2, vup, A2);
    k_gemm<0><<<512, 256, 0, stream>>>(A2, W_mix_s2, s2, NN, INV_AVG, 0);
    k_skip_fwd<<<512, 256, 0, stream>>>(s1, W_sk_s2, node_z, s2);
    // ---- energy head + backward seed ----
    k_mlp<<<NN, 128, 0, stream>>>(s2, W_mlp, w_out, w_r1, batch, out, g_s2, g_s1);
    // ---- backward ----
    k_gemm<1><<<512, 256, 0, stream>>>(g_s2, W_mix_s2, A2, NN, INV_AVG, 0);       // g_A2 (reuses A2)
    k_skip_bwd<<<512, 256, 0, stream>>>(g_s2, W_sk_s2, node_z, g_s1);
    k_bwdA<<<1024, 256, 0, stream>>>(ef, Y1, edge_index, R2, A2, s1u2, vup, Gsj2, Gvj, gef, gy1);
    k_gemm<1><<<512, 256, 0, stream>>>(Gsj2, W_up2s, g_s1, NN, 1.f, 1);
    k_gemm<1><<<512, 256, 0, stream>>>(Gvj, W_up2v, v1, NN * 3, 1.f, 0);          // g_v1 (reuses v1)
    k_gemm<1><<<512, 256, 0, stream>>>(v1, W_mix_v1, A1, NN * 3, INV_AVG, 0);     // g_A1 (reuses A1)
    k_gemm<1><<<512, 256, 0, stream>>>(g_s1, W_mix_s1, A0, NN, INV_AVG, 0);       // g_A0 (reuses A0)
    k_bwdB<<<1024, 256, 0, stream>>>(ef, Y1, edge_index, R1, su1, A0, A1, gef, gy1);
    k_force<<<(EE + 255) / 256, 256, 0, stream>>>(gef, defdr, gy1, Y1, rr, edge_index, out + GG + GG * 3);
}

// Round 2
// 1951.774 us; speedup vs baseline: 1.1142x; 1.1142x over previous
//
#include <hip/hip_runtime.h>
#include <math.h>

#define NN 10000
#define EE 160000
#define KK 128
#define GG 16
#define SQ3F 1.7320508075688772f
#define INV_SQ3 0.57735026918962576f
#define INV_AVG 0.0625f
#define RMAXI 0.2f

__device__ __forceinline__ void atomAddF(float* p, float v) { unsafeAtomicAdd(p, v); }

__device__ __forceinline__ float waveRed(float v) {
#pragma unroll
    for (int m = 32; m >= 1; m >>= 1) v += __shfl_xor(v, m);
    return v;
}

// ---------------- edge geometry: r, Y1, ef(bessel*fcut), d(ef)/dr ----------------
__global__ void k_edge_geom(const float* __restrict__ pos, const float* __restrict__ shifts,
                            const int* __restrict__ ei,
                            float* __restrict__ ef, float* __restrict__ defdr,
                            float* __restrict__ Y1, float* __restrict__ rr) {
    int e = blockIdx.x * blockDim.x + threadIdx.x;
    if (e >= EE) return;
    int sn = ei[e], rv = ei[EE + e];
    float vx = pos[rv*3+0] - pos[sn*3+0] + shifts[e*3+0];
    float vy = pos[rv*3+1] - pos[sn*3+1] + shifts[e*3+1];
    float vz = pos[rv*3+2] - pos[sn*3+2] + shifts[e*3+2];
    float r = sqrtf(vx*vx + vy*vy + vz*vz + 1e-12f);
    float ir = 1.0f / r;
    rr[e] = r;
    Y1[e*3+0] = SQ3F*vx*ir; Y1[e*3+1] = SQ3F*vy*ir; Y1[e*3+2] = SQ3F*vz*ir;
    float x = r * RMAXI;
    float fc = 0.f, dfc = 0.f;
    if (x < 1.0f) {
        float x2 = x*x, x4 = x2*x2, x5 = x4*x, x6 = x5*x, x7 = x6*x;
        fc  = 1.0f - 21.0f*x5 + 35.0f*x6 - 15.0f*x7;
        dfc = (-105.0f*x4 + 210.0f*x5 - 105.0f*x6) * RMAXI;
    }
    const float C = 0.63245553203367587f; // sqrt(2/5)
    float4 efa, efb4, da, db;
    float* efp = (float*)&efa; float* dp = (float*)&da;
#pragma unroll
    for (int b = 0; b < 8; b++) {
        float kb = (float)(b + 1) * 0.62831853071795865f; // (b+1)*pi/5
        float sb, cb;
        sincosf(kb * r, &sb, &cb);
        float bess  = C * sb * ir;
        float dbess = C * ir * (kb * cb - sb * ir);
        if (b == 4) { efp = (float*)&efb4; dp = (float*)&db; }
        efp[b & 3] = bess * fc;
        dp[b & 3]  = dbess * fc + bess * dfc;
    }
    ((float4*)ef)[e*2]      = efa; ((float4*)ef)[e*2+1]    = efb4;
    ((float4*)defdr)[e*2]   = da;  ((float4*)defdr)[e*2+1] = db;
}

// ---------------- CSR build ----------------
__global__ void k_hist(const int* __restrict__ ei, int* __restrict__ deg_r, int* __restrict__ deg_s) {
    int e = blockIdx.x * blockDim.x + threadIdx.x;
    if (e >= EE) return;
    atomicAdd(&deg_s[ei[e]], 1);
    atomicAdd(&deg_r[ei[EE + e]], 1);
}

__global__ __launch_bounds__(1024) void k_scan(const int* __restrict__ deg_r, const int* __restrict__ deg_s,
                                               int* __restrict__ row_r, int* __restrict__ row_s) {
    __shared__ int part[1024];
    int t = threadIdx.x;
    for (int a = 0; a < 2; a++) {
        const int* deg = a ? deg_s : deg_r;
        int* row = a ? row_s : row_r;
        int base = t * 10;
        int loc[10];
        int s = 0;
#pragma unroll
        for (int k = 0; k < 10; k++) {
            loc[k] = s;
            if (base + k < NN) s += deg[base + k];
        }
        part[t] = s;
        __syncthreads();
        for (int off = 1; off < 1024; off <<= 1) {
            int v = (t >= off) ? part[t - off] : 0;
            __syncthreads();
            part[t] += v;
            __syncthreads();
        }
        int bex = (t > 0) ? part[t - 1] : 0;
#pragma unroll
        for (int k = 0; k < 10; k++)
            if (base + k < NN) row[base + k] = bex + loc[k];
        if (t == 1023) row[NN] = part[1023];
        __syncthreads();
    }
}

__global__ void k_fill(const int* __restrict__ ei, const int* __restrict__ row_r, const int* __restrict__ row_s,
                       int* __restrict__ cur_r, int* __restrict__ cur_s,
                       int2* __restrict__ list_r, int2* __restrict__ list_s) {
    int e = blockIdx.x * blockDim.x + threadIdx.x;
    if (e >= EE) return;
    int sn = ei[e], rv = ei[EE + e];
    int pr = atomicAdd(&cur_r[rv], 1);
    list_r[row_r[rv] + pr] = make_int2(e, sn);
    int ps = atomicAdd(&cur_s[sn], 1);
    list_s[row_s[sn] + ps] = make_int2(e, rv);
}

// ---------------- node embedding + e0 ----------------
__global__ void k_embed(const int* __restrict__ z, const int* __restrict__ batch,
                        const float* __restrict__ W_embed, const float* __restrict__ ae,
                        float* __restrict__ s, float* __restrict__ out) {
    int i = blockIdx.x * blockDim.x + threadIdx.x;
    if (i >= NN * KK) return;
    int n = i >> 7, d = i & 127;
    int zz = z[n];
    s[i] = W_embed[zz * KK + d];
    if (d == 0) {
        float v = ae[zz];
        int b = batch[n];
        atomAddF(&out[b], v);
        atomAddF(&out[GG + b*3 + 0], v);
    }
}

// ---------------- generic K x K GEMM ----------------
template <int TRANS>
__global__ __launch_bounds__(256) void k_gemm(const float* __restrict__ in, const float* __restrict__ W,
                                              float* __restrict__ out, int rows, float alpha, int accum) {
    __shared__ float WL[KK * KK];
    int t = threadIdx.x;
    int lane = t & 127, slot = t >> 7;
    for (int a = slot; a < KK; a += 2) {
        float v = W[a * KK + lane];
        if (!TRANS) WL[a * KK + ((a + lane) & 127)] = v;
        else        WL[lane * KK + ((lane + a) & 127)] = v;
    }
    __syncthreads();
    for (int row = blockIdx.x * 2 + slot; row < rows; row += gridDim.x * 2) {
        const float4* inr4 = (const float4*)(in + (size_t)row * KK);
        float acc = 0.f;
#pragma unroll
        for (int i0 = 0; i0 < KK; i0 += 4) {
            float4 v = inr4[i0 >> 2];
            acc += v.x * WL[(i0+0)*KK + ((i0+0+lane)&127)];
            acc += v.y * WL[(i0+1)*KK + ((i0+1+lane)&127)];
            acc += v.z * WL[(i0+2)*KK + ((i0+2+lane)&127)];
            acc += v.w * WL[(i0+3)*KK + ((i0+3+lane)&127)];
        }
        acc *= alpha;
        float* o = out + (size_t)row * KK + lane;
        if (accum) *o += acc; else *o = acc;
    }
}

// ---------------- per-z skip ----------------
__global__ __launch_bounds__(256) void k_skip_fwd(const float* __restrict__ in, const float* __restrict__ Wall,
                                                  const int* __restrict__ z, float* __restrict__ out) {
    int wv = (blockIdx.x * 256 + threadIdx.x) >> 6;
    int lane = threadIdx.x & 63;
    int nw = gridDim.x * 4;
    for (int n = wv; n < NN; n += nw) {
        const float* Wz = Wall + (size_t)z[n] * (KK * KK);
        const float* inr = in + (size_t)n * KK;
        float a0 = 0.f, a1 = 0.f;
        for (int c = 0; c < KK; c++) {
            float v = inr[c];
            a0 += v * Wz[c * KK + lane];
            a1 += v * Wz[c * KK + 64 + lane];
        }
        out[n * KK + lane] += a0;
        out[n * KK + 64 + lane] += a1;
    }
}

__global__ __launch_bounds__(256) void k_skip_bwd(const float* __restrict__ gin, const float* __restrict__ Wall,
                                                  const int* __restrict__ z, float* __restrict__ gout) {
    int wv = (blockIdx.x * 256 + threadIdx.x) >> 6;
    int lane = threadIdx.x & 63;
    int nw = gridDim.x * 4;
    for (int n = wv; n < NN; n += nw) {
        const float* Wz = Wall + (size_t)z[n] * (KK * KK);
        const float4* g4 = (const float4*)(gin + (size_t)n * KK);
        const float4* w0 = (const float4*)(Wz + lane * KK);
        const float4* w1 = (const float4*)(Wz + (64 + lane) * KK);
        float a0 = 0.f, a1 = 0.f;
#pragma unroll 8
        for (int d0 = 0; d0 < 32; d0++) {
            float4 g = g4[d0];
            float4 u = w0[d0]; a0 += g.x*u.x + g.y*u.y + g.z*u.z + g.w*u.w;
            float4 w = w1[d0]; a1 += g.x*w.x + g.y*w.y + g.z*w.z + g.w*w.w;
        }
        gout[n * KK + lane] += a0;
        gout[n * KK + 64 + lane] += a1;
    }
}

// ---------------- e1 ----------------
__global__ __launch_bounds__(256) void k_e1(const float* __restrict__ s1, const float* __restrict__ w_r1,
                                            const int* __restrict__ batch, float* __restrict__ out) {
    int wv = (blockIdx.x * 256 + threadIdx.x) >> 6;
    int lane = threadIdx.x & 63;
    int nw = gridDim.x * 4;
    for (int n = wv; n < NN; n += nw) {
        float a = s1[n*KK + lane] * w_r1[lane] + s1[n*KK + 64 + lane] * w_r1[64 + lane];
        a = waveRed(a);
        if (lane == 0) {
            int b = batch[n];
            atomAddF(&out[b], a);
            atomAddF(&out[GG + b*3 + 1], a);
        }
    }
}

// ---------------- edge pass 1 (rcv-centric gather): A0[n], A1[n] ----------------
__global__ __launch_bounds__(256) void k_edge1_g(const float* __restrict__ ef, const float* __restrict__ Y1,
                                                 const float* __restrict__ R1, const float* __restrict__ su1,
                                                 const int* __restrict__ row_r, const int2* __restrict__ list_r,
                                                 float* __restrict__ A0, float* __restrict__ A1) {
    __shared__ float RL[2048];
    for (int i = threadIdx.x; i < 2048; i += 256) RL[i] = R1[i];
    __syncthreads();
    int lane = threadIdx.x & 63;
    int n = blockIdx.x * 4 + (threadIdx.x >> 6);
    if (n >= NN) return;
    int c0 = lane, c1 = lane + 64;
    float a00 = 0.f, a01 = 0.f;
    float ax0 = 0.f, ax1 = 0.f, ay0 = 0.f, ay1 = 0.f, az0 = 0.f, az1 = 0.f;
    int beg = row_r[n], end = row_r[n + 1];
    for (int i = beg; i < end; i++) {
        int2 p = list_r[i];
        int e = p.x, sn = p.y;
        float4 efa = ((const float4*)ef)[e*2], efb4 = ((const float4*)ef)[e*2+1];
        float y0 = Y1[e*3+0], y1 = Y1[e*3+1], y2 = Y1[e*3+2];
        float wa0 = 0, wa1 = 0, wb0 = 0, wb1 = 0;
        const float* eb = (const float*)&efa;
#pragma unroll
        for (int b = 0; b < 8; b++) {
            if (b == 4) eb = (const float*)&efb4;
            float v = eb[b & 3];
            wa0 += v * RL[b*256 + c0];       wb0 += v * RL[b*256 + 128 + c0];
            wa1 += v * RL[b*256 + c1];       wb1 += v * RL[b*256 + 128 + c1];
        }
        float sj0 = su1[sn*KK + c0], sj1 = su1[sn*KK + c1];
        a00 += wa0 * sj0; a01 += wa1 * sj1;
        float mb0 = wb0 * sj0, mb1 = wb1 * sj1;
        ax0 += mb0*y0; ax1 += mb1*y0;
        ay0 += mb0*y1; ay1 += mb1*y1;
        az0 += mb0*y2; az1 += mb1*y2;
    }
    A0[(size_t)n*KK + c0] = a00;  A0[(size_t)n*KK + c1] = a01;
    float* A1r = A1 + (size_t)n * 384;
    A1r[c0] = ax0;        A1r[c1] = ax1;
    A1r[128 + c0] = ay0;  A1r[128 + c1] = ay1;
    A1r[256 + c0] = az0;  A1r[256 + c1] = az1;
}

// ---------------- edge pass 2 (rcv-centric gather): A2[n] ----------------
__global__ __launch_bounds__(256) void k_edge2_g(const float* __restrict__ ef, const float* __restrict__ Y1,
                                                 const float* __restrict__ R2, const float* __restrict__ s1u2,
                                                 const float* __restrict__ vup,
                                                 const int* __restrict__ row_r, const int2* __restrict__ list_r,
                                                 float* __restrict__ A2) {
    __shared__ float RL[2048];
    for (int i = threadIdx.x; i < 2048; i += 256) RL[i] = R2[(i >> 8) * 512 + (i & 255)];
    __syncthreads();
    int lane = threadIdx.x & 63;
    int n = blockIdx.x * 4 + (threadIdx.x >> 6);
    if (n >= NN) return;
    int c0 = lane, c1 = lane + 64;
    float a0 = 0.f, a1 = 0.f;
    int beg = row_r[n], end = row_r[n + 1];
    for (int i = beg; i < end; i++) {
        int2 p = list_r[i];
        int e = p.x, sn = p.y;
        float4 efa = ((const float4*)ef)[e*2], efb4 = ((const float4*)ef)[e*2+1];
        float y0 = Y1[e*3+0], y1 = Y1[e*3+1], y2 = Y1[e*3+2];
        float w00_0 = 0, w00_1 = 0, w110_0 = 0, w110_1 = 0;
        const float* eb = (const float*)&efa;
#pragma unroll
        for (int b = 0; b < 8; b++) {
            if (b == 4) eb = (const float*)&efb4;
            float v = eb[b & 3];
            w00_0  += v * RL[b*256 + c0];      w110_0 += v * RL[b*256 + 128 + c0];
            w00_1  += v * RL[b*256 + c1];      w110_1 += v * RL[b*256 + 128 + c1];
        }
        float sj0 = s1u2[sn*KK + c0], sj1 = s1u2[sn*KK + c1];
        const float* vu = vup + (size_t)sn * 384;
        float tt0 = (vu[c0]*y0 + vu[128 + c0]*y1 + vu[256 + c0]*y2) * INV_SQ3;
        float tt1 = (vu[c1]*y0 + vu[128 + c1]*y1 + vu[256 + c1]*y2) * INV_SQ3;
        a0 += w00_0 * sj0 + w110_0 * tt0;
        a1 += w00_1 * sj1 + w110_1 * tt1;
    }
    A2[(size_t)n*KK + c0] = a0;
    A2[(size_t)n*KK + c1] = a1;
}

// ---------------- MLP energy + backward seed ----------------
__global__ __launch_bounds__(128) void k_mlp(const float* __restrict__ s2, const float* __restrict__ W_mlp,
                                             const float* __restrict__ w_out, const float* __restrict__ w_r1,
                                             const int* __restrict__ batch,
                                             float* __restrict__ out, float* __restrict__ g_s2,
                                             float* __restrict__ g_s1) {
    __shared__ float WmL[KK * 17];
    __shared__ float s2L[KK];
    __shared__ float ghL[16];
    __shared__ float eL[16];
    int n = blockIdx.x, t = threadIdx.x;
    for (int i = t; i < KK * 16; i += 128) WmL[(i >> 4) * 17 + (i & 15)] = W_mlp[i];
    s2L[t] = s2[(size_t)n * KK + t];
    __syncthreads();
    if (t < 16) {
        float h = 0.f;
        for (int c = 0; c < KK; c++) h += s2L[c] * WmL[c * 17 + t];
        float sg = 1.f / (1.f + expf(-h));
        eL[t]  = h * sg * w_out[t];
        ghL[t] = w_out[t] * sg * (1.f + h * (1.f - sg));
    }
    __syncthreads();
    if (t == 0) {
        float e = 0.f;
#pragma unroll
        for (int j = 0; j < 16; j++) e += eL[j];
        int b = batch[n];
        atomAddF(&out[b], e);
        atomAddF(&out[GG + b*3 + 2], e);
    }
    float g = 0.f;
#pragma unroll
    for (int j = 0; j < 16; j++) g += ghL[j] * WmL[t * 17 + j];
    g_s2[(size_t)n * KK + t] = g;
    g_s1[(size_t)n * KK + t] = w_r1[t];
}

// ---------------- backward edge pass A (snd-centric gather) ----------------
__global__ __launch_bounds__(256) void k_bwdA_g(const float* __restrict__ ef, const float* __restrict__ Y1,
                                                const float* __restrict__ R2, const float* __restrict__ gA2,
                                                const float* __restrict__ s1u2, const float* __restrict__ vup,
                                                const int* __restrict__ row_s, const int2* __restrict__ list_s,
                                                float* __restrict__ Gsj2, float* __restrict__ Gvj,
                                                float* __restrict__ gef, float* __restrict__ gy1) {
    __shared__ float RL[2048];
    for (int i = threadIdx.x; i < 2048; i += 256) RL[i] = R2[(i >> 8) * 512 + (i & 255)];
    __syncthreads();
    int lane = threadIdx.x & 63;
    int sn = blockIdx.x * 4 + (threadIdx.x >> 6);
    if (sn >= NN) return;
    int c0 = lane, c1 = lane + 64;
    // node-invariant gathers
    float sj0 = s1u2[(size_t)sn*KK + c0], sj1 = s1u2[(size_t)sn*KK + c1];
    const float* vu = vup + (size_t)sn * 384;
    float vj00 = vu[c0], vj01 = vu[c1];
    float vj10 = vu[128 + c0], vj11 = vu[128 + c1];
    float vj20 = vu[256 + c0], vj21 = vu[256 + c1];
    float gs0 = 0.f, gs1 = 0.f;
    float gv00 = 0.f, gv01 = 0.f, gv10 = 0.f, gv11 = 0.f, gv20 = 0.f, gv21 = 0.f;
    int beg = row_s[sn], end = row_s[sn + 1];
    for (int i = beg; i < end; i++) {
        int2 p = list_s[i];
        int e = p.x, rv = p.y;
        float4 efa = ((const float4*)ef)[e*2], efb4 = ((const float4*)ef)[e*2+1];
        float y0 = Y1[e*3+0], y1 = Y1[e*3+1], y2 = Y1[e*3+2];
        float w00_0 = 0, w00_1 = 0, w110_0 = 0, w110_1 = 0;
        const float* eb = (const float*)&efa;
#pragma unroll
        for (int b = 0; b < 8; b++) {
            if (b == 4) eb = (const float*)&efb4;
            float v = eb[b & 3];
            w00_0  += v * RL[b*256 + c0];      w110_0 += v * RL[b*256 + 128 + c0];
            w00_1  += v * RL[b*256 + c1];      w110_1 += v * RL[b*256 + 128 + c1];
        }
        float ga0 = gA2[(size_t)rv*KK + c0], ga1 = gA2[(size_t)rv*KK + c1];
        float tt0 = (vj00*y0 + vj10*y1 + vj20*y2) * INV_SQ3;
        float tt1 = (vj01*y0 + vj11*y1 + vj21*y2) * INV_SQ3;
        gs0 += ga0 * w00_0;
        gs1 += ga1 * w00_1;
        float gt0 = ga0 * w110_0, gt1 = ga1 * w110_1;
        float gts0 = gt0 * INV_SQ3, gts1 = gt1 * INV_SQ3;
        gv00 += gts0*y0; gv01 += gts1*y0;
        gv10 += gts0*y1; gv11 += gts1*y1;
        gv20 += gts0*y2; gv21 += gts1*y2;
        float gw00_0 = ga0 * sj0, gw00_1 = ga1 * sj1;
        float gw110_0 = ga0 * tt0, gw110_1 = ga1 * tt1;
        const float* eb2 = (const float*)&efa; (void)eb2;
#pragma unroll
        for (int b = 0; b < 8; b++) {
            float pb = gw00_0 * RL[b*256 + c0] + gw00_1 * RL[b*256 + c1]
                     + gw110_0 * RL[b*256 + 128 + c0] + gw110_1 * RL[b*256 + 128 + c1];
            pb = waveRed(pb);
            if (lane == 0) gef[e*8 + b] = pb;
        }
        float p0 = waveRed((gt0*vj00 + gt1*vj01) * INV_SQ3);
        float p1 = waveRed((gt0*vj10 + gt1*vj11) * INV_SQ3);
        float p2 = waveRed((gt0*vj20 + gt1*vj21) * INV_SQ3);
        if (lane == 0) { gy1[e*3+0] = p0; gy1[e*3+1] = p1; gy1[e*3+2] = p2; }
    }
    float* G = Gsj2 + (size_t)sn * KK;
    G[c0] = gs0; G[c1] = gs1;
    float* Gv = Gvj + (size_t)sn * 384;
    Gv[c0] = gv00;        Gv[c1] = gv01;
    Gv[128 + c0] = gv10;  Gv[128 + c1] = gv11;
    Gv[256 + c0] = gv20;  Gv[256 + c1] = gv21;
}

// ---------------- backward edge pass B (rcv-centric gather) ----------------
__global__ __launch_bounds__(256) void k_bwdB_g(const float* __restrict__ ef, const float* __restrict__ Y1,
                                                const float* __restrict__ R1, const float* __restrict__ su1,
                                                const float* __restrict__ gA0, const float* __restrict__ gA1,
                                                const int* __restrict__ row_r, const int2* __restrict__ list_r,
                                                float* __restrict__ gef, float* __restrict__ gy1) {
    __shared__ float RL[2048];
    for (int i = threadIdx.x; i < 2048; i += 256) RL[i] = R1[i];
    __syncthreads();
    int lane = threadIdx.x & 63;
    int rv = blockIdx.x * 4 + (threadIdx.x >> 6);
    if (rv >= NN) return;
    int c0 = lane, c1 = lane + 64;
    // node-invariant gathers (indexed by rv)
    float gm00 = gA0[(size_t)rv*KK + c0], gm01 = gA0[(size_t)rv*KK + c1];
    const float* gA1r = gA1 + (size_t)rv * 384;
    float g10 = gA1r[c0], g11 = gA1r[c1];
    float g20 = gA1r[128 + c0], g21 = gA1r[128 + c1];
    float g30 = gA1r[256 + c0], g31 = gA1r[256 + c1];
    int beg = row_r[rv], end = row_r[rv + 1];
    for (int i = beg; i < end; i++) {
        int2 p = list_r[i];
        int e = p.x, sn = p.y;
        float4 efa = ((const float4*)ef)[e*2], efb4 = ((const float4*)ef)[e*2+1];
        float y0 = Y1[e*3+0], y1 = Y1[e*3+1], y2 = Y1[e*3+2];
        float wb0 = 0, wb1 = 0;
        const float* eb = (const float*)&efa;
#pragma unroll
        for (int b = 0; b < 8; b++) {
            if (b == 4) eb = (const float*)&efb4;
            float v = eb[b & 3];
            wb0 += v * RL[b*256 + 128 + c0];
            wb1 += v * RL[b*256 + 128 + c1];
        }
        float sj0 = su1[(size_t)sn*KK + c0], sj1 = su1[(size_t)sn*KK + c1];
        float gwa0 = gm00 * sj0, gwa1 = gm01 * sj1;
        float q0 = g10*y0 + g20*y1 + g30*y2;
        float q1 = g11*y0 + g21*y1 + g31*y2;
        float gwb0 = q0 * sj0, gwb1 = q1 * sj1;
#pragma unroll
        for (int b = 0; b < 8; b++) {
            float pb = gwa0 * RL[b*256 + c0] + gwa1 * RL[b*256 + c1]
                     + gwb0 * RL[b*256 + 128 + c0] + gwb1 * RL[b*256 + 128 + c1];
            pb = waveRed(pb);
            if (lane == 0) gef[e*8 + b] += pb;
        }
        float w0s = wb0 * sj0, w1s = wb1 * sj1;
        float p0 = waveRed(g10 * w0s + g11 * w1s);
        float p1 = waveRed(g20 * w0s + g21 * w1s);
        float p2 = waveRed(g30 * w0s + g31 * w1s);
        if (lane == 0) { gy1[e*3+0] += p0; gy1[e*3+1] += p1; gy1[e*3+2] += p2; }
    }
}

// ---------------- final: per-edge g_vec -> forces ----------------
__global__ void k_force(const float* __restrict__ gef, const float* __restrict__ defdr,
                        const float* __restrict__ gy1, const float* __restrict__ Y1,
                        const float* __restrict__ rr, const int* __restrict__ ei,
                        float* __restrict__ forces) {
    int e = blockIdx.x * blockDim.x + threadIdx.x;
    if (e >= EE) return;
    float gr = 0.f;
#pragma unroll
    for (int b = 0; b < 8; b++) gr += gef[e*8+b] * defdr[e*8+b];
    float y0 = Y1[e*3+0], y1 = Y1[e*3+1], y2 = Y1[e*3+2];
    float g0 = gy1[e*3+0], g1 = gy1[e*3+1], g2 = gy1[e*3+2];
    float ir = 1.f / rr[e];
    float dot = g0*y0 + g1*y1 + g2*y2;
    float a = gr * INV_SQ3;
    float b2 = SQ3F * ir;
    float c = b2 * dot * (1.f / 3.f);
    float gv0 = a*y0 + b2*g0 - c*y0;
    float gv1 = a*y1 + b2*g1 - c*y1;
    float gv2 = a*y2 + b2*g2 - c*y2;
    int sn = ei[e], rv = ei[EE + e];
    atomAddF(&forces[rv*3+0], -gv0); atomAddF(&forces[rv*3+1], -gv1); atomAddF(&forces[rv*3+2], -gv2);
    atomAddF(&forces[sn*3+0],  gv0); atomAddF(&forces[sn*3+1],  gv1); atomAddF(&forces[sn*3+2],  gv2);
}

extern "C" void kernel_launch(void* const* d_in, const int* in_sizes, int n_in,
                              void* d_out, int out_size, void* d_ws, size_t ws_size,
                              hipStream_t stream) {
    const float* positions  = (const float*)d_in[0];
    const float* shifts     = (const float*)d_in[1];
    const int*   edge_index = (const int*)d_in[2];
    const int*   node_z     = (const int*)d_in[3];
    const int*   batch      = (const int*)d_in[4];
    const float* atomic_e   = (const float*)d_in[5];
    const float* W_embed    = (const float*)d_in[6];
    const float* R1         = (const float*)d_in[7];
    const float* W_up1      = (const float*)d_in[8];
    const float* W_mix_s1   = (const float*)d_in[9];
    const float* W_mix_v1   = (const float*)d_in[10];
    const float* W_sk_s1    = (const float*)d_in[11];
    const float* w_r1       = (const float*)d_in[12];
    const float* R2         = (const float*)d_in[13];
    const float* W_up2s     = (const float*)d_in[14];
    const float* W_up2v     = (const float*)d_in[15];
    const float* W_mix_s2   = (const float*)d_in[16];
    const float* W_sk_s2    = (const float*)d_in[17];
    const float* W_mlp      = (const float*)d_in[18];
    const float* w_out      = (const float*)d_in[19];

    float* out = (float*)d_out;
    float* ws = (float*)d_ws;
    size_t off = 0;
    float* ef    = ws + off; off += (size_t)EE * 8;
    float* defdr = ws + off; off += (size_t)EE * 8;
    float* Y1    = ws + off; off += (size_t)EE * 3;
    float* rr    = ws + off; off += (size_t)EE;
    float* gef   = ws + off; off += (size_t)EE * 8;
    float* gy1   = ws + off; off += (size_t)EE * 3;
    float* s     = ws + off; off += (size_t)NN * KK;
    float* su1   = ws + off; off += (size_t)NN * KK;
    float* s1    = ws + off; off += (size_t)NN * KK;
    float* s1u2  = ws + off; off += (size_t)NN * KK;
    float* s2    = ws + off; off += (size_t)NN * KK;
    float* g_s2  = ws + off; off += (size_t)NN * KK;
    float* g_s1  = ws + off; off += (size_t)NN * KK;
    float* v1    = ws + off; off += (size_t)NN * KK * 3;   // later g_v1
    float* vup   = ws + off; off += (size_t)NN * KK * 3;
    float* A0    = ws + off; off += (size_t)NN * KK;       // later g_A0
    float* A2    = ws + off; off += (size_t)NN * KK;       // later g_A2
    float* Gsj2  = ws + off; off += (size_t)NN * KK;
    float* A1    = ws + off; off += (size_t)NN * KK * 3;   // later g_A1
    float* Gvj   = ws + off; off += (size_t)NN * KK * 3;
    // int region (8B aligned: off is even)
    int* ip = (int*)(ws + off);
    size_t ioff = 0;
    int* deg_r = ip + ioff; ioff += NN;
    int* deg_s = ip + ioff; ioff += NN;
    int* cur_r = ip + ioff; ioff += NN;
    int* cur_s = ip + ioff; ioff += NN;
    int* row_r = ip + ioff; ioff += NN + 2;
    int* row_s = ip + ioff; ioff += NN + 2;
    int2* list_r = (int2*)(ip + ioff); ioff += (size_t)EE * 2;
    int2* list_s = (int2*)(ip + ioff); ioff += (size_t)EE * 2;

    hipMemsetAsync(out, 0, (size_t)out_size * sizeof(float), stream);
    hipMemsetAsync(deg_r, 0, (size_t)4 * NN * sizeof(int), stream);  // deg_r,deg_s,cur_r,cur_s

    // ---- CSR build + geometry ----
    k_edge_geom<<<(EE + 255) / 256, 256, 0, stream>>>(positions, shifts, edge_index, ef, defdr, Y1, rr);
    k_hist<<<(EE + 255) / 256, 256, 0, stream>>>(edge_index, deg_r, deg_s);
    k_scan<<<1, 1024, 0, stream>>>(deg_r, deg_s, row_r, row_s);
    k_fill<<<(EE + 255) / 256, 256, 0, stream>>>(edge_index, row_r, row_s, cur_r, cur_s, list_r, list_s);
    // ---- forward ----
    k_embed<<<(NN * KK + 255) / 256, 256, 0, stream>>>(node_z, batch, W_embed, atomic_e, s, out);
    k_gemm<0><<<512, 256, 0, stream>>>(s, W_up1, su1, NN, 1.f, 0);
    k_edge1_g<<<(NN + 3) / 4, 256, 0, stream>>>(ef, Y1, R1, su1, row_r, list_r, A0, A1);
    k_gemm<0><<<512, 256, 0, stream>>>(A0, W_mix_s1, s1, NN, INV_AVG, 0);
    k_skip_fwd<<<512, 256, 0, stream>>>(s, W_sk_s1, node_z, s1);
    k_gemm<0><<<512, 256, 0, stream>>>(A1, W_mix_v1, v1, NN * 3, INV_AVG, 0);
    k_e1<<<256, 256, 0, stream>>>(s1, w_r1, batch, out);
    k_gemm<0><<<512, 256, 0, stream>>>(s1, W_up2s, s1u2, NN, 1.f, 0);
    k_gemm<0><<<512, 256, 0, stream>>>(v1, W_up2v, vup, NN * 3, 1.f, 0);
    k_edge2_g<<<(NN + 3) / 4, 256, 0, stream>>>(ef, Y1, R2, s1u2, vup, row_r, list_r, A2);
    k_gemm<0><<<512, 256, 0, stream>>>(A2, W_mix_s2, s2, NN, INV_AVG, 0);
    k_skip_fwd<<<512, 256, 0, stream>>>(s1, W_sk_s2, node_z, s2);
    // ---- energy head + backward seed ----
    k_mlp<<<NN, 128, 0, stream>>>(s2, W_mlp, w_out, w_r1, batch, out, g_s2, g_s1);
    // ---- backward ----
    k_gemm<1><<<512, 256, 0, stream>>>(g_s2, W_mix_s2, A2, NN, INV_AVG, 0);       // g_A2 (reuses A2)
    k_skip_bwd<<<512, 256, 0, stream>>>(g_s2, W_sk_s2, node_z, g_s1);
    k_bwdA_g<<<(NN + 3) / 4, 256, 0, stream>>>(ef, Y1, R2, A2, s1u2, vup, row_s, list_s, Gsj2, Gvj, gef, gy1);
    k_gemm<1><<<512, 256, 0, stream>>>(Gsj2, W_up2s, g_s1, NN, 1.f, 1);
    k_gemm<1><<<512, 256, 0, stream>>>(Gvj, W_up2v, v1, NN * 3, 1.f, 0);          // g_v1 (reuses v1)
    k_gemm<1><<<512, 256, 0, stream>>>(v1, W_mix_v1, A1, NN * 3, INV_AVG, 0);     // g_A1 (reuses A1)
    k_gemm<1><<<512, 256, 0, stream>>>(g_s1, W_mix_s1, A0, NN, INV_AVG, 0);       // g_A0 (reuses A0)
    k_bwdB_g<<<(NN + 3) / 4, 256, 0, stream>>>(ef, Y1, R1, su1, A0, A1, row_r, list_r, gef, gy1);
    k_force<<<(EE + 255) / 256, 256, 0, stream>>>(gef, defdr, gy1, Y1, rr, edge_index, out + GG + GG * 3);
}

// Round 3
// 1646.391 us; speedup vs baseline: 1.3208x; 1.1855x over previous
//
#include <hip/hip_runtime.h>
#include <math.h>

#define NN 10000
#define EE 160000
#define KK 128
#define GG 16
#define SQ3F 1.7320508075688772f
#define INV_SQ3 0.57735026918962576f
#define INV_AVG 0.0625f
#define RMAXI 0.2f

__device__ __forceinline__ void atomAddF(float* p, float v) { unsafeAtomicAdd(p, v); }

__device__ __forceinline__ float waveRed(float v) {
#pragma unroll
    for (int m = 32; m >= 1; m >>= 1) v += __shfl_xor(v, m);
    return v;
}

// ---------------- edge geometry ----------------
__global__ void k_edge_geom(const float* __restrict__ pos, const float* __restrict__ shifts,
                            const int* __restrict__ ei,
                            float* __restrict__ ef, float* __restrict__ defdr,
                            float* __restrict__ Y1, float* __restrict__ rr) {
    int e = blockIdx.x * blockDim.x + threadIdx.x;
    if (e >= EE) return;
    int sn = ei[e], rv = ei[EE + e];
    float vx = pos[rv*3+0] - pos[sn*3+0] + shifts[e*3+0];
    float vy = pos[rv*3+1] - pos[sn*3+1] + shifts[e*3+1];
    float vz = pos[rv*3+2] - pos[sn*3+2] + shifts[e*3+2];
    float r = sqrtf(vx*vx + vy*vy + vz*vz + 1e-12f);
    float ir = 1.0f / r;
    rr[e] = r;
    Y1[e*3+0] = SQ3F*vx*ir; Y1[e*3+1] = SQ3F*vy*ir; Y1[e*3+2] = SQ3F*vz*ir;
    float x = r * RMAXI;
    float fc = 0.f, dfc = 0.f;
    if (x < 1.0f) {
        float x2 = x*x, x4 = x2*x2, x5 = x4*x, x6 = x5*x, x7 = x6*x;
        fc  = 1.0f - 21.0f*x5 + 35.0f*x6 - 15.0f*x7;
        dfc = (-105.0f*x4 + 210.0f*x5 - 105.0f*x6) * RMAXI;
    }
    const float C = 0.63245553203367587f; // sqrt(2/5)
    float4 efa, efb4, da, db;
    float* efp = (float*)&efa; float* dp = (float*)&da;
#pragma unroll
    for (int b = 0; b < 8; b++) {
        float kb = (float)(b + 1) * 0.62831853071795865f; // (b+1)*pi/5
        float sb, cb;
        sincosf(kb * r, &sb, &cb);
        float bess  = C * sb * ir;
        float dbess = C * ir * (kb * cb - sb * ir);
        if (b == 4) { efp = (float*)&efb4; dp = (float*)&db; }
        efp[b & 3] = bess * fc;
        dp[b & 3]  = dbess * fc + bess * dfc;
    }
    ((float4*)ef)[e*2]      = efa; ((float4*)ef)[e*2+1]    = efb4;
    ((float4*)defdr)[e*2]   = da;  ((float4*)defdr)[e*2+1] = db;
}

// ---------------- CSR build ----------------
__global__ void k_hist(const int* __restrict__ ei, int* __restrict__ deg_r, int* __restrict__ deg_s) {
    int e = blockIdx.x * blockDim.x + threadIdx.x;
    if (e >= EE) return;
    atomicAdd(&deg_s[ei[e]], 1);
    atomicAdd(&deg_r[ei[EE + e]], 1);
}

__global__ __launch_bounds__(1024) void k_scan(const int* __restrict__ deg_r, const int* __restrict__ deg_s,
                                               int* __restrict__ row_r, int* __restrict__ row_s) {
    __shared__ int part[1024];
    int t = threadIdx.x;
    for (int a = 0; a < 2; a++) {
        const int* deg = a ? deg_s : deg_r;
        int* row = a ? row_s : row_r;
        int base = t * 10;
        int loc[10];
        int s = 0;
#pragma unroll
        for (int k = 0; k < 10; k++) {
            loc[k] = s;
            if (base + k < NN) s += deg[base + k];
        }
        part[t] = s;
        __syncthreads();
        for (int off = 1; off < 1024; off <<= 1) {
            int v = (t >= off) ? part[t - off] : 0;
            __syncthreads();
            part[t] += v;
            __syncthreads();
        }
        int bex = (t > 0) ? part[t - 1] : 0;
#pragma unroll
        for (int k = 0; k < 10; k++)
            if (base + k < NN) row[base + k] = bex + loc[k];
        if (t == 1023) row[NN] = part[1023];
        __syncthreads();
    }
}

__global__ void k_fill(const int* __restrict__ ei, const int* __restrict__ row_r, const int* __restrict__ row_s,
                       int* __restrict__ cur_r, int* __restrict__ cur_s,
                       int2* __restrict__ list_r, int2* __restrict__ list_s) {
    int e = blockIdx.x * blockDim.x + threadIdx.x;
    if (e >= EE) return;
    int sn = ei[e], rv = ei[EE + e];
    int pr = atomicAdd(&cur_r[rv], 1);
    list_r[row_r[rv] + pr] = make_int2(e, sn);
    int ps = atomicAdd(&cur_s[sn], 1);
    list_s[row_s[sn] + ps] = make_int2(e, rv);
}

// ---------------- z-tables: E1 = W_embed@W_up1, T1 = per-z skip1 of embed ----------------
__global__ void k_tables(const float* __restrict__ We, const float* __restrict__ Wup1,
                         const float* __restrict__ Wsk1, float* __restrict__ E1, float* __restrict__ T1) {
    int zz = blockIdx.x, d = threadIdx.x;
    float a = 0.f, bv = 0.f;
    for (int c = 0; c < KK; c++) {
        float w = We[zz*KK + c];
        a  += w * Wup1[c*KK + d];
        bv += w * Wsk1[(size_t)(zz*KK + c)*KK + d];
    }
    E1[zz*KK + d] = a;
    T1[zz*KK + d] = bv;
}

__global__ void k_zinit(float* __restrict__ out, const float* __restrict__ tab, const int* __restrict__ z) {
    int i = blockIdx.x * blockDim.x + threadIdx.x;
    if (i >= NN * KK) return;
    out[i] = tab[z[i >> 7] * KK + (i & 127)];
}

// ---------------- e0 ----------------
__global__ void k_e0(const int* __restrict__ z, const int* __restrict__ batch,
                     const float* __restrict__ ae, float* __restrict__ out) {
    int n = blockIdx.x * blockDim.x + threadIdx.x;
    if (n >= NN) return;
    float v = ae[z[n]];
    int b = batch[n];
    atomAddF(&out[b], v);
    atomAddF(&out[GG + b*3 + 0], v);
}

// ---------------- K x K GEMM, 4 outputs/thread sharing LDS reads ----------------
// rows must be a multiple of 8 in all call sites (10000, 30000, 128 all are... grid = rows/8)
template <int TRANS>
__global__ __launch_bounds__(256) void k_gemm(const float* __restrict__ in, const float* __restrict__ W,
                                              float* __restrict__ out, int rows, float alpha, int accum) {
    __shared__ float WL[KK * KK];
    int t = threadIdx.x;
    int lane = t & 127, slot = t >> 7;
    for (int a = slot; a < KK; a += 2) {
        float v = W[a * KK + lane];
        if (!TRANS) WL[a * KK + ((a + lane) & 127)] = v;
        else        WL[lane * KK + ((lane + a) & 127)] = v;
    }
    __syncthreads();
    int r0 = blockIdx.x * 8 + slot * 4;
    if (r0 >= rows) return;
    const float4* p0 = (const float4*)(in + (size_t)r0 * KK);
    const float4* p1 = (const float4*)(in + (size_t)(r0 + 1) * KK);
    const float4* p2 = (const float4*)(in + (size_t)(r0 + 2) * KK);
    const float4* p3 = (const float4*)(in + (size_t)(r0 + 3) * KK);
    float a0 = 0.f, a1 = 0.f, a2 = 0.f, a3 = 0.f;
#pragma unroll 4
    for (int i0 = 0; i0 < KK; i0 += 4) {
        float4 x0 = p0[i0 >> 2], x1 = p1[i0 >> 2], x2 = p2[i0 >> 2], x3 = p3[i0 >> 2];
#pragma unroll
        for (int k = 0; k < 4; k++) {
            float wv = WL[(i0 + k) * KK + ((i0 + k + lane) & 127)];
            a0 += ((const float*)&x0)[k] * wv;
            a1 += ((const float*)&x1)[k] * wv;
            a2 += ((const float*)&x2)[k] * wv;
            a3 += ((const float*)&x3)[k] * wv;
        }
    }
    a0 *= alpha; a1 *= alpha; a2 *= alpha; a3 *= alpha;
    float* o = out + (size_t)r0 * KK + lane;
    if (accum) {
        o[0] += a0; o[KK] += a1; o[2*KK] += a2; o[3*KK] += a3;
    } else {
        o[0] = a0; o[KK] = a1; o[2*KK] = a2; o[3*KK] = a3;
    }
}

// ---------------- per-z skip layer2 (writes) ----------------
__global__ __launch_bounds__(256) void k_skip_fwd(const float* __restrict__ in, const float* __restrict__ Wall,
                                                  const int* __restrict__ z, float* __restrict__ out) {
    int wv = (blockIdx.x * 256 + threadIdx.x) >> 6;
    int lane = threadIdx.x & 63;
    int nw = gridDim.x * 4;
    for (int n = wv; n < NN; n += nw) {
        const float* Wz = Wall + (size_t)z[n] * (KK * KK);
        const float* inr = in + (size_t)n * KK;
        float a0 = 0.f, a1 = 0.f;
        for (int c = 0; c < KK; c++) {
            float v = inr[c];
            a0 += v * Wz[c * KK + lane];
            a1 += v * Wz[c * KK + 64 + lane];
        }
        out[n * KK + lane] = a0;
        out[n * KK + 64 + lane] = a1;
    }
}

__global__ __launch_bounds__(256) void k_skip_bwd(const float* __restrict__ gin, const float* __restrict__ Wall,
                                                  const int* __restrict__ z, float* __restrict__ gout) {
    int wv = (blockIdx.x * 256 + threadIdx.x) >> 6;
    int lane = threadIdx.x & 63;
    int nw = gridDim.x * 4;
    for (int n = wv; n < NN; n += nw) {
        const float* Wz = Wall + (size_t)z[n] * (KK * KK);
        const float4* g4 = (const float4*)(gin + (size_t)n * KK);
        const float4* w0 = (const float4*)(Wz + lane * KK);
        const float4* w1 = (const float4*)(Wz + (64 + lane) * KK);
        float a0 = 0.f, a1 = 0.f;
#pragma unroll 8
        for (int d0 = 0; d0 < 32; d0++) {
            float4 g = g4[d0];
            float4 u = w0[d0]; a0 += g.x*u.x + g.y*u.y + g.z*u.z + g.w*u.w;
            float4 w = w1[d0]; a1 += g.x*w.x + g.y*w.y + g.z*w.z + g.w*w.w;
        }
        gout[n * KK + lane] += a0;
        gout[n * KK + 64 + lane] += a1;
    }
}

// ---------------- e1 ----------------
__global__ __launch_bounds__(256) void k_e1(const float* __restrict__ s1, const float* __restrict__ w_r1,
                                            const int* __restrict__ batch, float* __restrict__ out) {
    int wv = (blockIdx.x * 256 + threadIdx.x) >> 6;
    int lane = threadIdx.x & 63;
    int nw = gridDim.x * 4;
    for (int n = wv; n < NN; n += nw) {
        float a = s1[n*KK + lane] * w_r1[lane] + s1[n*KK + 64 + lane] * w_r1[64 + lane];
        a = waveRed(a);
        if (lane == 0) {
            int b = batch[n];
            atomAddF(&out[b], a);
            atomAddF(&out[GG + b*3 + 1], a);
        }
    }
}

// ---------------- edge pass 1 (rcv-centric gather): A0[n], A1[n] ----------------
__global__ __launch_bounds__(256) void k_edge1_g(const float* __restrict__ ef, const float* __restrict__ Y1,
                                                 const float* __restrict__ R1, const float* __restrict__ su1,
                                                 const int* __restrict__ row_r, const int2* __restrict__ list_r,
                                                 float* __restrict__ A0, float* __restrict__ A1) {
    __shared__ float RL[2048];
    for (int i = threadIdx.x; i < 2048; i += 256) RL[i] = R1[i];
    __syncthreads();
    int lane = threadIdx.x & 63;
    int n = blockIdx.x * 4 + (threadIdx.x >> 6);
    if (n >= NN) return;
    int c0 = lane, c1 = lane + 64;
    float a00 = 0.f, a01 = 0.f;
    float ax0 = 0.f, ax1 = 0.f, ay0 = 0.f, ay1 = 0.f, az0 = 0.f, az1 = 0.f;
    int beg = row_r[n], end = row_r[n + 1];
    for (int i = beg; i < end; i++) {
        int2 p = list_r[i];
        int e = p.x, sn = p.y;
        float4 efa = ((const float4*)ef)[e*2], efb4 = ((const float4*)ef)[e*2+1];
        float y0 = Y1[e*3+0], y1 = Y1[e*3+1], y2 = Y1[e*3+2];
        float wa0 = 0, wa1 = 0, wb0 = 0, wb1 = 0;
        const float* eb = (const float*)&efa;
#pragma unroll
        for (int b = 0; b < 8; b++) {
            if (b == 4) eb = (const float*)&efb4;
            float v = eb[b & 3];
            wa0 += v * RL[b*256 + c0];       wb0 += v * RL[b*256 + 128 + c0];
            wa1 += v * RL[b*256 + c1];       wb1 += v * RL[b*256 + 128 + c1];
        }
        float sj0 = su1[sn*KK + c0], sj1 = su1[sn*KK + c1];
        a00 += wa0 * sj0; a01 += wa1 * sj1;
        float mb0 = wb0 * sj0, mb1 = wb1 * sj1;
        ax0 += mb0*y0; ax1 += mb1*y0;
        ay0 += mb0*y1; ay1 += mb1*y1;
        az0 += mb0*y2; az1 += mb1*y2;
    }
    A0[(size_t)n*KK + c0] = a00;  A0[(size_t)n*KK + c1] = a01;
    float* A1r = A1 + (size_t)n * 384;
    A1r[c0] = ax0;        A1r[c1] = ax1;
    A1r[128 + c0] = ay0;  A1r[128 + c1] = ay1;
    A1r[256 + c0] = az0;  A1r[256 + c1] = az1;
}

// ---------------- edge pass 2 (rcv-centric gather): A2[n] ----------------
__global__ __launch_bounds__(256) void k_edge2_g(const float* __restrict__ ef, const float* __restrict__ Y1,
                                                 const float* __restrict__ R2, const float* __restrict__ s1u2,
                                                 const float* __restrict__ vup,
                                                 const int* __restrict__ row_r, const int2* __restrict__ list_r,
                                                 float* __restrict__ A2) {
    __shared__ float RL[2048];
    for (int i = threadIdx.x; i < 2048; i += 256) RL[i] = R2[(i >> 8) * 512 + (i & 255)];
    __syncthreads();
    int lane = threadIdx.x & 63;
    int n = blockIdx.x * 4 + (threadIdx.x >> 6);
    if (n >= NN) return;
    int c0 = lane, c1 = lane + 64;
    float a0 = 0.f, a1 = 0.f;
    int beg = row_r[n], end = row_r[n + 1];
    for (int i = beg; i < end; i++) {
        int2 p = list_r[i];
        int e = p.x, sn = p.y;
        float4 efa = ((const float4*)ef)[e*2], efb4 = ((const float4*)ef)[e*2+1];
        float y0 = Y1[e*3+0], y1 = Y1[e*3+1], y2 = Y1[e*3+2];
        float w00_0 = 0, w00_1 = 0, w110_0 = 0, w110_1 = 0;
        const float* eb = (const float*)&efa;
#pragma unroll
        for (int b = 0; b < 8; b++) {
            if (b == 4) eb = (const float*)&efb4;
            float v = eb[b & 3];
            w00_0  += v * RL[b*256 + c0];      w110_0 += v * RL[b*256 + 128 + c0];
            w00_1  += v * RL[b*256 + c1];      w110_1 += v * RL[b*256 + 128 + c1];
        }
        float sj0 = s1u2[sn*KK + c0], sj1 = s1u2[sn*KK + c1];
        const float* vu = vup + (size_t)sn * 384;
        float tt0 = (vu[c0]*y0 + vu[128 + c0]*y1 + vu[256 + c0]*y2) * INV_SQ3;
        float tt1 = (vu[c1]*y0 + vu[128 + c1]*y1 + vu[256 + c1]*y2) * INV_SQ3;
        a0 += w00_0 * sj0 + w110_0 * tt0;
        a1 += w00_1 * sj1 + w110_1 * tt1;
    }
    A2[(size_t)n*KK + c0] = a0;
    A2[(size_t)n*KK + c1] = a1;
}

// ---------------- MLP energy + backward seed ----------------
__global__ __launch_bounds__(128) void k_mlp(const float* __restrict__ s2, const float* __restrict__ W_mlp,
                                             const float* __restrict__ w_out, const float* __restrict__ w_r1,
                                             const int* __restrict__ batch,
                                             float* __restrict__ out, float* __restrict__ g_s2,
                                             float* __restrict__ g_s1) {
    __shared__ float WmL[KK * 17];
    __shared__ float s2L[KK];
    __shared__ float ghL[16];
    __shared__ float eL[16];
    int n = blockIdx.x, t = threadIdx.x;
    for (int i = t; i < KK * 16; i += 128) WmL[(i >> 4) * 17 + (i & 15)] = W_mlp[i];
    s2L[t] = s2[(size_t)n * KK + t];
    __syncthreads();
    if (t < 16) {
        float h = 0.f;
        for (int c = 0; c < KK; c++) h += s2L[c] * WmL[c * 17 + t];
        float sg = 1.f / (1.f + expf(-h));
        eL[t]  = h * sg * w_out[t];
        ghL[t] = w_out[t] * sg * (1.f + h * (1.f - sg));
    }
    __syncthreads();
    if (t == 0) {
        float e = 0.f;
#pragma unroll
        for (int j = 0; j < 16; j++) e += eL[j];
        int b = batch[n];
        atomAddF(&out[b], e);
        atomAddF(&out[GG + b*3 + 2], e);
    }
    float g = 0.f;
#pragma unroll
    for (int j = 0; j < 16; j++) g += ghL[j] * WmL[t * 17 + j];
    g_s2[(size_t)n * KK + t] = g;
    g_s1[(size_t)n * KK + t] = w_r1[t];
}

// ---------------- backward layer2, per-edge outputs (lane = edge, no cross-lane ops) ----------------
__global__ __launch_bounds__(256) void k_bwdA_e(const float* __restrict__ ef8, const float* __restrict__ Y1,
                                                const int* __restrict__ ei, const float* __restrict__ R2,
                                                const float* __restrict__ gA2, const float* __restrict__ s1u2,
                                                const float* __restrict__ vup, const int2* __restrict__ list_s,
                                                float* __restrict__ gefA, float* __restrict__ gyA) {
    int i = blockIdx.x * 256 + threadIdx.x;
    if (i >= EE) return;
    int2 p = list_s[i];
    int e = p.x, rv = p.y;
    int sn = ei[e];
    float y0 = Y1[e*3+0], y1 = Y1[e*3+1], y2 = Y1[e*3+2];
    float4 efa = ((const float4*)ef8)[e*2], efb = ((const float4*)ef8)[e*2+1];
    float efv[8] = {efa.x, efa.y, efa.z, efa.w, efb.x, efb.y, efb.z, efb.w};
    float acc[8] = {0,0,0,0,0,0,0,0};
    float g0 = 0.f, g1 = 0.f, g2 = 0.f;
    const float4* gaR = (const float4*)(gA2 + (size_t)rv * KK);
    const float4* sjR = (const float4*)(s1u2 + (size_t)sn * KK);
    const float4* vxR = (const float4*)(vup + (size_t)sn * 384);
    const float4* vyR = vxR + 32;
    const float4* vzR = vxR + 64;
    for (int cc = 0; cc < 32; cc++) {
        float4 ga = gaR[cc], sj = sjR[cc], vx = vxR[cc], vy = vyR[cc], vz = vzR[cc];
#pragma unroll
        for (int k = 0; k < 4; k++) {
            float gaE = ((const float*)&ga)[k];
            float sjE = ((const float*)&sj)[k];
            float vxE = ((const float*)&vx)[k];
            float vyE = ((const float*)&vy)[k];
            float vzE = ((const float*)&vz)[k];
            float tt = (vxE*y0 + vyE*y1 + vzE*y2) * INV_SQ3;
            float gw00 = gaE * sjE;
            float gw110 = gaE * tt;
            float w110 = 0.f;
            int c = cc*4 + k;
#pragma unroll
            for (int b = 0; b < 8; b++) {
                float r2a = R2[b*512 + c];         // wave-uniform -> s_load broadcast
                float r2b = R2[b*512 + 128 + c];
                acc[b] += gw00 * r2a + gw110 * r2b;
                w110 += efv[b] * r2b;
            }
            float gt = gaE * w110;
            g0 += gt * vxE; g1 += gt * vyE; g2 += gt * vzE;
        }
    }
    float4 o0 = make_float4(acc[0], acc[1], acc[2], acc[3]);
    float4 o1 = make_float4(acc[4], acc[5], acc[6], acc[7]);
    ((float4*)gefA)[e*2] = o0; ((float4*)gefA)[e*2+1] = o1;
    gyA[e*3+0] = g0 * INV_SQ3; gyA[e*3+1] = g1 * INV_SQ3; gyA[e*3+2] = g2 * INV_SQ3;
}

// ---------------- backward layer2, node sums Gsj2/Gvj (snd-centric, no waveRed) ----------------
__global__ __launch_bounds__(256) void k_bwdA_n(const float* __restrict__ ef, const float* __restrict__ Y1,
                                                const float* __restrict__ R2, const float* __restrict__ gA2,
                                                const int* __restrict__ row_s, const int2* __restrict__ list_s,
                                                float* __restrict__ Gsj2, float* __restrict__ Gvj) {
    __shared__ float RL[2048];
    for (int i = threadIdx.x; i < 2048; i += 256) RL[i] = R2[(i >> 8) * 512 + (i & 255)];
    __syncthreads();
    int lane = threadIdx.x & 63;
    int sn = blockIdx.x * 4 + (threadIdx.x >> 6);
    if (sn >= NN) return;
    int c0 = lane, c1 = lane + 64;
    float gs0 = 0.f, gs1 = 0.f;
    float gv00 = 0.f, gv01 = 0.f, gv10 = 0.f, gv11 = 0.f, gv20 = 0.f, gv21 = 0.f;
    int beg = row_s[sn], end = row_s[sn + 1];
    for (int i = beg; i < end; i++) {
        int2 p = list_s[i];
        int e = p.x, rv = p.y;
        float4 efa = ((const float4*)ef)[e*2], efb4 = ((const float4*)ef)[e*2+1];
        float y0 = Y1[e*3+0], y1 = Y1[e*3+1], y2 = Y1[e*3+2];
        float w00_0 = 0, w00_1 = 0, w110_0 = 0, w110_1 = 0;
        const float* eb = (const float*)&efa;
#pragma unroll
        for (int b = 0; b < 8; b++) {
            if (b == 4) eb = (const float*)&efb4;
            float v = eb[b & 3];
            w00_0  += v * RL[b*256 + c0];      w110_0 += v * RL[b*256 + 128 + c0];
            w00_1  += v * RL[b*256 + c1];      w110_1 += v * RL[b*256 + 128 + c1];
        }
        float ga0 = gA2[(size_t)rv*KK + c0], ga1 = gA2[(size_t)rv*KK + c1];
        gs0 += ga0 * w00_0;
        gs1 += ga1 * w00_1;
        float gts0 = ga0 * w110_0 * INV_SQ3, gts1 = ga1 * w110_1 * INV_SQ3;
        gv00 += gts0*y0; gv01 += gts1*y0;
        gv10 += gts0*y1; gv11 += gts1*y1;
        gv20 += gts0*y2; gv21 += gts1*y2;
    }
    Gsj2[(size_t)sn*KK + c0] = gs0; Gsj2[(size_t)sn*KK + c1] = gs1;
    float* Gv = Gvj + (size_t)sn * 384;
    Gv[c0] = gv00;        Gv[c1] = gv01;
    Gv[128 + c0] = gv10;  Gv[128 + c1] = gv11;
    Gv[256 + c0] = gv20;  Gv[256 + c1] = gv21;
}

// ---------------- backward layer1, per-edge outputs (lane = edge) ----------------
__global__ __launch_bounds__(256) void k_bwdB_e(const float* __restrict__ ef8, const float* __restrict__ Y1,
                                                const int* __restrict__ ei, const float* __restrict__ R1,
                                                const float* __restrict__ su1, const float* __restrict__ gA0,
                                                const float* __restrict__ gA1, const int2* __restrict__ list_r,
                                                float* __restrict__ gefB, float* __restrict__ gyB) {
    int i = blockIdx.x * 256 + threadIdx.x;
    if (i >= EE) return;
    int2 p = list_r[i];
    int e = p.x, sn = p.y;
    int rv = ei[EE + e];
    float y0 = Y1[e*3+0], y1 = Y1[e*3+1], y2 = Y1[e*3+2];
    float4 efa = ((const float4*)ef8)[e*2], efb = ((const float4*)ef8)[e*2+1];
    float efv[8] = {efa.x, efa.y, efa.z, efa.w, efb.x, efb.y, efb.z, efb.w};
    float acc[8] = {0,0,0,0,0,0,0,0};
    float gg0 = 0.f, gg1 = 0.f, gg2 = 0.f;
    const float4* gmR = (const float4*)(gA0 + (size_t)rv * KK);
    const float4* sjR = (const float4*)(su1 + (size_t)sn * KK);
    const float4* gxR = (const float4*)(gA1 + (size_t)rv * 384);
    const float4* gyR = gxR + 32;
    const float4* gzR = gxR + 64;
    for (int cc = 0; cc < 32; cc++) {
        float4 gm = gmR[cc], sj = sjR[cc], gx = gxR[cc], gy = gyR[cc], gz = gzR[cc];
#pragma unroll
        for (int k = 0; k < 4; k++) {
            float gmE = ((const float*)&gm)[k];
            float sjE = ((const float*)&sj)[k];
            float g1E = ((const float*)&gx)[k];
            float g2E = ((const float*)&gy)[k];
            float g3E = ((const float*)&gz)[k];
            float q = g1E*y0 + g2E*y1 + g3E*y2;
            float gwa = gmE * sjE;
            float gwb = q * sjE;
            float w = 0.f;
            int c = cc*4 + k;
#pragma unroll
            for (int b = 0; b < 8; b++) {
                float r1a = R1[b*256 + c];
                float r1b = R1[b*256 + 128 + c];
                acc[b] += gwa * r1a + gwb * r1b;
                w += efv[b] * r1b;
            }
            float ws = w * sjE;
            gg0 += g1E * ws; gg1 += g2E * ws; gg2 += g3E * ws;
        }
    }
    float4 o0 = make_float4(acc[0], acc[1], acc[2], acc[3]);
    float4 o1 = make_float4(acc[4], acc[5], acc[6], acc[7]);
    ((float4*)gefB)[e*2] = o0; ((float4*)gefB)[e*2+1] = o1;
    gyB[e*3+0] = gg0; gyB[e*3+1] = gg1; gyB[e*3+2] = gg2;
}

// ---------------- final: per-edge g_vec -> forces ----------------
__global__ void k_force(const float* __restrict__ gefA, const float* __restrict__ gefB,
                        const float* __restrict__ defdr,
                        const float* __restrict__ gyA, const float* __restrict__ gyB,
                        const float* __restrict__ Y1,
                        const float* __restrict__ rr, const int* __restrict__ ei,
                        float* __restrict__ forces) {
    int e = blockIdx.x * blockDim.x + threadIdx.x;
    if (e >= EE) return;
    float gr = 0.f;
#pragma unroll
    for (int b = 0; b < 8; b++) gr += (gefA[e*8+b] + gefB[e*8+b]) * defdr[e*8+b];
    float y0 = Y1[e*3+0], y1 = Y1[e*3+1], y2 = Y1[e*3+2];
    float g0 = gyA[e*3+0] + gyB[e*3+0];
    float g1 = gyA[e*3+1] + gyB[e*3+1];
    float g2 = gyA[e*3+2] + gyB[e*3+2];
    float ir = 1.f / rr[e];
    float dot = g0*y0 + g1*y1 + g2*y2;
    float a = gr * INV_SQ3;
    float b2 = SQ3F * ir;
    float c = b2 * dot * (1.f / 3.f);
    float gv0 = a*y0 + b2*g0 - c*y0;
    float gv1 = a*y1 + b2*g1 - c*y1;
    float gv2 = a*y2 + b2*g2 - c*y2;
    int sn = ei[e], rv = ei[EE + e];
    atomAddF(&forces[rv*3+0], -gv0); atomAddF(&forces[rv*3+1], -gv1); atomAddF(&forces[rv*3+2], -gv2);
    atomAddF(&forces[sn*3+0],  gv0); atomAddF(&forces[sn*3+1],  gv1); atomAddF(&forces[sn*3+2],  gv2);
}

extern "C" void kernel_launch(void* const* d_in, const int* in_sizes, int n_in,
                              void* d_out, int out_size, void* d_ws, size_t ws_size,
                              hipStream_t stream) {
    const float* positions  = (const float*)d_in[0];
    const float* shifts     = (const float*)d_in[1];
    const int*   edge_index = (const int*)d_in[2];
    const int*   node_z     = (const int*)d_in[3];
    const int*   batch      = (const int*)d_in[4];
    const float* atomic_e   = (const float*)d_in[5];
    const float* W_embed    = (const float*)d_in[6];
    const float* R1         = (const float*)d_in[7];
    const float* W_up1      = (const float*)d_in[8];
    const float* W_mix_s1   = (const float*)d_in[9];
    const float* W_mix_v1   = (const float*)d_in[10];
    const float* W_sk_s1    = (const float*)d_in[11];
    const float* w_r1       = (const float*)d_in[12];
    const float* R2         = (const float*)d_in[13];
    const float* W_up2s     = (const float*)d_in[14];
    const float* W_up2v     = (const float*)d_in[15];
    const float* W_mix_s2   = (const float*)d_in[16];
    const float* W_sk_s2    = (const float*)d_in[17];
    const float* W_mlp      = (const float*)d_in[18];
    const float* w_out      = (const float*)d_in[19];

    float* out = (float*)d_out;
    float* ws = (float*)d_ws;
    size_t off = 0;
    float* ef    = ws + off; off += (size_t)EE * 8;
    float* defdr = ws + off; off += (size_t)EE * 8;
    float* Y1    = ws + off; off += (size_t)EE * 3;
    float* rr    = ws + off; off += (size_t)EE;
    float* gefA  = ws + off; off += (size_t)EE * 8;
    float* gyA   = ws + off; off += (size_t)EE * 3;
    float* gefB  = ws + off; off += (size_t)EE * 8;
    float* gyB   = ws + off; off += (size_t)EE * 3;
    float* su1   = ws + off; off += (size_t)NN * KK;
    float* s1    = ws + off; off += (size_t)NN * KK;
    float* s1u2  = ws + off; off += (size_t)NN * KK;
    float* s2    = ws + off; off += (size_t)NN * KK;
    float* g_s2  = ws + off; off += (size_t)NN * KK;
    float* g_s1  = ws + off; off += (size_t)NN * KK;
    float* vup   = ws + off; off += (size_t)NN * KK * 3;
    float* A0    = ws + off; off += (size_t)NN * KK;       // later g_A0
    float* A2    = ws + off; off += (size_t)NN * KK;       // later g_A2
    float* Gsj2  = ws + off; off += (size_t)NN * KK;
    float* A1    = ws + off; off += (size_t)NN * KK * 3;   // later g_A1
    float* Gvj   = ws + off; off += (size_t)NN * KK * 3;
    float* E1    = ws + off; off += 10 * KK;
    float* T1    = ws + off; off += 10 * KK;
    float* Wc    = ws + off; off += KK * KK;
    // int region (8B aligned: off is even)
    int* ip = (int*)(ws + off);
    size_t ioff = 0;
    int* deg_r = ip + ioff; ioff += NN;
    int* deg_s = ip + ioff; ioff += NN;
    int* cur_r = ip + ioff; ioff += NN;
    int* cur_s = ip + ioff; ioff += NN;
    int* row_r = ip + ioff; ioff += NN + 2;
    int* row_s = ip + ioff; ioff += NN + 2;
    int2* list_r = (int2*)(ip + ioff); ioff += (size_t)EE * 2;
    int2* list_s = (int2*)(ip + ioff); ioff += (size_t)EE * 2;

    hipMemsetAsync(out, 0, (size_t)out_size * sizeof(float), stream);
    hipMemsetAsync(deg_r, 0, (size_t)4 * NN * sizeof(int), stream);

    // ---- CSR build + geometry + tables ----
    k_edge_geom<<<(EE + 255) / 256, 256, 0, stream>>>(positions, shifts, edge_index, ef, defdr, Y1, rr);
    k_hist<<<(EE + 255) / 256, 256, 0, stream>>>(edge_index, deg_r, deg_s);
    k_scan<<<1, 1024, 0, stream>>>(deg_r, deg_s, row_r, row_s);
    k_fill<<<(EE + 255) / 256, 256, 0, stream>>>(edge_index, row_r, row_s, cur_r, cur_s, list_r, list_s);
    k_tables<<<10, 128, 0, stream>>>(W_embed, W_up1, W_sk_s1, E1, T1);
    k_gemm<0><<<KK / 8, 256, 0, stream>>>(W_mix_v1, W_up2v, Wc, KK, 1.f, 0);   // Wc = W_mix_v1 @ W_up2v
    k_e0<<<(NN + 255) / 256, 256, 0, stream>>>(node_z, batch, atomic_e, out);
    // ---- forward ----
    k_zinit<<<(NN * KK + 255) / 256, 256, 0, stream>>>(su1, E1, node_z);
    k_edge1_g<<<(NN + 3) / 4, 256, 0, stream>>>(ef, Y1, R1, su1, row_r, list_r, A0, A1);
    k_zinit<<<(NN * KK + 255) / 256, 256, 0, stream>>>(s1, T1, node_z);
    k_gemm<0><<<NN / 8, 256, 0, stream>>>(A0, W_mix_s1, s1, NN, INV_AVG, 1);
    k_gemm<0><<<NN * 3 / 8, 256, 0, stream>>>(A1, Wc, vup, NN * 3, INV_AVG, 0);
    k_e1<<<256, 256, 0, stream>>>(s1, w_r1, batch, out);
    k_gemm<0><<<NN / 8, 256, 0, stream>>>(s1, W_up2s, s1u2, NN, 1.f, 0);
    k_edge2_g<<<(NN + 3) / 4, 256, 0, stream>>>(ef, Y1, R2, s1u2, vup, row_r, list_r, A2);
    k_skip_fwd<<<512, 256, 0, stream>>>(s1, W_sk_s2, node_z, s2);
    k_gemm<0><<<NN / 8, 256, 0, stream>>>(A2, W_mix_s2, s2, NN, INV_AVG, 1);
    // ---- energy head + backward seed ----
    k_mlp<<<NN, 128, 0, stream>>>(s2, W_mlp, w_out, w_r1, batch, out, g_s2, g_s1);
    // ---- backward ----
    k_gemm<1><<<NN / 8, 256, 0, stream>>>(g_s2, W_mix_s2, A2, NN, INV_AVG, 0);       // g_A2 -> A2
    k_skip_bwd<<<512, 256, 0, stream>>>(g_s2, W_sk_s2, node_z, g_s1);
    k_bwdA_e<<<(EE + 255) / 256, 256, 0, stream>>>(ef, Y1, edge_index, R2, A2, s1u2, vup, list_s, gefA, gyA);
    k_bwdA_n<<<(NN + 3) / 4, 256, 0, stream>>>(ef, Y1, R2, A2, row_s, list_s, Gsj2, Gvj);
    k_gemm<1><<<NN / 8, 256, 0, stream>>>(Gsj2, W_up2s, g_s1, NN, 1.f, 1);
    k_gemm<1><<<NN * 3 / 8, 256, 0, stream>>>(Gvj, Wc, A1, NN * 3, INV_AVG, 0);      // g_A1 -> A1
    k_gemm<1><<<NN / 8, 256, 0, stream>>>(g_s1, W_mix_s1, A0, NN, INV_AVG, 0);       // g_A0 -> A0
    k_bwdB_e<<<(EE + 255) / 256, 256, 0, stream>>>(ef, Y1, edge_index, R1, su1, A0, A1, list_r, gefB, gyB);
    k_force<<<(EE + 255) / 256, 256, 0, stream>>>(gefA, gefB, defdr, gyA, gyB, Y1, rr, edge_index, out + GG + GG * 3);
}

// Round 4
// 1233.976 us; speedup vs baseline: 1.7623x; 1.3342x over previous
//
#include <hip/hip_runtime.h>
#include <math.h>

#define NN 10000
#define EE 160000
#define KK 128
#define GG 16
#define SQ3F 1.7320508075688772f
#define INV_SQ3 0.57735026918962576f
#define INV_AVG 0.0625f
#define RMAXI 0.2f

__device__ __forceinline__ void atomAddF(float* p, float v) { unsafeAtomicAdd(p, v); }

__device__ __forceinline__ float waveRed(float v) {
#pragma unroll
    for (int m = 32; m >= 1; m >>= 1) v += __shfl_xor(v, m);
    return v;
}

// ---------------- edge geometry ----------------
__global__ void k_edge_geom(const float* __restrict__ pos, const float* __restrict__ shifts,
                            const int* __restrict__ ei,
                            float* __restrict__ ef, float* __restrict__ defdr,
                            float* __restrict__ Y1, float* __restrict__ rr) {
    int e = blockIdx.x * blockDim.x + threadIdx.x;
    if (e >= EE) return;
    int sn = ei[e], rv = ei[EE + e];
    float vx = pos[rv*3+0] - pos[sn*3+0] + shifts[e*3+0];
    float vy = pos[rv*3+1] - pos[sn*3+1] + shifts[e*3+1];
    float vz = pos[rv*3+2] - pos[sn*3+2] + shifts[e*3+2];
    float r = sqrtf(vx*vx + vy*vy + vz*vz + 1e-12f);
    float ir = 1.0f / r;
    rr[e] = r;
    Y1[e*3+0] = SQ3F*vx*ir; Y1[e*3+1] = SQ3F*vy*ir; Y1[e*3+2] = SQ3F*vz*ir;
    float x = r * RMAXI;
    float fc = 0.f, dfc = 0.f;
    if (x < 1.0f) {
        float x2 = x*x, x4 = x2*x2, x5 = x4*x, x6 = x5*x, x7 = x6*x;
        fc  = 1.0f - 21.0f*x5 + 35.0f*x6 - 15.0f*x7;
        dfc = (-105.0f*x4 + 210.0f*x5 - 105.0f*x6) * RMAXI;
    }
    const float C = 0.63245553203367587f; // sqrt(2/5)
    float4 efa, efb4, da, db;
    float* efp = (float*)&efa; float* dp = (float*)&da;
#pragma unroll
    for (int b = 0; b < 8; b++) {
        float kb = (float)(b + 1) * 0.62831853071795865f; // (b+1)*pi/5
        float sb, cb;
        sincosf(kb * r, &sb, &cb);
        float bess  = C * sb * ir;
        float dbess = C * ir * (kb * cb - sb * ir);
        if (b == 4) { efp = (float*)&efb4; dp = (float*)&db; }
        efp[b & 3] = bess * fc;
        dp[b & 3]  = dbess * fc + bess * dfc;
    }
    ((float4*)ef)[e*2]      = efa; ((float4*)ef)[e*2+1]    = efb4;
    ((float4*)defdr)[e*2]   = da;  ((float4*)defdr)[e*2+1] = db;
}

// ---------------- CSR build ----------------
__global__ void k_hist(const int* __restrict__ ei, int* __restrict__ deg_r, int* __restrict__ deg_s) {
    int e = blockIdx.x * blockDim.x + threadIdx.x;
    if (e >= EE) return;
    atomicAdd(&deg_s[ei[e]], 1);
    atomicAdd(&deg_r[ei[EE + e]], 1);
}

__global__ __launch_bounds__(1024) void k_scan(const int* __restrict__ deg_r, const int* __restrict__ deg_s,
                                               int* __restrict__ row_r, int* __restrict__ row_s) {
    __shared__ int part[1024];
    int t = threadIdx.x;
    for (int a = 0; a < 2; a++) {
        const int* deg = a ? deg_s : deg_r;
        int* row = a ? row_s : row_r;
        int base = t * 10;
        int loc[10];
        int s = 0;
#pragma unroll
        for (int k = 0; k < 10; k++) {
            loc[k] = s;
            if (base + k < NN) s += deg[base + k];
        }
        part[t] = s;
        __syncthreads();
        for (int off = 1; off < 1024; off <<= 1) {
            int v = (t >= off) ? part[t - off] : 0;
            __syncthreads();
            part[t] += v;
            __syncthreads();
        }
        int bex = (t > 0) ? part[t - 1] : 0;
#pragma unroll
        for (int k = 0; k < 10; k++)
            if (base + k < NN) row[base + k] = bex + loc[k];
        if (t == 1023) row[NN] = part[1023];
        __syncthreads();
    }
}

__global__ void k_fill(const int* __restrict__ ei, const int* __restrict__ row_r, const int* __restrict__ row_s,
                       int* __restrict__ cur_r, int* __restrict__ cur_s,
                       int2* __restrict__ list_r, int2* __restrict__ list_s) {
    int e = blockIdx.x * blockDim.x + threadIdx.x;
    if (e >= EE) return;
    int sn = ei[e], rv = ei[EE + e];
    int pr = atomicAdd(&cur_r[rv], 1);
    list_r[row_r[rv] + pr] = make_int2(e, sn);
    int ps = atomicAdd(&cur_s[sn], 1);
    list_s[row_s[sn] + ps] = make_int2(e, rv);
}

// ---------------- z-tables: E1 = W_embed@W_up1, T1 = per-z skip1 of embed ----------------
__global__ void k_tables(const float* __restrict__ We, const float* __restrict__ Wup1,
                         const float* __restrict__ Wsk1, float* __restrict__ E1, float* __restrict__ T1) {
    int zz = blockIdx.x, d = threadIdx.x;
    float a = 0.f, bv = 0.f;
    for (int c = 0; c < KK; c++) {
        float w = We[zz*KK + c];
        a  += w * Wup1[c*KK + d];
        bv += w * Wsk1[(size_t)(zz*KK + c)*KK + d];
    }
    E1[zz*KK + d] = a;
    T1[zz*KK + d] = bv;
}

__global__ void k_zinit(float* __restrict__ out, const float* __restrict__ tab, const int* __restrict__ z) {
    int i = blockIdx.x * blockDim.x + threadIdx.x;
    if (i >= NN * KK) return;
    out[i] = tab[z[i >> 7] * KK + (i & 127)];
}

// ---------------- K x K GEMM, 4 outputs/thread sharing LDS reads ----------------
template <int TRANS>
__global__ __launch_bounds__(256) void k_gemm(const float* __restrict__ in, const float* __restrict__ W,
                                              float* __restrict__ out, int rows, float alpha, int accum) {
    __shared__ float WL[KK * KK];
    int t = threadIdx.x;
    int lane = t & 127, slot = t >> 7;
    for (int a = slot; a < KK; a += 2) {
        float v = W[a * KK + lane];
        if (!TRANS) WL[a * KK + ((a + lane) & 127)] = v;
        else        WL[lane * KK + ((lane + a) & 127)] = v;
    }
    __syncthreads();
    int r0 = blockIdx.x * 8 + slot * 4;
    if (r0 >= rows) return;
    const float4* p0 = (const float4*)(in + (size_t)r0 * KK);
    const float4* p1 = (const float4*)(in + (size_t)(r0 + 1) * KK);
    const float4* p2 = (const float4*)(in + (size_t)(r0 + 2) * KK);
    const float4* p3 = (const float4*)(in + (size_t)(r0 + 3) * KK);
    float a0 = 0.f, a1 = 0.f, a2 = 0.f, a3 = 0.f;
#pragma unroll 4
    for (int i0 = 0; i0 < KK; i0 += 4) {
        float4 x0 = p0[i0 >> 2], x1 = p1[i0 >> 2], x2 = p2[i0 >> 2], x3 = p3[i0 >> 2];
#pragma unroll
        for (int k = 0; k < 4; k++) {
            float wv = WL[(i0 + k) * KK + ((i0 + k + lane) & 127)];
            a0 += ((const float*)&x0)[k] * wv;
            a1 += ((const float*)&x1)[k] * wv;
            a2 += ((const float*)&x2)[k] * wv;
            a3 += ((const float*)&x3)[k] * wv;
        }
    }
    a0 *= alpha; a1 *= alpha; a2 *= alpha; a3 *= alpha;
    float* o = out + (size_t)r0 * KK + lane;
    if (accum) {
        o[0] += a0; o[KK] += a1; o[2*KK] += a2; o[3*KK] += a3;
    } else {
        o[0] = a0; o[KK] = a1; o[2*KK] = a2; o[3*KK] = a3;
    }
}

// ---------------- per-z skip layer2 ----------------
__global__ __launch_bounds__(256) void k_skip_fwd(const float* __restrict__ in, const float* __restrict__ Wall,
                                                  const int* __restrict__ z, float* __restrict__ out) {
    int wv = (blockIdx.x * 256 + threadIdx.x) >> 6;
    int lane = threadIdx.x & 63;
    int nw = gridDim.x * 4;
    for (int n = wv; n < NN; n += nw) {
        const float* Wz = Wall + (size_t)z[n] * (KK * KK);
        const float* inr = in + (size_t)n * KK;
        float a0 = 0.f, a1 = 0.f;
        for (int c = 0; c < KK; c++) {
            float v = inr[c];
            a0 += v * Wz[c * KK + lane];
            a1 += v * Wz[c * KK + 64 + lane];
        }
        out[n * KK + lane] = a0;
        out[n * KK + 64 + lane] = a1;
    }
}

__global__ __launch_bounds__(256) void k_skip_bwd(const float* __restrict__ gin, const float* __restrict__ Wall,
                                                  const int* __restrict__ z, float* __restrict__ gout) {
    int wv = (blockIdx.x * 256 + threadIdx.x) >> 6;
    int lane = threadIdx.x & 63;
    int nw = gridDim.x * 4;
    for (int n = wv; n < NN; n += nw) {
        const float* Wz = Wall + (size_t)z[n] * (KK * KK);
        const float4* g4 = (const float4*)(gin + (size_t)n * KK);
        const float4* w0 = (const float4*)(Wz + lane * KK);
        const float4* w1 = (const float4*)(Wz + (64 + lane) * KK);
        float a0 = 0.f, a1 = 0.f;
#pragma unroll 8
        for (int d0 = 0; d0 < 32; d0++) {
            float4 g = g4[d0];
            float4 u = w0[d0]; a0 += g.x*u.x + g.y*u.y + g.z*u.z + g.w*u.w;
            float4 w = w1[d0]; a1 += g.x*w.x + g.y*w.y + g.z*w.z + g.w*w.w;
        }
        gout[n * KK + lane] += a0;
        gout[n * KK + 64 + lane] += a1;
    }
}

// ---------------- edge pass 1 (rcv-centric gather): A0[n], A1[n] ----------------
__global__ __launch_bounds__(256) void k_edge1_g(const float* __restrict__ ef, const float* __restrict__ Y1,
                                                 const float* __restrict__ R1, const float* __restrict__ su1,
                                                 const int* __restrict__ row_r, const int2* __restrict__ list_r,
                                                 float* __restrict__ A0, float* __restrict__ A1) {
    __shared__ float RL[2048];
    for (int i = threadIdx.x; i < 2048; i += 256) RL[i] = R1[i];
    __syncthreads();
    int lane = threadIdx.x & 63;
    int n = blockIdx.x * 4 + (threadIdx.x >> 6);
    if (n >= NN) return;
    int c0 = lane, c1 = lane + 64;
    float a00 = 0.f, a01 = 0.f;
    float ax0 = 0.f, ax1 = 0.f, ay0 = 0.f, ay1 = 0.f, az0 = 0.f, az1 = 0.f;
    int beg = row_r[n], end = row_r[n + 1];
    for (int i = beg; i < end; i++) {
        int2 p = list_r[i];
        int e = p.x, sn = p.y;
        float4 efa = ((const float4*)ef)[e*2], efb4 = ((const float4*)ef)[e*2+1];
        float y0 = Y1[e*3+0], y1 = Y1[e*3+1], y2 = Y1[e*3+2];
        float wa0 = 0, wa1 = 0, wb0 = 0, wb1 = 0;
        const float* eb = (const float*)&efa;
#pragma unroll
        for (int b = 0; b < 8; b++) {
            if (b == 4) eb = (const float*)&efb4;
            float v = eb[b & 3];
            wa0 += v * RL[b*256 + c0];       wb0 += v * RL[b*256 + 128 + c0];
            wa1 += v * RL[b*256 + c1];       wb1 += v * RL[b*256 + 128 + c1];
        }
        float sj0 = su1[sn*KK + c0], sj1 = su1[sn*KK + c1];
        a00 += wa0 * sj0; a01 += wa1 * sj1;
        float mb0 = wb0 * sj0, mb1 = wb1 * sj1;
        ax0 += mb0*y0; ax1 += mb1*y0;
        ay0 += mb0*y1; ay1 += mb1*y1;
        az0 += mb0*y2; az1 += mb1*y2;
    }
    A0[(size_t)n*KK + c0] = a00;  A0[(size_t)n*KK + c1] = a01;
    float* A1r = A1 + (size_t)n * 384;
    A1r[c0] = ax0;        A1r[c1] = ax1;
    A1r[128 + c0] = ay0;  A1r[128 + c1] = ay1;
    A1r[256 + c0] = az0;  A1r[256 + c1] = az1;
}

// ---------------- edge pass 2 (rcv-centric gather): A2[n] ----------------
__global__ __launch_bounds__(256) void k_edge2_g(const float* __restrict__ ef, const float* __restrict__ Y1,
                                                 const float* __restrict__ R2, const float* __restrict__ s1u2,
                                                 const float* __restrict__ vup,
                                                 const int* __restrict__ row_r, const int2* __restrict__ list_r,
                                                 float* __restrict__ A2) {
    __shared__ float RL[2048];
    for (int i = threadIdx.x; i < 2048; i += 256) RL[i] = R2[(i >> 8) * 512 + (i & 255)];
    __syncthreads();
    int lane = threadIdx.x & 63;
    int n = blockIdx.x * 4 + (threadIdx.x >> 6);
    if (n >= NN) return;
    int c0 = lane, c1 = lane + 64;
    float a0 = 0.f, a1 = 0.f;
    int beg = row_r[n], end = row_r[n + 1];
    for (int i = beg; i < end; i++) {
        int2 p = list_r[i];
        int e = p.x, sn = p.y;
        float4 efa = ((const float4*)ef)[e*2], efb4 = ((const float4*)ef)[e*2+1];
        float y0 = Y1[e*3+0], y1 = Y1[e*3+1], y2 = Y1[e*3+2];
        float w00_0 = 0, w00_1 = 0, w110_0 = 0, w110_1 = 0;
        const float* eb = (const float*)&efa;
#pragma unroll
        for (int b = 0; b < 8; b++) {
            if (b == 4) eb = (const float*)&efb4;
            float v = eb[b & 3];
            w00_0  += v * RL[b*256 + c0];      w110_0 += v * RL[b*256 + 128 + c0];
            w00_1  += v * RL[b*256 + c1];      w110_1 += v * RL[b*256 + 128 + c1];
        }
        float sj0 = s1u2[sn*KK + c0], sj1 = s1u2[sn*KK + c1];
        const float* vu = vup + (size_t)sn * 384;
        float tt0 = (vu[c0]*y0 + vu[128 + c0]*y1 + vu[256 + c0]*y2) * INV_SQ3;
        float tt1 = (vu[c1]*y0 + vu[128 + c1]*y1 + vu[256 + c1]*y2) * INV_SQ3;
        a0 += w00_0 * sj0 + w110_0 * tt0;
        a1 += w00_1 * sj1 + w110_1 * tt1;
    }
    A2[(size_t)n*KK + c0] = a0;
    A2[(size_t)n*KK + c1] = a1;
}

// ---------------- MLP energy head + e1 + backward seed (no global atomics) ----------------
__global__ __launch_bounds__(128) void k_mlp(const float* __restrict__ s2, const float* __restrict__ W_mlp,
                                             const float* __restrict__ w_out, const float* __restrict__ w_r1,
                                             const float* __restrict__ s1,
                                             float* __restrict__ g_s2, float* __restrict__ g_s1,
                                             float* __restrict__ e1n, float* __restrict__ e2n) {
    __shared__ float WmL[KK * 17];
    __shared__ float s2L[KK];
    __shared__ float ghL[16];
    __shared__ float eL[16];
    __shared__ float pw[2];
    int n = blockIdx.x, t = threadIdx.x;
    for (int i = t; i < KK * 16; i += 128) WmL[(i >> 4) * 17 + (i & 15)] = W_mlp[i];
    s2L[t] = s2[(size_t)n * KK + t];
    float wr = w_r1[t];
    float p = s1[(size_t)n * KK + t] * wr;
    p = waveRed(p);
    if ((t & 63) == 0) pw[t >> 6] = p;
    __syncthreads();
    if (t < 16) {
        float h = 0.f;
        for (int c = 0; c < KK; c++) h += s2L[c] * WmL[c * 17 + t];
        float sg = 1.f / (1.f + expf(-h));
        eL[t]  = h * sg * w_out[t];
        ghL[t] = w_out[t] * sg * (1.f + h * (1.f - sg));
    }
    __syncthreads();
    if (t == 0) {
        float e = 0.f;
#pragma unroll
        for (int j = 0; j < 16; j++) e += eL[j];
        e2n[n] = e;
        e1n[n] = pw[0] + pw[1];
    }
    float g = 0.f;
#pragma unroll
    for (int j = 0; j < 16; j++) g += ghL[j] * WmL[t * 17 + j];
    g_s2[(size_t)n * KK + t] = g;
    g_s1[(size_t)n * KK + t] = wr;
}

// ---------------- energy reduction: LDS bins, few global atomics ----------------
__global__ __launch_bounds__(256) void k_energy(const int* __restrict__ z, const int* __restrict__ batch,
                                                const float* __restrict__ ae,
                                                const float* __restrict__ e1n, const float* __restrict__ e2n,
                                                float* __restrict__ out) {
    __shared__ float bins[GG * 4];
    for (int i = threadIdx.x; i < GG * 4; i += 256) bins[i] = 0.f;
    __syncthreads();
    int idx = blockIdx.x * 256 + threadIdx.x;
    int stride = gridDim.x * 256;
    for (int n = idx; n < NN; n += stride) {
        int b = batch[n];
        float v0 = ae[z[n]], v1 = e1n[n], v2 = e2n[n];
        atomicAdd(&bins[b*4+0], v0 + v1 + v2);
        atomicAdd(&bins[b*4+1], v0);
        atomicAdd(&bins[b*4+2], v1);
        atomicAdd(&bins[b*4+3], v2);
    }
    __syncthreads();
    for (int i = threadIdx.x; i < GG * 4; i += 256) {
        float v = bins[i];
        if (v != 0.f) {
            int b = i >> 2, k = i & 3;
            float* dst = (k == 0) ? &out[b] : &out[GG + b*3 + (k - 1)];
            atomAddF(dst, v);
        }
    }
}

// ---------------- backward layer2, per-edge outputs (lane = edge) ----------------
__global__ __launch_bounds__(256) void k_bwdA_e(const float* __restrict__ ef8, const float* __restrict__ Y1,
                                                const int* __restrict__ ei, const float* __restrict__ R2,
                                                const float* __restrict__ gA2, const float* __restrict__ s1u2,
                                                const float* __restrict__ vup, const int2* __restrict__ list_s,
                                                float* __restrict__ gefA, float* __restrict__ gyA) {
    int i = blockIdx.x * 256 + threadIdx.x;
    if (i >= EE) return;
    int2 p = list_s[i];
    int e = p.x, rv = p.y;
    int sn = ei[e];
    float y0 = Y1[e*3+0], y1 = Y1[e*3+1], y2 = Y1[e*3+2];
    float4 efa = ((const float4*)ef8)[e*2], efb = ((const float4*)ef8)[e*2+1];
    float efv[8] = {efa.x, efa.y, efa.z, efa.w, efb.x, efb.y, efb.z, efb.w};
    float acc[8] = {0,0,0,0,0,0,0,0};
    float g0 = 0.f, g1 = 0.f, g2 = 0.f;
    const float4* gaR = (const float4*)(gA2 + (size_t)rv * KK);
    const float4* sjR = (const float4*)(s1u2 + (size_t)sn * KK);
    const float4* vxR = (const float4*)(vup + (size_t)sn * 384);
    const float4* vyR = vxR + 32;
    const float4* vzR = vxR + 64;
    for (int cc = 0; cc < 32; cc++) {
        float4 ga = gaR[cc], sj = sjR[cc], vx = vxR[cc], vy = vyR[cc], vz = vzR[cc];
#pragma unroll
        for (int k = 0; k < 4; k++) {
            float gaE = ((const float*)&ga)[k];
            float sjE = ((const float*)&sj)[k];
            float vxE = ((const float*)&vx)[k];
            float vyE = ((const float*)&vy)[k];
            float vzE = ((const float*)&vz)[k];
            float tt = (vxE*y0 + vyE*y1 + vzE*y2) * INV_SQ3;
            float gw00 = gaE * sjE;
            float gw110 = gaE * tt;
            float w110 = 0.f;
            int c = cc*4 + k;
#pragma unroll
            for (int b = 0; b < 8; b++) {
                float r2a = R2[b*512 + c];
                float r2b = R2[b*512 + 128 + c];
                acc[b] += gw00 * r2a + gw110 * r2b;
                w110 += efv[b] * r2b;
            }
            float gt = gaE * w110;
            g0 += gt * vxE; g1 += gt * vyE; g2 += gt * vzE;
        }
    }
    float4 o0 = make_float4(acc[0], acc[1], acc[2], acc[3]);
    float4 o1 = make_float4(acc[4], acc[5], acc[6], acc[7]);
    ((float4*)gefA)[e*2] = o0; ((float4*)gefA)[e*2+1] = o1;
    gyA[e*3+0] = g0 * INV_SQ3; gyA[e*3+1] = g1 * INV_SQ3; gyA[e*3+2] = g2 * INV_SQ3;
}

// ---------------- backward layer2, node sums Gsj2/Gvj ----------------
__global__ __launch_bounds__(256) void k_bwdA_n(const float* __restrict__ ef, const float* __restrict__ Y1,
                                                const float* __restrict__ R2, const float* __restrict__ gA2,
                                                const int* __restrict__ row_s, const int2* __restrict__ list_s,
                                                float* __restrict__ Gsj2, float* __restrict__ Gvj) {
    __shared__ float RL[2048];
    for (int i = threadIdx.x; i < 2048; i += 256) RL[i] = R2[(i >> 8) * 512 + (i & 255)];
    __syncthreads();
    int lane = threadIdx.x & 63;
    int sn = blockIdx.x * 4 + (threadIdx.x >> 6);
    if (sn >= NN) return;
    int c0 = lane, c1 = lane + 64;
    float gs0 = 0.f, gs1 = 0.f;
    float gv00 = 0.f, gv01 = 0.f, gv10 = 0.f, gv11 = 0.f, gv20 = 0.f, gv21 = 0.f;
    int beg = row_s[sn], end = row_s[sn + 1];
    for (int i = beg; i < end; i++) {
        int2 p = list_s[i];
        int e = p.x, rv = p.y;
        float4 efa = ((const float4*)ef)[e*2], efb4 = ((const float4*)ef)[e*2+1];
        float y0 = Y1[e*3+0], y1 = Y1[e*3+1], y2 = Y1[e*3+2];
        float w00_0 = 0, w00_1 = 0, w110_0 = 0, w110_1 = 0;
        const float* eb = (const float*)&efa;
#pragma unroll
        for (int b = 0; b < 8; b++) {
            if (b == 4) eb = (const float*)&efb4;
            float v = eb[b & 3];
            w00_0  += v * RL[b*256 + c0];      w110_0 += v * RL[b*256 + 128 + c0];
            w00_1  += v * RL[b*256 + c1];      w110_1 += v * RL[b*256 + 128 + c1];
        }
        float ga0 = gA2[(size_t)rv*KK + c0], ga1 = gA2[(size_t)rv*KK + c1];
        gs0 += ga0 * w00_0;
        gs1 += ga1 * w00_1;
        float gts0 = ga0 * w110_0 * INV_SQ3, gts1 = ga1 * w110_1 * INV_SQ3;
        gv00 += gts0*y0; gv01 += gts1*y0;
        gv10 += gts0*y1; gv11 += gts1*y1;
        gv20 += gts0*y2; gv21 += gts1*y2;
    }
    Gsj2[(size_t)sn*KK + c0] = gs0; Gsj2[(size_t)sn*KK + c1] = gs1;
    float* Gv = Gvj + (size_t)sn * 384;
    Gv[c0] = gv00;        Gv[c1] = gv01;
    Gv[128 + c0] = gv10;  Gv[128 + c1] = gv11;
    Gv[256 + c0] = gv20;  Gv[256 + c1] = gv21;
}

// ---------------- backward layer1, per-edge outputs (lane = edge) ----------------
__global__ __launch_bounds__(256) void k_bwdB_e(const float* __restrict__ ef8, const float* __restrict__ Y1,
                                                const int* __restrict__ ei, const float* __restrict__ R1,
                                                const float* __restrict__ su1, const float* __restrict__ gA0,
                                                const float* __restrict__ gA1, const int2* __restrict__ list_r,
                                                float* __restrict__ gefB, float* __restrict__ gyB) {
    int i = blockIdx.x * 256 + threadIdx.x;
    if (i >= EE) return;
    int2 p = list_r[i];
    int e = p.x, sn = p.y;
    int rv = ei[EE + e];
    float y0 = Y1[e*3+0], y1 = Y1[e*3+1], y2 = Y1[e*3+2];
    float4 efa = ((const float4*)ef8)[e*2], efb = ((const float4*)ef8)[e*2+1];
    float efv[8] = {efa.x, efa.y, efa.z, efa.w, efb.x, efb.y, efb.z, efb.w};
    float acc[8] = {0,0,0,0,0,0,0,0};
    float gg0 = 0.f, gg1 = 0.f, gg2 = 0.f;
    const float4* gmR = (const float4*)(gA0 + (size_t)rv * KK);
    const float4* sjR = (const float4*)(su1 + (size_t)sn * KK);
    const float4* gxR = (const float4*)(gA1 + (size_t)rv * 384);
    const float4* gyR = gxR + 32;
    const float4* gzR = gxR + 64;
    for (int cc = 0; cc < 32; cc++) {
        float4 gm = gmR[cc], sj = sjR[cc], gx = gxR[cc], gy = gyR[cc], gz = gzR[cc];
#pragma unroll
        for (int k = 0; k < 4; k++) {
            float gmE = ((const float*)&gm)[k];
            float sjE = ((const float*)&sj)[k];
            float g1E = ((const float*)&gx)[k];
            float g2E = ((const float*)&gy)[k];
            float g3E = ((const float*)&gz)[k];
            float q = g1E*y0 + g2E*y1 + g3E*y2;
            float gwa = gmE * sjE;
            float gwb = q * sjE;
            float w = 0.f;
            int c = cc*4 + k;
#pragma unroll
            for (int b = 0; b < 8; b++) {
                float r1a = R1[b*256 + c];
                float r1b = R1[b*256 + 128 + c];
                acc[b] += gwa * r1a + gwb * r1b;
                w += efv[b] * r1b;
            }
            float ws = w * sjE;
            gg0 += g1E * ws; gg1 += g2E * ws; gg2 += g3E * ws;
        }
    }
    float4 o0 = make_float4(acc[0], acc[1], acc[2], acc[3]);
    float4 o1 = make_float4(acc[4], acc[5], acc[6], acc[7]);
    ((float4*)gefB)[e*2] = o0; ((float4*)gefB)[e*2+1] = o1;
    gyB[e*3+0] = gg0; gyB[e*3+1] = gg1; gyB[e*3+2] = gg2;
}

// ---------------- final: per-edge g_vec -> forces ----------------
__global__ void k_force(const float* __restrict__ gefA, const float* __restrict__ gefB,
                        const float* __restrict__ defdr,
                        const float* __restrict__ gyA, const float* __restrict__ gyB,
                        const float* __restrict__ Y1,
                        const float* __restrict__ rr, const int* __restrict__ ei,
                        float* __restrict__ forces) {
    int e = blockIdx.x * blockDim.x + threadIdx.x;
    if (e >= EE) return;
    float gr = 0.f;
#pragma unroll
    for (int b = 0; b < 8; b++) gr += (gefA[e*8+b] + gefB[e*8+b]) * defdr[e*8+b];
    float y0 = Y1[e*3+0], y1 = Y1[e*3+1], y2 = Y1[e*3+2];
    float g0 = gyA[e*3+0] + gyB[e*3+0];
    float g1 = gyA[e*3+1] + gyB[e*3+1];
    float g2 = gyA[e*3+2] + gyB[e*3+2];
    float ir = 1.f / rr[e];
    float dot = g0*y0 + g1*y1 + g2*y2;
    float a = gr * INV_SQ3;
    float b2 = SQ3F * ir;
    float c = b2 * dot * (1.f / 3.f);
    float gv0 = a*y0 + b2*g0 - c*y0;
    float gv1 = a*y1 + b2*g1 - c*y1;
    float gv2 = a*y2 + b2*g2 - c*y2;
    int sn = ei[e], rv = ei[EE + e];
    atomAddF(&forces[rv*3+0], -gv0); atomAddF(&forces[rv*3+1], -gv1); atomAddF(&forces[rv*3+2], -gv2);
    atomAddF(&forces[sn*3+0],  gv0); atomAddF(&forces[sn*3+1],  gv1); atomAddF(&forces[sn*3+2],  gv2);
}

extern "C" void kernel_launch(void* const* d_in, const int* in_sizes, int n_in,
                              void* d_out, int out_size, void* d_ws, size_t ws_size,
                              hipStream_t stream) {
    const float* positions  = (const float*)d_in[0];
    const float* shifts     = (const float*)d_in[1];
    const int*   edge_index = (const int*)d_in[2];
    const int*   node_z     = (const int*)d_in[3];
    const int*   batch      = (const int*)d_in[4];
    const float* atomic_e   = (const float*)d_in[5];
    const float* W_embed    = (const float*)d_in[6];
    const float* R1         = (const float*)d_in[7];
    const float* W_up1      = (const float*)d_in[8];
    const float* W_mix_s1   = (const float*)d_in[9];
    const float* W_mix_v1   = (const float*)d_in[10];
    const float* W_sk_s1    = (const float*)d_in[11];
    const float* w_r1       = (const float*)d_in[12];
    const float* R2         = (const float*)d_in[13];
    const float* W_up2s     = (const float*)d_in[14];
    const float* W_up2v     = (const float*)d_in[15];
    const float* W_mix_s2   = (const float*)d_in[16];
    const float* W_sk_s2    = (const float*)d_in[17];
    const float* W_mlp      = (const float*)d_in[18];
    const float* w_out      = (const float*)d_in[19];

    float* out = (float*)d_out;
    float* ws = (float*)d_ws;
    size_t off = 0;
    float* ef    = ws + off; off += (size_t)EE * 8;
    float* defdr = ws + off; off += (size_t)EE * 8;
    float* Y1    = ws + off; off += (size_t)EE * 3;
    float* rr    = ws + off; off += (size_t)EE;
    float* gefA  = ws + off; off += (size_t)EE * 8;
    float* gyA   = ws + off; off += (size_t)EE * 3;
    float* gefB  = ws + off; off += (size_t)EE * 8;
    float* gyB   = ws + off; off += (size_t)EE * 3;
    float* su1   = ws + off; off += (size_t)NN * KK;
    float* s1    = ws + off; off += (size_t)NN * KK;
    float* s1u2  = ws + off; off += (size_t)NN * KK;
    float* s2    = ws + off; off += (size_t)NN * KK;
    float* g_s2  = ws + off; off += (size_t)NN * KK;
    float* g_s1  = ws + off; off += (size_t)NN * KK;
    float* vup   = ws + off; off += (size_t)NN * KK * 3;
    float* A0    = ws + off; off += (size_t)NN * KK;       // later g_A0
    float* A2    = ws + off; off += (size_t)NN * KK;       // later g_A2
    float* Gsj2  = ws + off; off += (size_t)NN * KK;
    float* A1    = ws + off; off += (size_t)NN * KK * 3;   // later g_A1
    float* Gvj   = ws + off; off += (size_t)NN * KK * 3;
    float* E1    = ws + off; off += 10 * KK;
    float* T1    = ws + off; off += 10 * KK;
    float* Wc    = ws + off; off += KK * KK;
    float* e1n   = ws + off; off += NN;
    float* e2n   = ws + off; off += NN;
    // int region (8B aligned: off is even)
    int* ip = (int*)(ws + off);
    size_t ioff = 0;
    int* deg_r = ip + ioff; ioff += NN;
    int* deg_s = ip + ioff; ioff += NN;
    int* cur_r = ip + ioff; ioff += NN;
    int* cur_s = ip + ioff; ioff += NN;
    int* row_r = ip + ioff; ioff += NN + 2;
    int* row_s = ip + ioff; ioff += NN + 2;
    int2* list_r = (int2*)(ip + ioff); ioff += (size_t)EE * 2;
    int2* list_s = (int2*)(ip + ioff); ioff += (size_t)EE * 2;

    hipMemsetAsync(out, 0, (size_t)out_size * sizeof(float), stream);
    hipMemsetAsync(deg_r, 0, (size_t)4 * NN * sizeof(int), stream);

    // ---- CSR build + geometry + tables ----
    k_edge_geom<<<(EE + 255) / 256, 256, 0, stream>>>(positions, shifts, edge_index, ef, defdr, Y1, rr);
    k_hist<<<(EE + 255) / 256, 256, 0, stream>>>(edge_index, deg_r, deg_s);
    k_scan<<<1, 1024, 0, stream>>>(deg_r, deg_s, row_r, row_s);
    k_fill<<<(EE + 255) / 256, 256, 0, stream>>>(edge_index, row_r, row_s, cur_r, cur_s, list_r, list_s);
    k_tables<<<10, 128, 0, stream>>>(W_embed, W_up1, W_sk_s1, E1, T1);
    k_gemm<0><<<KK / 8, 256, 0, stream>>>(W_mix_v1, W_up2v, Wc, KK, 1.f, 0);   // Wc = W_mix_v1 @ W_up2v
    // ---- forward ----
    k_zinit<<<(NN * KK + 255) / 256, 256, 0, stream>>>(su1, E1, node_z);
    k_edge1_g<<<(NN + 3) / 4, 256, 0, stream>>>(ef, Y1, R1, su1, row_r, list_r, A0, A1);
    k_zinit<<<(NN * KK + 255) / 256, 256, 0, stream>>>(s1, T1, node_z);
    k_gemm<0><<<NN / 8, 256, 0, stream>>>(A0, W_mix_s1, s1, NN, INV_AVG, 1);
    k_gemm<0><<<NN * 3 / 8, 256, 0, stream>>>(A1, Wc, vup, NN * 3, INV_AVG, 0);
    k_gemm<0><<<NN / 8, 256, 0, stream>>>(s1, W_up2s, s1u2, NN, 1.f, 0);
    k_edge2_g<<<(NN + 3) / 4, 256, 0, stream>>>(ef, Y1, R2, s1u2, vup, row_r, list_r, A2);
    k_skip_fwd<<<512, 256, 0, stream>>>(s1, W_sk_s2, node_z, s2);
    k_gemm<0><<<NN / 8, 256, 0, stream>>>(A2, W_mix_s2, s2, NN, INV_AVG, 1);
    // ---- energy head + backward seed (also computes e1n) ----
    k_mlp<<<NN, 128, 0, stream>>>(s2, W_mlp, w_out, w_r1, s1, g_s2, g_s1, e1n, e2n);
    k_energy<<<32, 256, 0, stream>>>(node_z, batch, atomic_e, e1n, e2n, out);
    // ---- backward ----
    k_gemm<1><<<NN / 8, 256, 0, stream>>>(g_s2, W_mix_s2, A2, NN, INV_AVG, 0);       // g_A2 -> A2
    k_skip_bwd<<<512, 256, 0, stream>>>(g_s2, W_sk_s2, node_z, g_s1);
    k_bwdA_e<<<(EE + 255) / 256, 256, 0, stream>>>(ef, Y1, edge_index, R2, A2, s1u2, vup, list_s, gefA, gyA);
    k_bwdA_n<<<(NN + 3) / 4, 256, 0, stream>>>(ef, Y1, R2, A2, row_s, list_s, Gsj2, Gvj);
    k_gemm<1><<<NN / 8, 256, 0, stream>>>(Gsj2, W_up2s, g_s1, NN, 1.f, 1);
    k_gemm<1><<<NN * 3 / 8, 256, 0, stream>>>(Gvj, Wc, A1, NN * 3, INV_AVG, 0);      // g_A1 -> A1
    k_gemm<1><<<NN / 8, 256, 0, stream>>>(g_s1, W_mix_s1, A0, NN, INV_AVG, 0);       // g_A0 -> A0
    k_bwdB_e<<<(EE + 255) / 256, 256, 0, stream>>>(ef, Y1, edge_index, R1, su1, A0, A1, list_r, gefB, gyB);
    k_force<<<(EE + 255) / 256, 256, 0, stream>>>(gefA, gefB, defdr, gyA, gyB, Y1, rr, edge_index, out + GG + GG * 3);
}

// Round 5
// 719.521 us; speedup vs baseline: 3.0223x; 1.7150x over previous
//
#include <hip/hip_runtime.h>
#include <math.h>

#define NN 10000
#define EE 160000
#define KK 128
#define GG 16
#define NE 10
#define SQ3F 1.7320508075688772f
#define INV_SQ3 0.57735026918962576f
#define INV_AVG 0.0625f
#define RMAXI 0.2f

__device__ __forceinline__ void atomAddF(float* p, float v) { unsafeAtomicAdd(p, v); }

__device__ __forceinline__ float waveRed(float v) {
#pragma unroll
    for (int m = 32; m >= 1; m >>= 1) v += __shfl_xor(v, m);
    return v;
}

// ---------------- edge geometry ----------------
__global__ void k_edge_geom(const float* __restrict__ pos, const float* __restrict__ shifts,
                            const int* __restrict__ ei,
                            float* __restrict__ ef, float* __restrict__ defdr,
                            float* __restrict__ Y1, float* __restrict__ rr) {
    int e = blockIdx.x * blockDim.x + threadIdx.x;
    if (e >= EE) return;
    int sn = ei[e], rv = ei[EE + e];
    float vx = pos[rv*3+0] - pos[sn*3+0] + shifts[e*3+0];
    float vy = pos[rv*3+1] - pos[sn*3+1] + shifts[e*3+1];
    float vz = pos[rv*3+2] - pos[sn*3+2] + shifts[e*3+2];
    float r = sqrtf(vx*vx + vy*vy + vz*vz + 1e-12f);
    float ir = 1.0f / r;
    rr[e] = r;
    Y1[e*3+0] = SQ3F*vx*ir; Y1[e*3+1] = SQ3F*vy*ir; Y1[e*3+2] = SQ3F*vz*ir;
    float x = r * RMAXI;
    float fc = 0.f, dfc = 0.f;
    if (x < 1.0f) {
        float x2 = x*x, x4 = x2*x2, x5 = x4*x, x6 = x5*x, x7 = x6*x;
        fc  = 1.0f - 21.0f*x5 + 35.0f*x6 - 15.0f*x7;
        dfc = (-105.0f*x4 + 210.0f*x5 - 105.0f*x6) * RMAXI;
    }
    const float C = 0.63245553203367587f; // sqrt(2/5)
    float4 efa, efb4, da, db;
    float* efp = (float*)&efa; float* dp = (float*)&da;
#pragma unroll
    for (int b = 0; b < 8; b++) {
        float kb = (float)(b + 1) * 0.62831853071795865f; // (b+1)*pi/5
        float sb, cb;
        sincosf(kb * r, &sb, &cb);
        float bess  = C * sb * ir;
        float dbess = C * ir * (kb * cb - sb * ir);
        if (b == 4) { efp = (float*)&efb4; dp = (float*)&db; }
        efp[b & 3] = bess * fc;
        dp[b & 3]  = dbess * fc + bess * dfc;
    }
    ((float4*)ef)[e*2]      = efa; ((float4*)ef)[e*2+1]    = efb4;
    ((float4*)defdr)[e*2]   = da;  ((float4*)defdr)[e*2+1] = db;
}

// ---------------- CSR build ----------------
__global__ void k_hist(const int* __restrict__ ei, int* __restrict__ deg_r, int* __restrict__ deg_s) {
    int e = blockIdx.x * blockDim.x + threadIdx.x;
    if (e >= EE) return;
    atomicAdd(&deg_s[ei[e]], 1);
    atomicAdd(&deg_r[ei[EE + e]], 1);
}

__global__ __launch_bounds__(1024) void k_scan(const int* __restrict__ deg_r, const int* __restrict__ deg_s,
                                               int* __restrict__ row_r, int* __restrict__ row_s) {
    __shared__ int part[1024];
    int t = threadIdx.x;
    for (int a = 0; a < 2; a++) {
        const int* deg = a ? deg_s : deg_r;
        int* row = a ? row_s : row_r;
        int base = t * 10;
        int loc[10];
        int s = 0;
#pragma unroll
        for (int k = 0; k < 10; k++) {
            loc[k] = s;
            if (base + k < NN) s += deg[base + k];
        }
        part[t] = s;
        __syncthreads();
        for (int off = 1; off < 1024; off <<= 1) {
            int v = (t >= off) ? part[t - off] : 0;
            __syncthreads();
            part[t] += v;
            __syncthreads();
        }
        int bex = (t > 0) ? part[t - 1] : 0;
#pragma unroll
        for (int k = 0; k < 10; k++)
            if (base + k < NN) row[base + k] = bex + loc[k];
        if (t == 1023) row[NN] = part[1023];
        __syncthreads();
    }
}

__global__ void k_fill(const int* __restrict__ ei, const int* __restrict__ row_r, const int* __restrict__ row_s,
                       int* __restrict__ cur_r, int* __restrict__ cur_s,
                       int2* __restrict__ list_r, int2* __restrict__ list_s) {
    int e = blockIdx.x * blockDim.x + threadIdx.x;
    if (e >= EE) return;
    int sn = ei[e], rv = ei[EE + e];
    int pr = atomicAdd(&cur_r[rv], 1);
    list_r[row_r[rv] + pr] = make_int2(e, sn);
    int ps = atomicAdd(&cur_s[sn], 1);
    list_s[row_s[sn] + ps] = make_int2(e, rv);
}

// ---------------- z buckets ----------------
__global__ void k_zcount(const int* __restrict__ z, int* __restrict__ zcnt) {
    __shared__ int h[NE];
    if (threadIdx.x < NE) h[threadIdx.x] = 0;
    __syncthreads();
    int n = blockIdx.x * 256 + threadIdx.x;
    if (n < NN) atomicAdd(&h[z[n]], 1);
    __syncthreads();
    if (threadIdx.x < NE && h[threadIdx.x] > 0) atomicAdd(&zcnt[threadIdx.x], h[threadIdx.x]);
}

__global__ void k_zscan(const int* __restrict__ zcnt, int* __restrict__ zrow) {
    if (threadIdx.x == 0) {
        int s = 0;
        for (int i = 0; i < NE; i++) { zrow[i] = s; s += zcnt[i]; }
        zrow[NE] = s;
    }
}

__global__ void k_zfill(const int* __restrict__ z, int* __restrict__ zcur, const int* __restrict__ zrow,
                        int* __restrict__ zlist) {
    __shared__ int cnt[NE];
    __shared__ int base[NE];
    int t = threadIdx.x;
    if (t < NE) cnt[t] = 0;
    __syncthreads();
    int n = blockIdx.x * 256 + t;
    int pos = -1, zz = 0;
    if (n < NN) { zz = z[n]; pos = atomicAdd(&cnt[zz], 1); }
    __syncthreads();
    if (t < NE && cnt[t] > 0) base[t] = atomicAdd(&zcur[t], cnt[t]);
    __syncthreads();
    if (n < NN) zlist[zrow[zz] + base[zz] + pos] = n;
}

// ---------------- z-tables: E1 = W_embed@W_up1, T1 = per-z skip1 of embed ----------------
__global__ void k_tables(const float* __restrict__ We, const float* __restrict__ Wup1,
                         const float* __restrict__ Wsk1, float* __restrict__ E1, float* __restrict__ T1) {
    int zz = blockIdx.x, d = threadIdx.x;
    float a = 0.f, bv = 0.f;
    for (int c = 0; c < KK; c++) {
        float w = We[zz*KK + c];
        a  += w * Wup1[c*KK + d];
        bv += w * Wsk1[(size_t)(zz*KK + c)*KK + d];
    }
    E1[zz*KK + d] = a;
    T1[zz*KK + d] = bv;
}

__global__ void k_zinit(float* __restrict__ out, const float* __restrict__ tab, const int* __restrict__ z) {
    int i = blockIdx.x * blockDim.x + threadIdx.x;
    if (i >= NN * KK) return;
    out[i] = tab[z[i >> 7] * KK + (i & 127)];
}

// ============ register-tiled K x K GEMM: 64-row tile, thread = 8 rows x 4 cols ============
// W staged in LDS with group-diagonal swizzle: elem (k,c) at k*128 + (((c>>2)+k)&31)*4 + (c&3)
// -> b128 reads of W[k][cg..cg+3] are 16B-aligned and conflict-benign.
template <int TRANS>
__global__ __launch_bounds__(256) void k_gemm(const float* __restrict__ in, const float* __restrict__ W,
                                              float* __restrict__ out, int rows, float alpha, int accum) {
    __shared__ float WL[KK * KK];
    int t = threadIdx.x;
    for (int i = t; i < KK * KK; i += 256) {
        float v = W[i];
        int a = i >> 7, b = i & 127;      // v = W[a][b]
        int k = TRANS ? b : a;            // logical M[k][c], M = TRANS ? W^T : W
        int c = TRANS ? a : b;
        WL[k * KK + ((((c >> 2) + k) & 31) << 2) + (c & 3)] = v;
    }
    __syncthreads();
    int g0 = t & 31;                 // col group -> cols cg..cg+3
    int cg = g0 << 2;
    int r0 = blockIdx.x * 64 + ((t >> 5) << 3);
    if (r0 >= rows && blockIdx.x) { /* keep uniform-ish; still safe below */ }
    const float* Ap[8];
#pragma unroll
    for (int j = 0; j < 8; j++) {
        int r = r0 + j; if (r > rows - 1) r = rows - 1;
        Ap[j] = in + (size_t)r * KK;
    }
    float acc[8][4];
#pragma unroll
    for (int j = 0; j < 8; j++) { acc[j][0] = acc[j][1] = acc[j][2] = acc[j][3] = 0.f; }
#pragma unroll 2
    for (int k = 0; k < KK; k += 4) {
        float4 w0 = *(const float4*)&WL[(k+0)*KK + (((g0 + k + 0) & 31) << 2)];
        float4 w1 = *(const float4*)&WL[(k+1)*KK + (((g0 + k + 1) & 31) << 2)];
        float4 w2 = *(const float4*)&WL[(k+2)*KK + (((g0 + k + 2) & 31) << 2)];
        float4 w3 = *(const float4*)&WL[(k+3)*KK + (((g0 + k + 3) & 31) << 2)];
#pragma unroll
        for (int j = 0; j < 8; j++) {
            float4 a = *(const float4*)(Ap[j] + k);
            acc[j][0] += a.x*w0.x + a.y*w1.x + a.z*w2.x + a.w*w3.x;
            acc[j][1] += a.x*w0.y + a.y*w1.y + a.z*w2.y + a.w*w3.y;
            acc[j][2] += a.x*w0.z + a.y*w1.z + a.z*w2.z + a.w*w3.z;
            acc[j][3] += a.x*w0.w + a.y*w1.w + a.z*w2.w + a.w*w3.w;
        }
    }
#pragma unroll
    for (int j = 0; j < 8; j++) {
        int r = r0 + j;
        if (r < rows) {
            float4* o = (float4*)(out + (size_t)r * KK + cg);
            float4 v = make_float4(acc[j][0]*alpha, acc[j][1]*alpha, acc[j][2]*alpha, acc[j][3]*alpha);
            if (accum) { float4 old = *o; v.x += old.x; v.y += old.y; v.z += old.z; v.w += old.w; }
            *o = v;
        }
    }
}

// ============ per-z skip as bucketed tiled GEMM ============
template <int TRANS, int ACCUM>
__global__ __launch_bounds__(256) void k_skip(const float* __restrict__ in, const float* __restrict__ Wall,
                                              const int* __restrict__ zrow, const int* __restrict__ zlist,
                                              float* __restrict__ out) {
    int zz = blockIdx.x;
    int beg = zrow[zz], cnt = zrow[zz + 1] - beg;
    if (cnt == 0) return;
    __shared__ float WL[KK * KK];
    const float* W = Wall + (size_t)zz * (KK * KK);
    int t = threadIdx.x;
    for (int i = t; i < KK * KK; i += 256) {
        float v = W[i];
        int a = i >> 7, b = i & 127;
        int k = TRANS ? b : a;
        int c = TRANS ? a : b;
        WL[k * KK + ((((c >> 2) + k) & 31) << 2) + (c & 3)] = v;
    }
    __syncthreads();
    int g0 = t & 31;
    int cg = g0 << 2;
    int rg = (t >> 5) << 3;
    for (int ch = blockIdx.y; ch * 64 < cnt; ch += gridDim.y) {
        int i0 = ch * 64 + rg;
        int rowv[8];
        const float* Ap[8];
#pragma unroll
        for (int j = 0; j < 8; j++) {
            int idx = i0 + j; if (idx > cnt - 1) idx = cnt - 1;
            rowv[j] = zlist[beg + idx];
            Ap[j] = in + (size_t)rowv[j] * KK;
        }
        float acc[8][4];
#pragma unroll
        for (int j = 0; j < 8; j++) { acc[j][0] = acc[j][1] = acc[j][2] = acc[j][3] = 0.f; }
#pragma unroll 2
        for (int k = 0; k < KK; k += 4) {
            float4 w0 = *(const float4*)&WL[(k+0)*KK + (((g0 + k + 0) & 31) << 2)];
            float4 w1 = *(const float4*)&WL[(k+1)*KK + (((g0 + k + 1) & 31) << 2)];
            float4 w2 = *(const float4*)&WL[(k+2)*KK + (((g0 + k + 2) & 31) << 2)];
            float4 w3 = *(const float4*)&WL[(k+3)*KK + (((g0 + k + 3) & 31) << 2)];
#pragma unroll
            for (int j = 0; j < 8; j++) {
                float4 a = *(const float4*)(Ap[j] + k);
                acc[j][0] += a.x*w0.x + a.y*w1.x + a.z*w2.x + a.w*w3.x;
                acc[j][1] += a.x*w0.y + a.y*w1.y + a.z*w2.y + a.w*w3.y;
                acc[j][2] += a.x*w0.z + a.y*w1.z + a.z*w2.z + a.w*w3.z;
                acc[j][3] += a.x*w0.w + a.y*w1.w + a.z*w2.w + a.w*w3.w;
            }
        }
#pragma unroll
        for (int j = 0; j < 8; j++) {
            if (i0 + j < cnt) {
                float4* o = (float4*)(out + (size_t)rowv[j] * KK + cg);
                float4 v = make_float4(acc[j][0], acc[j][1], acc[j][2], acc[j][3]);
                if (ACCUM) { float4 old = *o; v.x += old.x; v.y += old.y; v.z += old.z; v.w += old.w; }
                *o = v;
            }
        }
    }
}

// ---------------- edge pass 1 (rcv-centric gather): A0[n], A1[n] ----------------
__global__ __launch_bounds__(256) void k_edge1_g(const float* __restrict__ ef, const float* __restrict__ Y1,
                                                 const float* __restrict__ R1, const float* __restrict__ su1,
                                                 const int* __restrict__ row_r, const int2* __restrict__ list_r,
                                                 float* __restrict__ A0, float* __restrict__ A1) {
    __shared__ float RL[2048];
    for (int i = threadIdx.x; i < 2048; i += 256) RL[i] = R1[i];
    __syncthreads();
    int lane = threadIdx.x & 63;
    int n = blockIdx.x * 4 + (threadIdx.x >> 6);
    if (n >= NN) return;
    int c0 = lane, c1 = lane + 64;
    float a00 = 0.f, a01 = 0.f;
    float ax0 = 0.f, ax1 = 0.f, ay0 = 0.f, ay1 = 0.f, az0 = 0.f, az1 = 0.f;
    int beg = row_r[n], end = row_r[n + 1];
    for (int i = beg; i < end; i++) {
        int2 p = list_r[i];
        int e = p.x, sn = p.y;
        float4 efa = ((const float4*)ef)[e*2], efb4 = ((const float4*)ef)[e*2+1];
        float y0 = Y1[e*3+0], y1 = Y1[e*3+1], y2 = Y1[e*3+2];
        float wa0 = 0, wa1 = 0, wb0 = 0, wb1 = 0;
        const float* eb = (const float*)&efa;
#pragma unroll
        for (int b = 0; b < 8; b++) {
            if (b == 4) eb = (const float*)&efb4;
            float v = eb[b & 3];
            wa0 += v * RL[b*256 + c0];       wb0 += v * RL[b*256 + 128 + c0];
            wa1 += v * RL[b*256 + c1];       wb1 += v * RL[b*256 + 128 + c1];
        }
        float sj0 = su1[sn*KK + c0], sj1 = su1[sn*KK + c1];
        a00 += wa0 * sj0; a01 += wa1 * sj1;
        float mb0 = wb0 * sj0, mb1 = wb1 * sj1;
        ax0 += mb0*y0; ax1 += mb1*y0;
        ay0 += mb0*y1; ay1 += mb1*y1;
        az0 += mb0*y2; az1 += mb1*y2;
    }
    A0[(size_t)n*KK + c0] = a00;  A0[(size_t)n*KK + c1] = a01;
    float* A1r = A1 + (size_t)n * 384;
    A1r[c0] = ax0;        A1r[c1] = ax1;
    A1r[128 + c0] = ay0;  A1r[128 + c1] = ay1;
    A1r[256 + c0] = az0;  A1r[256 + c1] = az1;
}

// ---------------- edge pass 2 (rcv-centric gather): A2[n] ----------------
__global__ __launch_bounds__(256) void k_edge2_g(const float* __restrict__ ef, const float* __restrict__ Y1,
                                                 const float* __restrict__ R2, const float* __restrict__ s1u2,
                                                 const float* __restrict__ vup,
                                                 const int* __restrict__ row_r, const int2* __restrict__ list_r,
                                                 float* __restrict__ A2) {
    __shared__ float RL[2048];
    for (int i = threadIdx.x; i < 2048; i += 256) RL[i] = R2[(i >> 8) * 512 + (i & 255)];
    __syncthreads();
    int lane = threadIdx.x & 63;
    int n = blockIdx.x * 4 + (threadIdx.x >> 6);
    if (n >= NN) return;
    int c0 = lane, c1 = lane + 64;
    float a0 = 0.f, a1 = 0.f;
    int beg = row_r[n], end = row_r[n + 1];
    for (int i = beg; i < end; i++) {
        int2 p = list_r[i];
        int e = p.x, sn = p.y;
        float4 efa = ((const float4*)ef)[e*2], efb4 = ((const float4*)ef)[e*2+1];
        float y0 = Y1[e*3+0], y1 = Y1[e*3+1], y2 = Y1[e*3+2];
        float w00_0 = 0, w00_1 = 0, w110_0 = 0, w110_1 = 0;
        const float* eb = (const float*)&efa;
#pragma unroll
        for (int b = 0; b < 8; b++) {
            if (b == 4) eb = (const float*)&efb4;
            float v = eb[b & 3];
            w00_0  += v * RL[b*256 + c0];      w110_0 += v * RL[b*256 + 128 + c0];
            w00_1  += v * RL[b*256 + c1];      w110_1 += v * RL[b*256 + 128 + c1];
        }
        float sj0 = s1u2[sn*KK + c0], sj1 = s1u2[sn*KK + c1];
        const float* vu = vup + (size_t)sn * 384;
        float tt0 = (vu[c0]*y0 + vu[128 + c0]*y1 + vu[256 + c0]*y2) * INV_SQ3;
        float tt1 = (vu[c1]*y0 + vu[128 + c1]*y1 + vu[256 + c1]*y2) * INV_SQ3;
        a0 += w00_0 * sj0 + w110_0 * tt0;
        a1 += w00_1 * sj1 + w110_1 * tt1;
    }
    A2[(size_t)n*KK + c0] = a0;
    A2[(size_t)n*KK + c1] = a1;
}

// ---------------- MLP energy head + e1 + backward seed (no global atomics) ----------------
__global__ __launch_bounds__(128) void k_mlp(const float* __restrict__ s2, const float* __restrict__ W_mlp,
                                             const float* __restrict__ w_out, const float* __restrict__ w_r1,
                                             const float* __restrict__ s1,
                                             float* __restrict__ g_s2, float* __restrict__ g_s1,
                                             float* __restrict__ e1n, float* __restrict__ e2n) {
    __shared__ float WmL[KK * 17];
    __shared__ float s2L[KK];
    __shared__ float ghL[16];
    __shared__ float eL[16];
    __shared__ float pw[2];
    int n = blockIdx.x, t = threadIdx.x;
    for (int i = t; i < KK * 16; i += 128) WmL[(i >> 4) * 17 + (i & 15)] = W_mlp[i];
    s2L[t] = s2[(size_t)n * KK + t];
    float wr = w_r1[t];
    float p = s1[(size_t)n * KK + t] * wr;
    p = waveRed(p);
    if ((t & 63) == 0) pw[t >> 6] = p;
    __syncthreads();
    if (t < 16) {
        float h = 0.f;
        for (int c = 0; c < KK; c++) h += s2L[c] * WmL[c * 17 + t];
        float sg = 1.f / (1.f + expf(-h));
        eL[t]  = h * sg * w_out[t];
        ghL[t] = w_out[t] * sg * (1.f + h * (1.f - sg));
    }
    __syncthreads();
    if (t == 0) {
        float e = 0.f;
#pragma unroll
        for (int j = 0; j < 16; j++) e += eL[j];
        e2n[n] = e;
        e1n[n] = pw[0] + pw[1];
    }
    float g = 0.f;
#pragma unroll
    for (int j = 0; j < 16; j++) g += ghL[j] * WmL[t * 17 + j];
    g_s2[(size_t)n * KK + t] = g;
    g_s1[(size_t)n * KK + t] = wr;
}

// ---------------- energy reduction ----------------
__global__ __launch_bounds__(256) void k_energy(const int* __restrict__ z, const int* __restrict__ batch,
                                                const float* __restrict__ ae,
                                                const float* __restrict__ e1n, const float* __restrict__ e2n,
                                                float* __restrict__ out) {
    __shared__ float bins[GG * 4];
    for (int i = threadIdx.x; i < GG * 4; i += 256) bins[i] = 0.f;
    __syncthreads();
    int idx = blockIdx.x * 256 + threadIdx.x;
    int stride = gridDim.x * 256;
    for (int n = idx; n < NN; n += stride) {
        int b = batch[n];
        float v0 = ae[z[n]], v1 = e1n[n], v2 = e2n[n];
        atomicAdd(&bins[b*4+0], v0 + v1 + v2);
        atomicAdd(&bins[b*4+1], v0);
        atomicAdd(&bins[b*4+2], v1);
        atomicAdd(&bins[b*4+3], v2);
    }
    __syncthreads();
    for (int i = threadIdx.x; i < GG * 4; i += 256) {
        float v = bins[i];
        if (v != 0.f) {
            int b = i >> 2, k = i & 3;
            float* dst = (k == 0) ? &out[b] : &out[GG + b*3 + (k - 1)];
            atomAddF(dst, v);
        }
    }
}

// ---------------- backward layer2, per-edge outputs (lane = edge) ----------------
__global__ __launch_bounds__(256) void k_bwdA_e(const float* __restrict__ ef8, const float* __restrict__ Y1,
                                                const int* __restrict__ ei, const float* __restrict__ R2,
                                                const float* __restrict__ gA2, const float* __restrict__ s1u2,
                                                const float* __restrict__ vup, const int2* __restrict__ list_s,
                                                float* __restrict__ gefA, float* __restrict__ gyA) {
    int i = blockIdx.x * 256 + threadIdx.x;
    if (i >= EE) return;
    int2 p = list_s[i];
    int e = p.x, rv = p.y;
    int sn = ei[e];
    float y0 = Y1[e*3+0], y1 = Y1[e*3+1], y2 = Y1[e*3+2];
    float4 efa = ((const float4*)ef8)[e*2], efb = ((const float4*)ef8)[e*2+1];
    float efv[8] = {efa.x, efa.y, efa.z, efa.w, efb.x, efb.y, efb.z, efb.w};
    float acc[8] = {0,0,0,0,0,0,0,0};
    float g0 = 0.f, g1 = 0.f, g2 = 0.f;
    const float4* gaR = (const float4*)(gA2 + (size_t)rv * KK);
    const float4* sjR = (const float4*)(s1u2 + (size_t)sn * KK);
    const float4* vxR = (const float4*)(vup + (size_t)sn * 384);
    const float4* vyR = vxR + 32;
    const float4* vzR = vxR + 64;
    for (int cc = 0; cc < 32; cc++) {
        float4 ga = gaR[cc], sj = sjR[cc], vx = vxR[cc], vy = vyR[cc], vz = vzR[cc];
#pragma unroll
        for (int k = 0; k < 4; k++) {
            float gaE = ((const float*)&ga)[k];
            float sjE = ((const float*)&sj)[k];
            float vxE = ((const float*)&vx)[k];
            float vyE = ((const float*)&vy)[k];
            float vzE = ((const float*)&vz)[k];
            float tt = (vxE*y0 + vyE*y1 + vzE*y2) * INV_SQ3;
            float gw00 = gaE * sjE;
            float gw110 = gaE * tt;
            float w110 = 0.f;
            int c = cc*4 + k;
#pragma unroll
            for (int b = 0; b < 8; b++) {
                float r2a = R2[b*512 + c];
                float r2b = R2[b*512 + 128 + c];
                acc[b] += gw00 * r2a + gw110 * r2b;
                w110 += efv[b] * r2b;
            }
            float gt = gaE * w110;
            g0 += gt * vxE; g1 += gt * vyE; g2 += gt * vzE;
        }
    }
    float4 o0 = make_float4(acc[0], acc[1], acc[2], acc[3]);
    float4 o1 = make_float4(acc[4], acc[5], acc[6], acc[7]);
    ((float4*)gefA)[e*2] = o0; ((float4*)gefA)[e*2+1] = o1;
    gyA[e*3+0] = g0 * INV_SQ3; gyA[e*3+1] = g1 * INV_SQ3; gyA[e*3+2] = g2 * INV_SQ3;
}

// ---------------- backward layer2, node sums Gsj2/Gvj ----------------
__global__ __launch_bounds__(256) void k_bwdA_n(const float* __restrict__ ef, const float* __restrict__ Y1,
                                                const float* __restrict__ R2, const float* __restrict__ gA2,
                                                const int* __restrict__ row_s, const int2* __restrict__ list_s,
                                                float* __restrict__ Gsj2, float* __restrict__ Gvj) {
    __shared__ float RL[2048];
    for (int i = threadIdx.x; i < 2048; i += 256) RL[i] = R2[(i >> 8) * 512 + (i & 255)];
    __syncthreads();
    int lane = threadIdx.x & 63;
    int sn = blockIdx.x * 4 + (threadIdx.x >> 6);
    if (sn >= NN) return;
    int c0 = lane, c1 = lane + 64;
    float gs0 = 0.f, gs1 = 0.f;
    float gv00 = 0.f, gv01 = 0.f, gv10 = 0.f, gv11 = 0.f, gv20 = 0.f, gv21 = 0.f;
    int beg = row_s[sn], end = row_s[sn + 1];
    for (int i = beg; i < end; i++) {
        int2 p = list_s[i];
        int e = p.x, rv = p.y;
        float4 efa = ((const float4*)ef)[e*2], efb4 = ((const float4*)ef)[e*2+1];
        float y0 = Y1[e*3+0], y1 = Y1[e*3+1], y2 = Y1[e*3+2];
        float w00_0 = 0, w00_1 = 0, w110_0 = 0, w110_1 = 0;
        const float* eb = (const float*)&efa;
#pragma unroll
        for (int b = 0; b < 8; b++) {
            if (b == 4) eb = (const float*)&efb4;
            float v = eb[b & 3];
            w00_0  += v * RL[b*256 + c0];      w110_0 += v * RL[b*256 + 128 + c0];
            w00_1  += v * RL[b*256 + c1];      w110_1 += v * RL[b*256 + 128 + c1];
        }
        float ga0 = gA2[(size_t)rv*KK + c0], ga1 = gA2[(size_t)rv*KK + c1];
        gs0 += ga0 * w00_0;
        gs1 += ga1 * w00_1;
        float gts0 = ga0 * w110_0 * INV_SQ3, gts1 = ga1 * w110_1 * INV_SQ3;
        gv00 += gts0*y0; gv01 += gts1*y0;
        gv10 += gts0*y1; gv11 += gts1*y1;
        gv20 += gts0*y2; gv21 += gts1*y2;
    }
    Gsj2[(size_t)sn*KK + c0] = gs0; Gsj2[(size_t)sn*KK + c1] = gs1;
    float* Gv = Gvj + (size_t)sn * 384;
    Gv[c0] = gv00;        Gv[c1] = gv01;
    Gv[128 + c0] = gv10;  Gv[128 + c1] = gv11;
    Gv[256 + c0] = gv20;  Gv[256 + c1] = gv21;
}

// ---------------- backward layer1, per-edge outputs (lane = edge) ----------------
__global__ __launch_bounds__(256) void k_bwdB_e(const float* __restrict__ ef8, const float* __restrict__ Y1,
                                                const int* __restrict__ ei, const float* __restrict__ R1,
                                                const float* __restrict__ su1, const float* __restrict__ gA0,
                                                const float* __restrict__ gA1, const int2* __restrict__ list_r,
                                                float* __restrict__ gefB, float* __restrict__ gyB) {
    int i = blockIdx.x * 256 + threadIdx.x;
    if (i >= EE) return;
    int2 p = list_r[i];
    int e = p.x, sn = p.y;
    int rv = ei[EE + e];
    float y0 = Y1[e*3+0], y1 = Y1[e*3+1], y2 = Y1[e*3+2];
    float4 efa = ((const float4*)ef8)[e*2], efb = ((const float4*)ef8)[e*2+1];
    float efv[8] = {efa.x, efa.y, efa.z, efa.w, efb.x, efb.y, efb.z, efb.w};
    float acc[8] = {0,0,0,0,0,0,0,0};
    float gg0 = 0.f, gg1 = 0.f, gg2 = 0.f;
    const float4* gmR = (const float4*)(gA0 + (size_t)rv * KK);
    const float4* sjR = (const float4*)(su1 + (size_t)sn * KK);
    const float4* gxR = (const float4*)(gA1 + (size_t)rv * 384);
    const float4* gyR = gxR + 32;
    const float4* gzR = gxR + 64;
    for (int cc = 0; cc < 32; cc++) {
        float4 gm = gmR[cc], sj = sjR[cc], gx = gxR[cc], gy = gyR[cc], gz = gzR[cc];
#pragma unroll
        for (int k = 0; k < 4; k++) {
            float gmE = ((const float*)&gm)[k];
            float sjE = ((const float*)&sj)[k];
            float g1E = ((const float*)&gx)[k];
            float g2E = ((const float*)&gy)[k];
            float g3E = ((const float*)&gz)[k];
            float q = g1E*y0 + g2E*y1 + g3E*y2;
            float gwa = gmE * sjE;
            float gwb = q * sjE;
            float w = 0.f;
            int c = cc*4 + k;
#pragma unroll
            for (int b = 0; b < 8; b++) {
                float r1a = R1[b*256 + c];
                float r1b = R1[b*256 + 128 + c];
                acc[b] += gwa * r1a + gwb * r1b;
                w += efv[b] * r1b;
            }
            float ws = w * sjE;
            gg0 += g1E * ws; gg1 += g2E * ws; gg2 += g3E * ws;
        }
    }
    float4 o0 = make_float4(acc[0], acc[1], acc[2], acc[3]);
    float4 o1 = make_float4(acc[4], acc[5], acc[6], acc[7]);
    ((float4*)gefB)[e*2] = o0; ((float4*)gefB)[e*2+1] = o1;
    gyB[e*3+0] = gg0; gyB[e*3+1] = gg1; gyB[e*3+2] = gg2;
}

// ---------------- final: per-edge g_vec -> forces ----------------
__global__ void k_force(const float* __restrict__ gefA, const float* __restrict__ gefB,
                        const float* __restrict__ defdr,
                        const float* __restrict__ gyA, const float* __restrict__ gyB,
                        const float* __restrict__ Y1,
                        const float* __restrict__ rr, const int* __restrict__ ei,
                        float* __restrict__ forces) {
    int e = blockIdx.x * blockDim.x + threadIdx.x;
    if (e >= EE) return;
    float gr = 0.f;
#pragma unroll
    for (int b = 0; b < 8; b++) gr += (gefA[e*8+b] + gefB[e*8+b]) * defdr[e*8+b];
    float y0 = Y1[e*3+0], y1 = Y1[e*3+1], y2 = Y1[e*3+2];
    float g0 = gyA[e*3+0] + gyB[e*3+0];
    float g1 = gyA[e*3+1] + gyB[e*3+1];
    float g2 = gyA[e*3+2] + gyB[e*3+2];
    float ir = 1.f / rr[e];
    float dot = g0*y0 + g1*y1 + g2*y2;
    float a = gr * INV_SQ3;
    float b2 = SQ3F * ir;
    float c = b2 * dot * (1.f / 3.f);
    float gv0 = a*y0 + b2*g0 - c*y0;
    float gv1 = a*y1 + b2*g1 - c*y1;
    float gv2 = a*y2 + b2*g2 - c*y2;
    int sn = ei[e], rv = ei[EE + e];
    atomAddF(&forces[rv*3+0], -gv0); atomAddF(&forces[rv*3+1], -gv1); atomAddF(&forces[rv*3+2], -gv2);
    atomAddF(&forces[sn*3+0],  gv0); atomAddF(&forces[sn*3+1],  gv1); atomAddF(&forces[sn*3+2],  gv2);
}

extern "C" void kernel_launch(void* const* d_in, const int* in_sizes, int n_in,
                              void* d_out, int out_size, void* d_ws, size_t ws_size,
                              hipStream_t stream) {
    const float* positions  = (const float*)d_in[0];
    const float* shifts     = (const float*)d_in[1];
    const int*   edge_index = (const int*)d_in[2];
    const int*   node_z     = (const int*)d_in[3];
    const int*   batch      = (const int*)d_in[4];
    const float* atomic_e   = (const float*)d_in[5];
    const float* W_embed    = (const float*)d_in[6];
    const float* R1         = (const float*)d_in[7];
    const float* W_up1      = (const float*)d_in[8];
    const float* W_mix_s1   = (const float*)d_in[9];
    const float* W_mix_v1   = (const float*)d_in[10];
    const float* W_sk_s1    = (const float*)d_in[11];
    const float* w_r1       = (const float*)d_in[12];
    const float* R2         = (const float*)d_in[13];
    const float* W_up2s     = (const float*)d_in[14];
    const float* W_up2v     = (const float*)d_in[15];
    const float* W_mix_s2   = (const float*)d_in[16];
    const float* W_sk_s2    = (const float*)d_in[17];
    const float* W_mlp      = (const float*)d_in[18];
    const float* w_out      = (const float*)d_in[19];

    float* out = (float*)d_out;
    float* ws = (float*)d_ws;
    size_t off = 0;
    float* ef    = ws + off; off += (size_t)EE * 8;
    float* defdr = ws + off; off += (size_t)EE * 8;
    float* Y1    = ws + off; off += (size_t)EE * 3;
    float* rr    = ws + off; off += (size_t)EE;
    float* gefA  = ws + off; off += (size_t)EE * 8;
    float* gyA   = ws + off; off += (size_t)EE * 3;
    float* gefB  = ws + off; off += (size_t)EE * 8;
    float* gyB   = ws + off; off += (size_t)EE * 3;
    float* su1   = ws + off; off += (size_t)NN * KK;
    float* s1    = ws + off; off += (size_t)NN * KK;
    float* s1u2  = ws + off; off += (size_t)NN * KK;
    float* s2    = ws + off; off += (size_t)NN * KK;
    float* g_s2  = ws + off; off += (size_t)NN * KK;
    float* g_s1  = ws + off; off += (size_t)NN * KK;
    float* vup   = ws + off; off += (size_t)NN * KK * 3;
    float* A0    = ws + off; off += (size_t)NN * KK;       // later g_A0
    float* A2    = ws + off; off += (size_t)NN * KK;       // later g_A2
    float* Gsj2  = ws + off; off += (size_t)NN * KK;
    float* A1    = ws + off; off += (size_t)NN * KK * 3;   // later g_A1
    float* Gvj   = ws + off; off += (size_t)NN * KK * 3;
    float* E1    = ws + off; off += 10 * KK;
    float* T1    = ws + off; off += 10 * KK;
    float* Wc    = ws + off; off += KK * KK;
    float* e1n   = ws + off; off += NN;
    float* e2n   = ws + off; off += NN;
    // int region (8B aligned: off is even)
    int* ip = (int*)(ws + off);
    size_t ioff = 0;
    int* deg_r = ip + ioff; ioff += NN;
    int* deg_s = ip + ioff; ioff += NN;
    int* cur_r = ip + ioff; ioff += NN;
    int* cur_s = ip + ioff; ioff += NN;
    int* zcnt  = ip + ioff; ioff += 16;
    int* zcur  = ip + ioff; ioff += 16;
    int* row_r = ip + ioff; ioff += NN + 2;
    int* row_s = ip + ioff; ioff += NN + 2;
    int* zrow  = ip + ioff; ioff += 16;
    int* zlist = ip + ioff; ioff += NN;
    int2* list_r = (int2*)(ip + ioff); ioff += (size_t)EE * 2;
    int2* list_s = (int2*)(ip + ioff); ioff += (size_t)EE * 2;

    hipMemsetAsync(out, 0, (size_t)out_size * sizeof(float), stream);
    hipMemsetAsync(deg_r, 0, ((size_t)4 * NN + 32) * sizeof(int), stream);  // deg_r..zcur

    // ---- CSR build + buckets + geometry + tables ----
    k_edge_geom<<<(EE + 255) / 256, 256, 0, stream>>>(positions, shifts, edge_index, ef, defdr, Y1, rr);
    k_hist<<<(EE + 255) / 256, 256, 0, stream>>>(edge_index, deg_r, deg_s);
    k_scan<<<1, 1024, 0, stream>>>(deg_r, deg_s, row_r, row_s);
    k_fill<<<(EE + 255) / 256, 256, 0, stream>>>(edge_index, row_r, row_s, cur_r, cur_s, list_r, list_s);
    k_zcount<<<(NN + 255) / 256, 256, 0, stream>>>(node_z, zcnt);
    k_zscan<<<1, 64, 0, stream>>>(zcnt, zrow);
    k_zfill<<<(NN + 255) / 256, 256, 0, stream>>>(node_z, zcur, zrow, zlist);
    k_tables<<<10, 128, 0, stream>>>(W_embed, W_up1, W_sk_s1, E1, T1);
    k_gemm<0><<<(KK + 63) / 64, 256, 0, stream>>>(W_mix_v1, W_up2v, Wc, KK, 1.f, 0);  // Wc = W_mix_v1 @ W_up2v
    // ---- forward ----
    k_zinit<<<(NN * KK + 255) / 256, 256, 0, stream>>>(su1, E1, node_z);
    k_edge1_g<<<(NN + 3) / 4, 256, 0, stream>>>(ef, Y1, R1, su1, row_r, list_r, A0, A1);
    k_zinit<<<(NN * KK + 255) / 256, 256, 0, stream>>>(s1, T1, node_z);
    k_gemm<0><<<(NN + 63) / 64, 256, 0, stream>>>(A0, W_mix_s1, s1, NN, INV_AVG, 1);
    k_gemm<0><<<(NN * 3 + 63) / 64, 256, 0, stream>>>(A1, Wc, vup, NN * 3, INV_AVG, 0);
    k_gemm<0><<<(NN + 63) / 64, 256, 0, stream>>>(s1, W_up2s, s1u2, NN, 1.f, 0);
    k_edge2_g<<<(NN + 3) / 4, 256, 0, stream>>>(ef, Y1, R2, s1u2, vup, row_r, list_r, A2);
    { dim3 g(10, 24); k_skip<0, 0><<<g, 256, 0, stream>>>(s1, W_sk_s2, zrow, zlist, s2); }
    k_gemm<0><<<(NN + 63) / 64, 256, 0, stream>>>(A2, W_mix_s2, s2, NN, INV_AVG, 1);
    // ---- energy head + backward seed ----
    k_mlp<<<NN, 128, 0, stream>>>(s2, W_mlp, w_out, w_r1, s1, g_s2, g_s1, e1n, e2n);
    k_energy<<<32, 256, 0, stream>>>(node_z, batch, atomic_e, e1n, e2n, out);
    // ---- backward ----
    k_gemm<1><<<(NN + 63) / 64, 256, 0, stream>>>(g_s2, W_mix_s2, A2, NN, INV_AVG, 0);   // g_A2 -> A2
    { dim3 g(10, 24); k_skip<1, 1><<<g, 256, 0, stream>>>(g_s2, W_sk_s2, zrow, zlist, g_s1); }
    k_bwdA_e<<<(EE + 255) / 256, 256, 0, stream>>>(ef, Y1, edge_index, R2, A2, s1u2, vup, list_s, gefA, gyA);
    k_bwdA_n<<<(NN + 3) / 4, 256, 0, stream>>>(ef, Y1, R2, A2, row_s, list_s, Gsj2, Gvj);
    k_gemm<1><<<(NN + 63) / 64, 256, 0, stream>>>(Gsj2, W_up2s, g_s1, NN, 1.f, 1);
    k_gemm<1><<<(NN * 3 + 63) / 64, 256, 0, stream>>>(Gvj, Wc, A1, NN * 3, INV_AVG, 0);  // g_A1 -> A1
    k_gemm<1><<<(NN + 63) / 64, 256, 0, stream>>>(g_s1, W_mix_s1, A0, NN, INV_AVG, 0);   // g_A0 -> A0
    k_bwdB_e<<<(EE + 255) / 256, 256, 0, stream>>>(ef, Y1, edge_index, R1, su1, A0, A1, list_r, gefB, gyB);
    k_force<<<(EE + 255) / 256, 256, 0, stream>>>(gefA, gefB, defdr, gyA, gyB, Y1, rr, edge_index, out + GG + GG * 3);
}

// Round 6
// 516.619 us; speedup vs baseline: 4.2093x; 1.3927x over previous
//
#include <hip/hip_runtime.h>
#include <math.h>

#define NN 10000
#define EE 160000
#define KK 128
#define GG 16
#define NE 10
#define SQ3F 1.7320508075688772f
#define INV_SQ3 0.57735026918962576f
#define INV_AVG 0.0625f
#define RMAXI 0.2f

__device__ __forceinline__ void atomAddF(float* p, float v) { unsafeAtomicAdd(p, v); }

__device__ __forceinline__ float waveRed(float v) {
#pragma unroll
    for (int m = 32; m >= 1; m >>= 1) v += __shfl_xor(v, m);
    return v;
}

// ---------------- edge geometry + ACTIVE-EDGE COMPACTION ----------------
// Edges with r >= R_MAX have fcut=0 -> ef=defdr=0 -> exactly zero contribution to
// energies AND forces (gradient through where() is zero too). Only ~6% survive.
__global__ void k_edge_geom(const float* __restrict__ pos, const float* __restrict__ shifts,
                            const int* __restrict__ ei,
                            float* __restrict__ ef, float* __restrict__ defdr,
                            float* __restrict__ Y1, float* __restrict__ rr,
                            int2* __restrict__ cei, int* __restrict__ nact) {
    int e = blockIdx.x * blockDim.x + threadIdx.x;
    if (e >= EE) return;
    int sn = ei[e], rv = ei[EE + e];
    float vx = pos[rv*3+0] - pos[sn*3+0] + shifts[e*3+0];
    float vy = pos[rv*3+1] - pos[sn*3+1] + shifts[e*3+1];
    float vz = pos[rv*3+2] - pos[sn*3+2] + shifts[e*3+2];
    float r = sqrtf(vx*vx + vy*vy + vz*vz + 1e-12f);
    float x = r * RMAXI;
    if (x >= 1.0f) return;                 // inactive edge: contributes exactly 0
    int idx = atomicAdd(nact, 1);
    cei[idx] = make_int2(sn, rv);
    float ir = 1.0f / r;
    rr[idx] = r;
    Y1[idx*3+0] = SQ3F*vx*ir; Y1[idx*3+1] = SQ3F*vy*ir; Y1[idx*3+2] = SQ3F*vz*ir;
    float x2 = x*x, x4 = x2*x2, x5 = x4*x, x6 = x5*x, x7 = x6*x;
    float fc  = 1.0f - 21.0f*x5 + 35.0f*x6 - 15.0f*x7;
    float dfc = (-105.0f*x4 + 210.0f*x5 - 105.0f*x6) * RMAXI;
    const float C = 0.63245553203367587f; // sqrt(2/5)
    float4 efa, efb4, da, db;
    float* efp = (float*)&efa; float* dp = (float*)&da;
#pragma unroll
    for (int b = 0; b < 8; b++) {
        float kb = (float)(b + 1) * 0.62831853071795865f; // (b+1)*pi/5
        float sb, cb;
        sincosf(kb * r, &sb, &cb);
        float bess  = C * sb * ir;
        float dbess = C * ir * (kb * cb - sb * ir);
        if (b == 4) { efp = (float*)&efb4; dp = (float*)&db; }
        efp[b & 3] = bess * fc;
        dp[b & 3]  = dbess * fc + bess * dfc;
    }
    ((float4*)ef)[idx*2]      = efa; ((float4*)ef)[idx*2+1]    = efb4;
    ((float4*)defdr)[idx*2]   = da;  ((float4*)defdr)[idx*2+1] = db;
}

// ---------------- CSR build (over compacted edges) ----------------
__global__ void k_hist(const int2* __restrict__ cei, const int* __restrict__ nact,
                       int* __restrict__ deg_r, int* __restrict__ deg_s) {
    int i = blockIdx.x * blockDim.x + threadIdx.x;
    if (i >= *nact) return;
    int2 p = cei[i];
    atomicAdd(&deg_s[p.x], 1);
    atomicAdd(&deg_r[p.y], 1);
}

__global__ __launch_bounds__(1024) void k_scan(const int* __restrict__ deg_r, const int* __restrict__ deg_s,
                                               int* __restrict__ row_r, int* __restrict__ row_s) {
    __shared__ int part[1024];
    int t = threadIdx.x;
    for (int a = 0; a < 2; a++) {
        const int* deg = a ? deg_s : deg_r;
        int* row = a ? row_s : row_r;
        int base = t * 10;
        int loc[10];
        int s = 0;
#pragma unroll
        for (int k = 0; k < 10; k++) {
            loc[k] = s;
            if (base + k < NN) s += deg[base + k];
        }
        part[t] = s;
        __syncthreads();
        for (int off = 1; off < 1024; off <<= 1) {
            int v = (t >= off) ? part[t - off] : 0;
            __syncthreads();
            part[t] += v;
            __syncthreads();
        }
        int bex = (t > 0) ? part[t - 1] : 0;
#pragma unroll
        for (int k = 0; k < 10; k++)
            if (base + k < NN) row[base + k] = bex + loc[k];
        if (t == 1023) row[NN] = part[1023];
        __syncthreads();
    }
}

__global__ void k_fill(const int2* __restrict__ cei, const int* __restrict__ nact,
                       const int* __restrict__ row_r, const int* __restrict__ row_s,
                       int* __restrict__ cur_r, int* __restrict__ cur_s,
                       int2* __restrict__ list_r, int2* __restrict__ list_s) {
    int i = blockIdx.x * blockDim.x + threadIdx.x;
    if (i >= *nact) return;
    int2 p = cei[i];
    int sn = p.x, rv = p.y;
    int pr = atomicAdd(&cur_r[rv], 1);
    list_r[row_r[rv] + pr] = make_int2(i, sn);
    int ps = atomicAdd(&cur_s[sn], 1);
    list_s[row_s[sn] + ps] = make_int2(i, rv);
}

// ---------------- z buckets ----------------
__global__ void k_zcount(const int* __restrict__ z, int* __restrict__ zcnt) {
    __shared__ int h[NE];
    if (threadIdx.x < NE) h[threadIdx.x] = 0;
    __syncthreads();
    int n = blockIdx.x * 256 + threadIdx.x;
    if (n < NN) atomicAdd(&h[z[n]], 1);
    __syncthreads();
    if (threadIdx.x < NE && h[threadIdx.x] > 0) atomicAdd(&zcnt[threadIdx.x], h[threadIdx.x]);
}

__global__ void k_zscan(const int* __restrict__ zcnt, int* __restrict__ zrow) {
    if (threadIdx.x == 0) {
        int s = 0;
        for (int i = 0; i < NE; i++) { zrow[i] = s; s += zcnt[i]; }
        zrow[NE] = s;
    }
}

__global__ void k_zfill(const int* __restrict__ z, int* __restrict__ zcur, const int* __restrict__ zrow,
                        int* __restrict__ zlist) {
    __shared__ int cnt[NE];
    __shared__ int base[NE];
    int t = threadIdx.x;
    if (t < NE) cnt[t] = 0;
    __syncthreads();
    int n = blockIdx.x * 256 + t;
    int pos = -1, zz = 0;
    if (n < NN) { zz = z[n]; pos = atomicAdd(&cnt[zz], 1); }
    __syncthreads();
    if (t < NE && cnt[t] > 0) base[t] = atomicAdd(&zcur[t], cnt[t]);
    __syncthreads();
    if (n < NN) zlist[zrow[zz] + base[zz] + pos] = n;
}

// ---------------- z-tables ----------------
__global__ void k_tables(const float* __restrict__ We, const float* __restrict__ Wup1,
                         const float* __restrict__ Wsk1, float* __restrict__ E1, float* __restrict__ T1) {
    int zz = blockIdx.x, d = threadIdx.x;
    float a = 0.f, bv = 0.f;
    for (int c = 0; c < KK; c++) {
        float w = We[zz*KK + c];
        a  += w * Wup1[c*KK + d];
        bv += w * Wsk1[(size_t)(zz*KK + c)*KK + d];
    }
    E1[zz*KK + d] = a;
    T1[zz*KK + d] = bv;
}

// write both su1 and s1 in one pass
__global__ void k_zinit2(float* __restrict__ o1, const float* __restrict__ t1,
                         float* __restrict__ o2, const float* __restrict__ t2,
                         const int* __restrict__ z) {
    int i = blockIdx.x * blockDim.x + threadIdx.x;
    if (i >= NN * KK) return;
    int base = z[i >> 7] * KK + (i & 127);
    o1[i] = t1[base];
    o2[i] = t2[base];
}

// ============ register-tiled K x K GEMM ============
template <int TRANS>
__global__ __launch_bounds__(256) void k_gemm(const float* __restrict__ in, const float* __restrict__ W,
                                              float* __restrict__ out, int rows, float alpha, int accum) {
    __shared__ float WL[KK * KK];
    int t = threadIdx.x;
    for (int i = t; i < KK * KK; i += 256) {
        float v = W[i];
        int a = i >> 7, b = i & 127;
        int k = TRANS ? b : a;
        int c = TRANS ? a : b;
        WL[k * KK + ((((c >> 2) + k) & 31) << 2) + (c & 3)] = v;
    }
    __syncthreads();
    int g0 = t & 31;
    int cg = g0 << 2;
    int r0 = blockIdx.x * 64 + ((t >> 5) << 3);
    const float* Ap[8];
#pragma unroll
    for (int j = 0; j < 8; j++) {
        int r = r0 + j; if (r > rows - 1) r = rows - 1;
        Ap[j] = in + (size_t)r * KK;
    }
    float acc[8][4];
#pragma unroll
    for (int j = 0; j < 8; j++) { acc[j][0] = acc[j][1] = acc[j][2] = acc[j][3] = 0.f; }
#pragma unroll 2
    for (int k = 0; k < KK; k += 4) {
        float4 w0 = *(const float4*)&WL[(k+0)*KK + (((g0 + k + 0) & 31) << 2)];
        float4 w1 = *(const float4*)&WL[(k+1)*KK + (((g0 + k + 1) & 31) << 2)];
        float4 w2 = *(const float4*)&WL[(k+2)*KK + (((g0 + k + 2) & 31) << 2)];
        float4 w3 = *(const float4*)&WL[(k+3)*KK + (((g0 + k + 3) & 31) << 2)];
#pragma unroll
        for (int j = 0; j < 8; j++) {
            float4 a = *(const float4*)(Ap[j] + k);
            acc[j][0] += a.x*w0.x + a.y*w1.x + a.z*w2.x + a.w*w3.x;
            acc[j][1] += a.x*w0.y + a.y*w1.y + a.z*w2.y + a.w*w3.y;
            acc[j][2] += a.x*w0.z + a.y*w1.z + a.z*w2.z + a.w*w3.z;
            acc[j][3] += a.x*w0.w + a.y*w1.w + a.z*w2.w + a.w*w3.w;
        }
    }
#pragma unroll
    for (int j = 0; j < 8; j++) {
        int r = r0 + j;
        if (r < rows) {
            float4* o = (float4*)(out + (size_t)r * KK + cg);
            float4 v = make_float4(acc[j][0]*alpha, acc[j][1]*alpha, acc[j][2]*alpha, acc[j][3]*alpha);
            if (accum) { float4 old = *o; v.x += old.x; v.y += old.y; v.z += old.z; v.w += old.w; }
            *o = v;
        }
    }
}

// ============ per-z skip as bucketed tiled GEMM ============
template <int TRANS, int ACCUM>
__global__ __launch_bounds__(256) void k_skip(const float* __restrict__ in, const float* __restrict__ Wall,
                                              const int* __restrict__ zrow, const int* __restrict__ zlist,
                                              float* __restrict__ out) {
    int zz = blockIdx.x;
    int beg = zrow[zz], cnt = zrow[zz + 1] - beg;
    if (cnt == 0) return;
    __shared__ float WL[KK * KK];
    const float* W = Wall + (size_t)zz * (KK * KK);
    int t = threadIdx.x;
    for (int i = t; i < KK * KK; i += 256) {
        float v = W[i];
        int a = i >> 7, b = i & 127;
        int k = TRANS ? b : a;
        int c = TRANS ? a : b;
        WL[k * KK + ((((c >> 2) + k) & 31) << 2) + (c & 3)] = v;
    }
    __syncthreads();
    int g0 = t & 31;
    int cg = g0 << 2;
    int rg = (t >> 5) << 3;
    for (int ch = blockIdx.y; ch * 64 < cnt; ch += gridDim.y) {
        int i0 = ch * 64 + rg;
        int rowv[8];
        const float* Ap[8];
#pragma unroll
        for (int j = 0; j < 8; j++) {
            int idx = i0 + j; if (idx > cnt - 1) idx = cnt - 1;
            rowv[j] = zlist[beg + idx];
            Ap[j] = in + (size_t)rowv[j] * KK;
        }
        float acc[8][4];
#pragma unroll
        for (int j = 0; j < 8; j++) { acc[j][0] = acc[j][1] = acc[j][2] = acc[j][3] = 0.f; }
#pragma unroll 2
        for (int k = 0; k < KK; k += 4) {
            float4 w0 = *(const float4*)&WL[(k+0)*KK + (((g0 + k + 0) & 31) << 2)];
            float4 w1 = *(const float4*)&WL[(k+1)*KK + (((g0 + k + 1) & 31) << 2)];
            float4 w2 = *(const float4*)&WL[(k+2)*KK + (((g0 + k + 2) & 31) << 2)];
            float4 w3 = *(const float4*)&WL[(k+3)*KK + (((g0 + k + 3) & 31) << 2)];
#pragma unroll
            for (int j = 0; j < 8; j++) {
                float4 a = *(const float4*)(Ap[j] + k);
                acc[j][0] += a.x*w0.x + a.y*w1.x + a.z*w2.x + a.w*w3.x;
                acc[j][1] += a.x*w0.y + a.y*w1.y + a.z*w2.y + a.w*w3.y;
                acc[j][2] += a.x*w0.z + a.y*w1.z + a.z*w2.z + a.w*w3.z;
                acc[j][3] += a.x*w0.w + a.y*w1.w + a.z*w2.w + a.w*w3.w;
            }
        }
#pragma unroll
        for (int j = 0; j < 8; j++) {
            if (i0 + j < cnt) {
                float4* o = (float4*)(out + (size_t)rowv[j] * KK + cg);
                float4 v = make_float4(acc[j][0], acc[j][1], acc[j][2], acc[j][3]);
                if (ACCUM) { float4 old = *o; v.x += old.x; v.y += old.y; v.z += old.z; v.w += old.w; }
                *o = v;
            }
        }
    }
}

// ---------------- edge pass 1 (rcv-centric gather): A0[n], A1[n] ----------------
__global__ __launch_bounds__(256) void k_edge1_g(const float* __restrict__ ef, const float* __restrict__ Y1,
                                                 const float* __restrict__ R1, const float* __restrict__ su1,
                                                 const int* __restrict__ row_r, const int2* __restrict__ list_r,
                                                 float* __restrict__ A0, float* __restrict__ A1) {
    __shared__ float RL[2048];
    for (int i = threadIdx.x; i < 2048; i += 256) RL[i] = R1[i];
    __syncthreads();
    int lane = threadIdx.x & 63;
    int n = blockIdx.x * 4 + (threadIdx.x >> 6);
    if (n >= NN) return;
    int c0 = lane, c1 = lane + 64;
    float a00 = 0.f, a01 = 0.f;
    float ax0 = 0.f, ax1 = 0.f, ay0 = 0.f, ay1 = 0.f, az0 = 0.f, az1 = 0.f;
    int beg = row_r[n], end = row_r[n + 1];
    for (int i = beg; i < end; i++) {
        int2 p = list_r[i];
        int e = p.x, sn = p.y;
        float4 efa = ((const float4*)ef)[e*2], efb4 = ((const float4*)ef)[e*2+1];
        float y0 = Y1[e*3+0], y1 = Y1[e*3+1], y2 = Y1[e*3+2];
        float wa0 = 0, wa1 = 0, wb0 = 0, wb1 = 0;
        const float* eb = (const float*)&efa;
#pragma unroll
        for (int b = 0; b < 8; b++) {
            if (b == 4) eb = (const float*)&efb4;
            float v = eb[b & 3];
            wa0 += v * RL[b*256 + c0];       wb0 += v * RL[b*256 + 128 + c0];
            wa1 += v * RL[b*256 + c1];       wb1 += v * RL[b*256 + 128 + c1];
        }
        float sj0 = su1[sn*KK + c0], sj1 = su1[sn*KK + c1];
        a00 += wa0 * sj0; a01 += wa1 * sj1;
        float mb0 = wb0 * sj0, mb1 = wb1 * sj1;
        ax0 += mb0*y0; ax1 += mb1*y0;
        ay0 += mb0*y1; ay1 += mb1*y1;
        az0 += mb0*y2; az1 += mb1*y2;
    }
    A0[(size_t)n*KK + c0] = a00;  A0[(size_t)n*KK + c1] = a01;
    float* A1r = A1 + (size_t)n * 384;
    A1r[c0] = ax0;        A1r[c1] = ax1;
    A1r[128 + c0] = ay0;  A1r[128 + c1] = ay1;
    A1r[256 + c0] = az0;  A1r[256 + c1] = az1;
}

// ---------------- edge pass 2 (rcv-centric gather): A2[n] ----------------
__global__ __launch_bounds__(256) void k_edge2_g(const float* __restrict__ ef, const float* __restrict__ Y1,
                                                 const float* __restrict__ R2, const float* __restrict__ s1u2,
                                                 const float* __restrict__ vup,
                                                 const int* __restrict__ row_r, const int2* __restrict__ list_r,
                                                 float* __restrict__ A2) {
    __shared__ float RL[2048];
    for (int i = threadIdx.x; i < 2048; i += 256) RL[i] = R2[(i >> 8) * 512 + (i & 255)];
    __syncthreads();
    int lane = threadIdx.x & 63;
    int n = blockIdx.x * 4 + (threadIdx.x >> 6);
    if (n >= NN) return;
    int c0 = lane, c1 = lane + 64;
    float a0 = 0.f, a1 = 0.f;
    int beg = row_r[n], end = row_r[n + 1];
    for (int i = beg; i < end; i++) {
        int2 p = list_r[i];
        int e = p.x, sn = p.y;
        float4 efa = ((const float4*)ef)[e*2], efb4 = ((const float4*)ef)[e*2+1];
        float y0 = Y1[e*3+0], y1 = Y1[e*3+1], y2 = Y1[e*3+2];
        float w00_0 = 0, w00_1 = 0, w110_0 = 0, w110_1 = 0;
        const float* eb = (const float*)&efa;
#pragma unroll
        for (int b = 0; b < 8; b++) {
            if (b == 4) eb = (const float*)&efb4;
            float v = eb[b & 3];
            w00_0  += v * RL[b*256 + c0];      w110_0 += v * RL[b*256 + 128 + c0];
            w00_1  += v * RL[b*256 + c1];      w110_1 += v * RL[b*256 + 128 + c1];
        }
        float sj0 = s1u2[sn*KK + c0], sj1 = s1u2[sn*KK + c1];
        const float* vu = vup + (size_t)sn * 384;
        float tt0 = (vu[c0]*y0 + vu[128 + c0]*y1 + vu[256 + c0]*y2) * INV_SQ3;
        float tt1 = (vu[c1]*y0 + vu[128 + c1]*y1 + vu[256 + c1]*y2) * INV_SQ3;
        a0 += w00_0 * sj0 + w110_0 * tt0;
        a1 += w00_1 * sj1 + w110_1 * tt1;
    }
    A2[(size_t)n*KK + c0] = a0;
    A2[(size_t)n*KK + c1] = a1;
}

// ---------------- MLP energy head + e1 + backward seed ----------------
__global__ __launch_bounds__(128) void k_mlp(const float* __restrict__ s2, const float* __restrict__ W_mlp,
                                             const float* __restrict__ w_out, const float* __restrict__ w_r1,
                                             const float* __restrict__ s1,
                                             float* __restrict__ g_s2, float* __restrict__ g_s1,
                                             float* __restrict__ e1n, float* __restrict__ e2n) {
    __shared__ float WmL[KK * 17];
    __shared__ float s2L[KK];
    __shared__ float ghL[16];
    __shared__ float eL[16];
    __shared__ float pw[2];
    int n = blockIdx.x, t = threadIdx.x;
    for (int i = t; i < KK * 16; i += 128) WmL[(i >> 4) * 17 + (i & 15)] = W_mlp[i];
    s2L[t] = s2[(size_t)n * KK + t];
    float wr = w_r1[t];
    float p = s1[(size_t)n * KK + t] * wr;
    p = waveRed(p);
    if ((t & 63) == 0) pw[t >> 6] = p;
    __syncthreads();
    if (t < 16) {
        float h = 0.f;
        for (int c = 0; c < KK; c++) h += s2L[c] * WmL[c * 17 + t];
        float sg = 1.f / (1.f + expf(-h));
        eL[t]  = h * sg * w_out[t];
        ghL[t] = w_out[t] * sg * (1.f + h * (1.f - sg));
    }
    __syncthreads();
    if (t == 0) {
        float e = 0.f;
#pragma unroll
        for (int j = 0; j < 16; j++) e += eL[j];
        e2n[n] = e;
        e1n[n] = pw[0] + pw[1];
    }
    float g = 0.f;
#pragma unroll
    for (int j = 0; j < 16; j++) g += ghL[j] * WmL[t * 17 + j];
    g_s2[(size_t)n * KK + t] = g;
    g_s1[(size_t)n * KK + t] = wr;
}

// ---------------- energy reduction ----------------
__global__ __launch_bounds__(256) void k_energy(const int* __restrict__ z, const int* __restrict__ batch,
                                                const float* __restrict__ ae,
                                                const float* __restrict__ e1n, const float* __restrict__ e2n,
                                                float* __restrict__ out) {
    __shared__ float bins[GG * 4];
    for (int i = threadIdx.x; i < GG * 4; i += 256) bins[i] = 0.f;
    __syncthreads();
    int idx = blockIdx.x * 256 + threadIdx.x;
    int stride = gridDim.x * 256;
    for (int n = idx; n < NN; n += stride) {
        int b = batch[n];
        float v0 = ae[z[n]], v1 = e1n[n], v2 = e2n[n];
        atomicAdd(&bins[b*4+0], v0 + v1 + v2);
        atomicAdd(&bins[b*4+1], v0);
        atomicAdd(&bins[b*4+2], v1);
        atomicAdd(&bins[b*4+3], v2);
    }
    __syncthreads();
    for (int i = threadIdx.x; i < GG * 4; i += 256) {
        float v = bins[i];
        if (v != 0.f) {
            int b = i >> 2, k = i & 3;
            float* dst = (k == 0) ? &out[b] : &out[GG + b*3 + (k - 1)];
            atomAddF(dst, v);
        }
    }
}

// ---------------- backward layer2, per-edge outputs (thread = edge) ----------------
__global__ __launch_bounds__(256) void k_bwdA_e(const float* __restrict__ ef8, const float* __restrict__ Y1,
                                                const int2* __restrict__ cei, const int* __restrict__ nact,
                                                const float* __restrict__ R2,
                                                const float* __restrict__ gA2, const float* __restrict__ s1u2,
                                                const float* __restrict__ vup, const int2* __restrict__ list_s,
                                                float* __restrict__ gefA, float* __restrict__ gyA) {
    int i = blockIdx.x * 256 + threadIdx.x;
    if (i >= *nact) return;
    int2 p = list_s[i];
    int e = p.x, rv = p.y;
    int sn = cei[e].x;
    float y0 = Y1[e*3+0], y1 = Y1[e*3+1], y2 = Y1[e*3+2];
    float4 efa = ((const float4*)ef8)[e*2], efb = ((const float4*)ef8)[e*2+1];
    float efv[8] = {efa.x, efa.y, efa.z, efa.w, efb.x, efb.y, efb.z, efb.w};
    float acc[8] = {0,0,0,0,0,0,0,0};
    float g0 = 0.f, g1 = 0.f, g2 = 0.f;
    const float4* gaR = (const float4*)(gA2 + (size_t)rv * KK);
    const float4* sjR = (const float4*)(s1u2 + (size_t)sn * KK);
    const float4* vxR = (const float4*)(vup + (size_t)sn * 384);
    const float4* vyR = vxR + 32;
    const float4* vzR = vxR + 64;
    for (int cc = 0; cc < 32; cc++) {
        float4 ga = gaR[cc], sj = sjR[cc], vx = vxR[cc], vy = vyR[cc], vz = vzR[cc];
#pragma unroll
        for (int k = 0; k < 4; k++) {
            float gaE = ((const float*)&ga)[k];
            float sjE = ((const float*)&sj)[k];
            float vxE = ((const float*)&vx)[k];
            float vyE = ((const float*)&vy)[k];
            float vzE = ((const float*)&vz)[k];
            float tt = (vxE*y0 + vyE*y1 + vzE*y2) * INV_SQ3;
            float gw00 = gaE * sjE;
            float gw110 = gaE * tt;
            float w110 = 0.f;
            int c = cc*4 + k;
#pragma unroll
            for (int b = 0; b < 8; b++) {
                float r2a = R2[b*512 + c];
                float r2b = R2[b*512 + 128 + c];
                acc[b] += gw00 * r2a + gw110 * r2b;
                w110 += efv[b] * r2b;
            }
            float gt = gaE * w110;
            g0 += gt * vxE; g1 += gt * vyE; g2 += gt * vzE;
        }
    }
    float4 o0 = make_float4(acc[0], acc[1], acc[2], acc[3]);
    float4 o1 = make_float4(acc[4], acc[5], acc[6], acc[7]);
    ((float4*)gefA)[e*2] = o0; ((float4*)gefA)[e*2+1] = o1;
    gyA[e*3+0] = g0 * INV_SQ3; gyA[e*3+1] = g1 * INV_SQ3; gyA[e*3+2] = g2 * INV_SQ3;
}

// ---------------- backward layer2, node sums Gsj2/Gvj ----------------
__global__ __launch_bounds__(256) void k_bwdA_n(const float* __restrict__ ef, const float* __restrict__ Y1,
                                                const float* __restrict__ R2, const float* __restrict__ gA2,
                                                const int* __restrict__ row_s, const int2* __restrict__ list_s,
                                                float* __restrict__ Gsj2, float* __restrict__ Gvj) {
    __shared__ float RL[2048];
    for (int i = threadIdx.x; i < 2048; i += 256) RL[i] = R2[(i >> 8) * 512 + (i & 255)];
    __syncthreads();
    int lane = threadIdx.x & 63;
    int sn = blockIdx.x * 4 + (threadIdx.x >> 6);
    if (sn >= NN) return;
    int c0 = lane, c1 = lane + 64;
    float gs0 = 0.f, gs1 = 0.f;
    float gv00 = 0.f, gv01 = 0.f, gv10 = 0.f, gv11 = 0.f, gv20 = 0.f, gv21 = 0.f;
    int beg = row_s[sn], end = row_s[sn + 1];
    for (int i = beg; i < end; i++) {
        int2 p = list_s[i];
        int e = p.x, rv = p.y;
        float4 efa = ((const float4*)ef)[e*2], efb4 = ((const float4*)ef)[e*2+1];
        float y0 = Y1[e*3+0], y1 = Y1[e*3+1], y2 = Y1[e*3+2];
        float w00_0 = 0, w00_1 = 0, w110_0 = 0, w110_1 = 0;
        const float* eb = (const float*)&efa;
#pragma unroll
        for (int b = 0; b < 8; b++) {
            if (b == 4) eb = (const float*)&efb4;
            float v = eb[b & 3];
            w00_0  += v * RL[b*256 + c0];      w110_0 += v * RL[b*256 + 128 + c0];
            w00_1  += v * RL[b*256 + c1];      w110_1 += v * RL[b*256 + 128 + c1];
        }
        float ga0 = gA2[(size_t)rv*KK + c0], ga1 = gA2[(size_t)rv*KK + c1];
        gs0 += ga0 * w00_0;
        gs1 += ga1 * w00_1;
        float gts0 = ga0 * w110_0 * INV_SQ3, gts1 = ga1 * w110_1 * INV_SQ3;
        gv00 += gts0*y0; gv01 += gts1*y0;
        gv10 += gts0*y1; gv11 += gts1*y1;
        gv20 += gts0*y2; gv21 += gts1*y2;
    }
    Gsj2[(size_t)sn*KK + c0] = gs0; Gsj2[(size_t)sn*KK + c1] = gs1;
    float* Gv = Gvj + (size_t)sn * 384;
    Gv[c0] = gv00;        Gv[c1] = gv01;
    Gv[128 + c0] = gv10;  Gv[128 + c1] = gv11;
    Gv[256 + c0] = gv20;  Gv[256 + c1] = gv21;
}

// ---------------- backward layer1, per-edge outputs (thread = edge) ----------------
__global__ __launch_bounds__(256) void k_bwdB_e(const float* __restrict__ ef8, const float* __restrict__ Y1,
                                                const int2* __restrict__ cei, const int* __restrict__ nact,
                                                const float* __restrict__ R1,
                                                const float* __restrict__ su1, const float* __restrict__ gA0,
                                                const float* __restrict__ gA1, const int2* __restrict__ list_r,
                                                float* __restrict__ gefB, float* __restrict__ gyB) {
    int i = blockIdx.x * 256 + threadIdx.x;
    if (i >= *nact) return;
    int2 p = list_r[i];
    int e = p.x, sn = p.y;
    int rv = cei[e].y;
    float y0 = Y1[e*3+0], y1 = Y1[e*3+1], y2 = Y1[e*3+2];
    float4 efa = ((const float4*)ef8)[e*2], efb = ((const float4*)ef8)[e*2+1];
    float efv[8] = {efa.x, efa.y, efa.z, efa.w, efb.x, efb.y, efb.z, efb.w};
    float acc[8] = {0,0,0,0,0,0,0,0};
    float gg0 = 0.f, gg1 = 0.f, gg2 = 0.f;
    const float4* gmR = (const float4*)(gA0 + (size_t)rv * KK);
    const float4* sjR = (const float4*)(su1 + (size_t)sn * KK);
    const float4* gxR = (const float4*)(gA1 + (size_t)rv * 384);
    const float4* gyR = gxR + 32;
    const float4* gzR = gxR + 64;
    for (int cc = 0; cc < 32; cc++) {
        float4 gm = gmR[cc], sj = sjR[cc], gx = gxR[cc], gy = gyR[cc], gz = gzR[cc];
#pragma unroll
        for (int k = 0; k < 4; k++) {
            float gmE = ((const float*)&gm)[k];
            float sjE = ((const float*)&sj)[k];
            float g1E = ((const float*)&gx)[k];
            float g2E = ((const float*)&gy)[k];
            float g3E = ((const float*)&gz)[k];
            float q = g1E*y0 + g2E*y1 + g3E*y2;
            float gwa = gmE * sjE;
            float gwb = q * sjE;
            float w = 0.f;
            int c = cc*4 + k;
#pragma unroll
            for (int b = 0; b < 8; b++) {
                float r1a = R1[b*256 + c];
                float r1b = R1[b*256 + 128 + c];
                acc[b] += gwa * r1a + gwb * r1b;
                w += efv[b] * r1b;
            }
            float ws = w * sjE;
            gg0 += g1E * ws; gg1 += g2E * ws; gg2 += g3E * ws;
        }
    }
    float4 o0 = make_float4(acc[0], acc[1], acc[2], acc[3]);
    float4 o1 = make_float4(acc[4], acc[5], acc[6], acc[7]);
    ((float4*)gefB)[e*2] = o0; ((float4*)gefB)[e*2+1] = o1;
    gyB[e*3+0] = gg0; gyB[e*3+1] = gg1; gyB[e*3+2] = gg2;
}

// ---------------- final: per-edge g_vec -> forces ----------------
__global__ void k_force(const float* __restrict__ gefA, const float* __restrict__ gefB,
                        const float* __restrict__ defdr,
                        const float* __restrict__ gyA, const float* __restrict__ gyB,
                        const float* __restrict__ Y1,
                        const float* __restrict__ rr, const int2* __restrict__ cei,
                        const int* __restrict__ nact, float* __restrict__ forces) {
    int e = blockIdx.x * blockDim.x + threadIdx.x;
    if (e >= *nact) return;
    float gr = 0.f;
#pragma unroll
    for (int b = 0; b < 8; b++) gr += (gefA[e*8+b] + gefB[e*8+b]) * defdr[e*8+b];
    float y0 = Y1[e*3+0], y1 = Y1[e*3+1], y2 = Y1[e*3+2];
    float g0 = gyA[e*3+0] + gyB[e*3+0];
    float g1 = gyA[e*3+1] + gyB[e*3+1];
    float g2 = gyA[e*3+2] + gyB[e*3+2];
    float ir = 1.f / rr[e];
    float dot = g0*y0 + g1*y1 + g2*y2;
    float a = gr * INV_SQ3;
    float b2 = SQ3F * ir;
    float c = b2 * dot * (1.f / 3.f);
    float gv0 = a*y0 + b2*g0 - c*y0;
    float gv1 = a*y1 + b2*g1 - c*y1;
    float gv2 = a*y2 + b2*g2 - c*y2;
    int2 p = cei[e];
    int sn = p.x, rv = p.y;
    atomAddF(&forces[rv*3+0], -gv0); atomAddF(&forces[rv*3+1], -gv1); atomAddF(&forces[rv*3+2], -gv2);
    atomAddF(&forces[sn*3+0],  gv0); atomAddF(&forces[sn*3+1],  gv1); atomAddF(&forces[sn*3+2],  gv2);
}

extern "C" void kernel_launch(void* const* d_in, const int* in_sizes, int n_in,
                              void* d_out, int out_size, void* d_ws, size_t ws_size,
                              hipStream_t stream) {
    const float* positions  = (const float*)d_in[0];
    const float* shifts     = (const float*)d_in[1];
    const int*   edge_index = (const int*)d_in[2];
    const int*   node_z     = (const int*)d_in[3];
    const int*   batch      = (const int*)d_in[4];
    const float* atomic_e   = (const float*)d_in[5];
    const float* W_embed    = (const float*)d_in[6];
    const float* R1         = (const float*)d_in[7];
    const float* W_up1      = (const float*)d_in[8];
    const float* W_mix_s1   = (const float*)d_in[9];
    const float* W_mix_v1   = (const float*)d_in[10];
    const float* W_sk_s1    = (const float*)d_in[11];
    const float* w_r1       = (const float*)d_in[12];
    const float* R2         = (const float*)d_in[13];
    const float* W_up2s     = (const float*)d_in[14];
    const float* W_up2v     = (const float*)d_in[15];
    const float* W_mix_s2   = (const float*)d_in[16];
    const float* W_sk_s2    = (const float*)d_in[17];
    const float* W_mlp      = (const float*)d_in[18];
    const float* w_out      = (const float*)d_in[19];

    float* out = (float*)d_out;
    float* ws = (float*)d_ws;
    size_t off = 0;
    float* ef    = ws + off; off += (size_t)EE * 8;
    float* defdr = ws + off; off += (size_t)EE * 8;
    float* Y1    = ws + off; off += (size_t)EE * 3;
    float* rr    = ws + off; off += (size_t)EE;
    float* gefA  = ws + off; off += (size_t)EE * 8;
    float* gyA   = ws + off; off += (size_t)EE * 3;
    float* gefB  = ws + off; off += (size_t)EE * 8;
    float* gyB   = ws + off; off += (size_t)EE * 3;
    float* su1   = ws + off; off += (size_t)NN * KK;
    float* s1    = ws + off; off += (size_t)NN * KK;
    float* s1u2  = ws + off; off += (size_t)NN * KK;
    float* s2    = ws + off; off += (size_t)NN * KK;
    float* g_s2  = ws + off; off += (size_t)NN * KK;
    float* g_s1  = ws + off; off += (size_t)NN * KK;
    float* vup   = ws + off; off += (size_t)NN * KK * 3;
    float* A0    = ws + off; off += (size_t)NN * KK;       // later g_A0
    float* A2    = ws + off; off += (size_t)NN * KK;       // later g_A2
    float* Gsj2  = ws + off; off += (size_t)NN * KK;
    float* A1    = ws + off; off += (size_t)NN * KK * 3;   // later g_A1
    float* Gvj   = ws + off; off += (size_t)NN * KK * 3;
    float* E1    = ws + off; off += 10 * KK;
    float* T1    = ws + off; off += 10 * KK;
    float* Wc    = ws + off; off += KK * KK;
    float* e1n   = ws + off; off += NN;
    float* e2n   = ws + off; off += NN;
    // int region (8B aligned: off is even)
    int* ip = (int*)(ws + off);
    size_t ioff = 0;
    int* deg_r = ip + ioff; ioff += NN;
    int* deg_s = ip + ioff; ioff += NN;
    int* cur_r = ip + ioff; ioff += NN;
    int* cur_s = ip + ioff; ioff += NN;
    int* zcnt  = ip + ioff; ioff += 16;
    int* zcur  = ip + ioff; ioff += 16;
    int* nact  = ip + ioff; ioff += 16;     // zeroed region ends here
    int* row_r = ip + ioff; ioff += NN + 2;
    int* row_s = ip + ioff; ioff += NN + 2;
    int* zrow  = ip + ioff; ioff += 16;
    int* zlist = ip + ioff; ioff += NN;
    int2* cei    = (int2*)(ip + ioff); ioff += (size_t)EE * 2;
    int2* list_r = (int2*)(ip + ioff); ioff += (size_t)EE * 2;
    int2* list_s = (int2*)(ip + ioff); ioff += (size_t)EE * 2;

    hipMemsetAsync(out, 0, (size_t)out_size * sizeof(float), stream);
    hipMemsetAsync(deg_r, 0, ((size_t)4 * NN + 48) * sizeof(int), stream);  // deg_r..nact

    const int EG = (EE + 255) / 256;
    // ---- geometry + compaction + CSR + buckets + tables ----
    k_edge_geom<<<EG, 256, 0, stream>>>(positions, shifts, edge_index, ef, defdr, Y1, rr, cei, nact);
    k_hist<<<EG, 256, 0, stream>>>(cei, nact, deg_r, deg_s);
    k_scan<<<1, 1024, 0, stream>>>(deg_r, deg_s, row_r, row_s);
    k_fill<<<EG, 256, 0, stream>>>(cei, nact, row_r, row_s, cur_r, cur_s, list_r, list_s);
    k_zcount<<<(NN + 255) / 256, 256, 0, stream>>>(node_z, zcnt);
    k_zscan<<<1, 64, 0, stream>>>(zcnt, zrow);
    k_zfill<<<(NN + 255) / 256, 256, 0, stream>>>(node_z, zcur, zrow, zlist);
    k_tables<<<10, 128, 0, stream>>>(W_embed, W_up1, W_sk_s1, E1, T1);
    k_gemm<0><<<(KK + 63) / 64, 256, 0, stream>>>(W_mix_v1, W_up2v, Wc, KK, 1.f, 0);  // Wc = W_mix_v1 @ W_up2v
    // ---- forward ----
    k_zinit2<<<(NN * KK + 255) / 256, 256, 0, stream>>>(su1, E1, s1, T1, node_z);
    k_edge1_g<<<(NN + 3) / 4, 256, 0, stream>>>(ef, Y1, R1, su1, row_r, list_r, A0, A1);
    k_gemm<0><<<(NN + 63) / 64, 256, 0, stream>>>(A0, W_mix_s1, s1, NN, INV_AVG, 1);
    k_gemm<0><<<(NN * 3 + 63) / 64, 256, 0, stream>>>(A1, Wc, vup, NN * 3, INV_AVG, 0);
    k_gemm<0><<<(NN + 63) / 64, 256, 0, stream>>>(s1, W_up2s, s1u2, NN, 1.f, 0);
    k_edge2_g<<<(NN + 3) / 4, 256, 0, stream>>>(ef, Y1, R2, s1u2, vup, row_r, list_r, A2);
    { dim3 g(10, 24); k_skip<0, 0><<<g, 256, 0, stream>>>(s1, W_sk_s2, zrow, zlist, s2); }
    k_gemm<0><<<(NN + 63) / 64, 256, 0, stream>>>(A2, W_mix_s2, s2, NN, INV_AVG, 1);
    // ---- energy head + backward seed ----
    k_mlp<<<NN, 128, 0, stream>>>(s2, W_mlp, w_out, w_r1, s1, g_s2, g_s1, e1n, e2n);
    k_energy<<<32, 256, 0, stream>>>(node_z, batch, atomic_e, e1n, e2n, out);
    // ---- backward ----
    k_gemm<1><<<(NN + 63) / 64, 256, 0, stream>>>(g_s2, W_mix_s2, A2, NN, INV_AVG, 0);   // g_A2 -> A2
    { dim3 g(10, 24); k_skip<1, 1><<<g, 256, 0, stream>>>(g_s2, W_sk_s2, zrow, zlist, g_s1); }
    k_bwdA_e<<<EG, 256, 0, stream>>>(ef, Y1, cei, nact, R2, A2, s1u2, vup, list_s, gefA, gyA);
    k_bwdA_n<<<(NN + 3) / 4, 256, 0, stream>>>(ef, Y1, R2, A2, row_s, list_s, Gsj2, Gvj);
    k_gemm<1><<<(NN + 63) / 64, 256, 0, stream>>>(Gsj2, W_up2s, g_s1, NN, 1.f, 1);
    k_gemm<1><<<(NN * 3 + 63) / 64, 256, 0, stream>>>(Gvj, Wc, A1, NN * 3, INV_AVG, 0);  // g_A1 -> A1
    k_gemm<1><<<(NN + 63) / 64, 256, 0, stream>>>(g_s1, W_mix_s1, A0, NN, INV_AVG, 0);   // g_A0 -> A0
    k_bwdB_e<<<EG, 256, 0, stream>>>(ef, Y1, cei, nact, R1, su1, A0, A1, list_r, gefB, gyB);
    k_force<<<EG, 256, 0, stream>>>(gefA, gefB, defdr, gyA, gyB, Y1, rr, cei, nact, out + GG + GG * 3);
}

// Round 9
// 471.040 us; speedup vs baseline: 4.6166x; 1.0968x over previous
//
#include <hip/hip_runtime.h>
#include <math.h>

#define NN 10000
#define EE 160000
#define KK 128
#define GG 16
#define NE 10
#define SQ3F 1.7320508075688772f
#define INV_SQ3 0.57735026918962576f
#define INV_AVG 0.0625f
#define RMAXI 0.2f

__device__ __forceinline__ void atomAddF(float* p, float v) { unsafeAtomicAdd(p, v); }

__device__ __forceinline__ float waveRed(float v) {
#pragma unroll
    for (int m = 32; m >= 1; m >>= 1) v += __shfl_xor(v, m);
    return v;
}

// ---------------- edge geometry + compaction + degree histogram (fused) ----------------
// grid*block == EE exactly (625*256); all barriers reached by all threads.
__global__ __launch_bounds__(256) void k_edge_geom(const float* __restrict__ pos, const float* __restrict__ shifts,
                            const int* __restrict__ ei,
                            float* __restrict__ ef, float* __restrict__ defdr,
                            float* __restrict__ Y1, float* __restrict__ rr,
                            int2* __restrict__ cei, int* __restrict__ nact,
                            int* __restrict__ deg_r, int* __restrict__ deg_s) {
    __shared__ int lcnt;
    __shared__ int lbase;
    if (threadIdx.x == 0) lcnt = 0;
    __syncthreads();
    int e = blockIdx.x * 256 + threadIdx.x;
    int sn = ei[e], rv = ei[EE + e];
    float vx = pos[rv*3+0] - pos[sn*3+0] + shifts[e*3+0];
    float vy = pos[rv*3+1] - pos[sn*3+1] + shifts[e*3+1];
    float vz = pos[rv*3+2] - pos[sn*3+2] + shifts[e*3+2];
    float r = sqrtf(vx*vx + vy*vy + vz*vz + 1e-12f);
    float x = r * RMAXI;
    int active = (x < 1.0f);
    int pos_l = 0;
    if (active) pos_l = atomicAdd(&lcnt, 1);
    __syncthreads();
    if (threadIdx.x == 0 && lcnt > 0) lbase = atomicAdd(nact, lcnt);
    __syncthreads();
    if (!active) return;
    int idx = lbase + pos_l;
    cei[idx] = make_int2(sn, rv);
    atomicAdd(&deg_s[sn], 1);
    atomicAdd(&deg_r[rv], 1);
    float ir = 1.0f / r;
    rr[idx] = r;
    Y1[idx*3+0] = SQ3F*vx*ir; Y1[idx*3+1] = SQ3F*vy*ir; Y1[idx*3+2] = SQ3F*vz*ir;
    float x2 = x*x, x4 = x2*x2, x5 = x4*x, x6 = x5*x, x7 = x6*x;
    float fc  = 1.0f - 21.0f*x5 + 35.0f*x6 - 15.0f*x7;
    float dfc = (-105.0f*x4 + 210.0f*x5 - 105.0f*x6) * RMAXI;
    const float C = 0.63245553203367587f; // sqrt(2/5)
    float4 efa, efb4, da, db;
    float* efp = (float*)&efa; float* dp = (float*)&da;
#pragma unroll
    for (int b = 0; b < 8; b++) {
        float kb = (float)(b + 1) * 0.62831853071795865f; // (b+1)*pi/5
        float sb, cb;
        sincosf(kb * r, &sb, &cb);
        float bess  = C * sb * ir;
        float dbess = C * ir * (kb * cb - sb * ir);
        if (b == 4) { efp = (float*)&efb4; dp = (float*)&db; }
        efp[b & 3] = bess * fc;
        dp[b & 3]  = dbess * fc + bess * dfc;
    }
    ((float4*)ef)[idx*2]      = efa; ((float4*)ef)[idx*2+1]    = efb4;
    ((float4*)defdr)[idx*2]   = da;  ((float4*)defdr)[idx*2+1] = db;
}

// ---------------- scans: CSR rows (r and s) + z-bucket rows ----------------
__global__ __launch_bounds__(1024) void k_scan(const int* __restrict__ deg_r, const int* __restrict__ deg_s,
                                               const int* __restrict__ zcnt,
                                               int* __restrict__ row_r, int* __restrict__ row_s,
                                               int* __restrict__ zrow) {
    __shared__ int part[1024];
    int t = threadIdx.x;
    if (t == 0) {
        int s = 0;
        for (int i = 0; i < NE; i++) { zrow[i] = s; s += zcnt[i]; }
        zrow[NE] = s;
    }
    for (int a = 0; a < 2; a++) {
        const int* deg = a ? deg_s : deg_r;
        int* row = a ? row_s : row_r;
        int base = t * 10;
        int loc[10];
        int s = 0;
#pragma unroll
        for (int k = 0; k < 10; k++) {
            loc[k] = s;
            if (base + k < NN) s += deg[base + k];
        }
        part[t] = s;
        __syncthreads();
        for (int off = 1; off < 1024; off <<= 1) {
            int v = (t >= off) ? part[t - off] : 0;
            __syncthreads();
            part[t] += v;
            __syncthreads();
        }
        int bex = (t > 0) ? part[t - 1] : 0;
#pragma unroll
        for (int k = 0; k < 10; k++)
            if (base + k < NN) row[base + k] = bex + loc[k];
        if (t == 1023) row[NN] = part[1023];
        __syncthreads();
    }
}

__global__ void k_fill(const int2* __restrict__ cei, const int* __restrict__ nact,
                       const int* __restrict__ row_r, const int* __restrict__ row_s,
                       int* __restrict__ cur_r, int* __restrict__ cur_s,
                       int2* __restrict__ list_r, int2* __restrict__ list_s) {
    int i = blockIdx.x * blockDim.x + threadIdx.x;
    if (i >= *nact) return;
    int2 p = cei[i];
    int sn = p.x, rv = p.y;
    int pr = atomicAdd(&cur_r[rv], 1);
    list_r[row_r[rv] + pr] = make_int2(i, sn);
    int ps = atomicAdd(&cur_s[sn], 1);
    list_s[row_s[sn] + ps] = make_int2(i, rv);
}

// ---------------- z buckets ----------------
__global__ void k_zcount(const int* __restrict__ z, int* __restrict__ zcnt) {
    __shared__ int h[NE];
    if (threadIdx.x < NE) h[threadIdx.x] = 0;
    __syncthreads();
    int n = blockIdx.x * 256 + threadIdx.x;
    if (n < NN) atomicAdd(&h[z[n]], 1);
    __syncthreads();
    if (threadIdx.x < NE && h[threadIdx.x] > 0) atomicAdd(&zcnt[threadIdx.x], h[threadIdx.x]);
}

__global__ void k_zfill(const int* __restrict__ z, int* __restrict__ zcur, const int* __restrict__ zrow,
                        int* __restrict__ zlist) {
    __shared__ int cnt[NE];
    __shared__ int base[NE];
    int t = threadIdx.x;
    if (t < NE) cnt[t] = 0;
    __syncthreads();
    int n = blockIdx.x * 256 + t;
    int pos = -1, zz = 0;
    if (n < NN) { zz = z[n]; pos = atomicAdd(&cnt[zz], 1); }
    __syncthreads();
    if (t < NE && cnt[t] > 0) base[t] = atomicAdd(&zcur[t], cnt[t]);
    __syncthreads();
    if (n < NN) zlist[zrow[zz] + base[zz] + pos] = n;
}

// ---------------- z-tables ----------------
__global__ void k_tables(const float* __restrict__ We, const float* __restrict__ Wup1,
                         const float* __restrict__ Wsk1, float* __restrict__ E1, float* __restrict__ T1) {
    int zz = blockIdx.x, d = threadIdx.x;
    float a = 0.f, bv = 0.f;
    for (int c = 0; c < KK; c++) {
        float w = We[zz*KK + c];
        a  += w * Wup1[c*KK + d];
        bv += w * Wsk1[(size_t)(zz*KK + c)*KK + d];
    }
    E1[zz*KK + d] = a;
    T1[zz*KK + d] = bv;
}

__global__ void k_zinit2(float* __restrict__ o1, const float* __restrict__ t1,
                         float* __restrict__ o2, const float* __restrict__ t2,
                         const int* __restrict__ z) {
    int i = blockIdx.x * blockDim.x + threadIdx.x;
    if (i >= NN * KK) return;
    int base = z[i >> 7] * KK + (i & 127);
    o1[i] = t1[base];
    o2[i] = t2[base];
}

// ============ register-tiled K x K GEMM (single op) ============
template <int TRANS>
__global__ __launch_bounds__(256) void k_gemm(const float* __restrict__ in, const float* __restrict__ W,
                                              float* __restrict__ out, int rows, float alpha, int accum) {
    __shared__ float WL[KK * KK];
    int t = threadIdx.x;
    for (int i = t; i < KK * KK; i += 256) {
        float v = W[i];
        int a = i >> 7, b = i & 127;
        int k = TRANS ? b : a;
        int c = TRANS ? a : b;
        WL[k * KK + ((((c >> 2) + k) & 31) << 2) + (c & 3)] = v;
    }
    __syncthreads();
    int g0 = t & 31;
    int cg = g0 << 2;
    int r0 = blockIdx.x * 64 + ((t >> 5) << 3);
    const float* Ap[8];
#pragma unroll
    for (int j = 0; j < 8; j++) {
        int r = r0 + j; if (r > rows - 1) r = rows - 1;
        Ap[j] = in + (size_t)r * KK;
    }
    float acc[8][4];
#pragma unroll
    for (int j = 0; j < 8; j++) { acc[j][0] = acc[j][1] = acc[j][2] = acc[j][3] = 0.f; }
#pragma unroll 2
    for (int k = 0; k < KK; k += 4) {
        float4 w0 = *(const float4*)&WL[(k+0)*KK + (((g0 + k + 0) & 31) << 2)];
        float4 w1 = *(const float4*)&WL[(k+1)*KK + (((g0 + k + 1) & 31) << 2)];
        float4 w2 = *(const float4*)&WL[(k+2)*KK + (((g0 + k + 2) & 31) << 2)];
        float4 w3 = *(const float4*)&WL[(k+3)*KK + (((g0 + k + 3) & 31) << 2)];
#pragma unroll
        for (int j = 0; j < 8; j++) {
            float4 a = *(const float4*)(Ap[j] + k);
            acc[j][0] += a.x*w0.x + a.y*w1.x + a.z*w2.x + a.w*w3.x;
            acc[j][1] += a.x*w0.y + a.y*w1.y + a.z*w2.y + a.w*w3.y;
            acc[j][2] += a.x*w0.z + a.y*w1.z + a.z*w2.z + a.w*w3.z;
            acc[j][3] += a.x*w0.w + a.y*w1.w + a.z*w2.w + a.w*w3.w;
        }
    }
#pragma unroll
    for (int j = 0; j < 8; j++) {
        int r = r0 + j;
        if (r < rows) {
            float4* o = (float4*)(out + (size_t)r * KK + cg);
            float4 v = make_float4(acc[j][0]*alpha, acc[j][1]*alpha, acc[j][2]*alpha, acc[j][3]*alpha);
            if (accum) { float4 old = *o; v.x += old.x; v.y += old.y; v.z += old.z; v.w += old.w; }
            *o = v;
        }
    }
}

// ============ batched 2-op GEMM (flat scalar args; two independent ops, one dispatch) ============
__global__ __launch_bounds__(256) void k_gemm2(
        const float* __restrict__ inA, const float* __restrict__ WA, float* __restrict__ outA,
        int rowsA, float alphaA, int accumA, int transA,
        const float* __restrict__ inB, const float* __restrict__ WB, float* __restrict__ outB,
        int rowsB, float alphaB, int accumB, int transB,
        int blocksA) {
    const float* in; const float* W; float* out;
    int rows, accum, trans, bid; float alpha;
    if ((int)blockIdx.x < blocksA) {
        in = inA; W = WA; out = outA; rows = rowsA; alpha = alphaA; accum = accumA; trans = transA; bid = blockIdx.x;
    } else {
        in = inB; W = WB; out = outB; rows = rowsB; alpha = alphaB; accum = accumB; trans = transB; bid = blockIdx.x - blocksA;
    }
    __shared__ float WL[KK * KK];
    int t = threadIdx.x;
    for (int i = t; i < KK * KK; i += 256) {
        float v = W[i];
        int a = i >> 7, b = i & 127;
        int k = trans ? b : a;
        int c = trans ? a : b;
        WL[k * KK + ((((c >> 2) + k) & 31) << 2) + (c & 3)] = v;
    }
    __syncthreads();
    int g0 = t & 31;
    int cg = g0 << 2;
    int r0 = bid * 64 + ((t >> 5) << 3);
    const float* Ap[8];
#pragma unroll
    for (int j = 0; j < 8; j++) {
        int r = r0 + j; if (r > rows - 1) r = rows - 1;
        Ap[j] = in + (size_t)r * KK;
    }
    float acc[8][4];
#pragma unroll
    for (int j = 0; j < 8; j++) { acc[j][0] = acc[j][1] = acc[j][2] = acc[j][3] = 0.f; }
#pragma unroll 2
    for (int k = 0; k < KK; k += 4) {
        float4 w0 = *(const float4*)&WL[(k+0)*KK + (((g0 + k + 0) & 31) << 2)];
        float4 w1 = *(const float4*)&WL[(k+1)*KK + (((g0 + k + 1) & 31) << 2)];
        float4 w2 = *(const float4*)&WL[(k+2)*KK + (((g0 + k + 2) & 31) << 2)];
        float4 w3 = *(const float4*)&WL[(k+3)*KK + (((g0 + k + 3) & 31) << 2)];
#pragma unroll
        for (int j = 0; j < 8; j++) {
            float4 a = *(const float4*)(Ap[j] + k);
            acc[j][0] += a.x*w0.x + a.y*w1.x + a.z*w2.x + a.w*w3.x;
            acc[j][1] += a.x*w0.y + a.y*w1.y + a.z*w2.y + a.w*w3.y;
            acc[j][2] += a.x*w0.z + a.y*w1.z + a.z*w2.z + a.w*w3.z;
            acc[j][3] += a.x*w0.w + a.y*w1.w + a.z*w2.w + a.w*w3.w;
        }
    }
#pragma unroll
    for (int j = 0; j < 8; j++) {
        int r = r0 + j;
        if (r < rows) {
            float4* o = (float4*)(out + (size_t)r * KK + cg);
            float4 v = make_float4(acc[j][0]*alpha, acc[j][1]*alpha, acc[j][2]*alpha, acc[j][3]*alpha);
            if (accum) { float4 old = *o; v.x += old.x; v.y += old.y; v.z += old.z; v.w += old.w; }
            *o = v;
        }
    }
}

// ============ per-z skip as bucketed tiled GEMM ============
template <int TRANS, int ACCUM>
__global__ __launch_bounds__(256) void k_skip(const float* __restrict__ in, const float* __restrict__ Wall,
                                              const int* __restrict__ zrow, const int* __restrict__ zlist,
                                              float* __restrict__ out) {
    int zz = blockIdx.x;
    int beg = zrow[zz], cnt = zrow[zz + 1] - beg;
    if (cnt == 0) return;
    __shared__ float WL[KK * KK];
    const float* W = Wall + (size_t)zz * (KK * KK);
    int t = threadIdx.x;
    for (int i = t; i < KK * KK; i += 256) {
        float v = W[i];
        int a = i >> 7, b = i & 127;
        int k = TRANS ? b : a;
        int c = TRANS ? a : b;
        WL[k * KK + ((((c >> 2) + k) & 31) << 2) + (c & 3)] = v;
    }
    __syncthreads();
    int g0 = t & 31;
    int cg = g0 << 2;
    int rg = (t >> 5) << 3;
    for (int ch = blockIdx.y; ch * 64 < cnt; ch += gridDim.y) {
        int i0 = ch * 64 + rg;
        int rowv[8];
        const float* Ap[8];
#pragma unroll
        for (int j = 0; j < 8; j++) {
            int idx = i0 + j; if (idx > cnt - 1) idx = cnt - 1;
            rowv[j] = zlist[beg + idx];
            Ap[j] = in + (size_t)rowv[j] * KK;
        }
        float acc[8][4];
#pragma unroll
        for (int j = 0; j < 8; j++) { acc[j][0] = acc[j][1] = acc[j][2] = acc[j][3] = 0.f; }
#pragma unroll 2
        for (int k = 0; k < KK; k += 4) {
            float4 w0 = *(const float4*)&WL[(k+0)*KK + (((g0 + k + 0) & 31) << 2)];
            float4 w1 = *(const float4*)&WL[(k+1)*KK + (((g0 + k + 1) & 31) << 2)];
            float4 w2 = *(const float4*)&WL[(k+2)*KK + (((g0 + k + 2) & 31) << 2)];
            float4 w3 = *(const float4*)&WL[(k+3)*KK + (((g0 + k + 3) & 31) << 2)];
#pragma unroll
            for (int j = 0; j < 8; j++) {
                float4 a = *(const float4*)(Ap[j] + k);
                acc[j][0] += a.x*w0.x + a.y*w1.x + a.z*w2.x + a.w*w3.x;
                acc[j][1] += a.x*w0.y + a.y*w1.y + a.z*w2.y + a.w*w3.y;
                acc[j][2] += a.x*w0.z + a.y*w1.z + a.z*w2.z + a.w*w3.z;
                acc[j][3] += a.x*w0.w + a.y*w1.w + a.z*w2.w + a.w*w3.w;
            }
        }
#pragma unroll
        for (int j = 0; j < 8; j++) {
            if (i0 + j < cnt) {
                float4* o = (float4*)(out + (size_t)rowv[j] * KK + cg);
                float4 v = make_float4(acc[j][0], acc[j][1], acc[j][2], acc[j][3]);
                if (ACCUM) { float4 old = *o; v.x += old.x; v.y += old.y; v.z += old.z; v.w += old.w; }
                *o = v;
            }
        }
    }
}

// ---------------- edge pass 1 (rcv-centric gather): A0[n], A1[n] ----------------
__global__ __launch_bounds__(256) void k_edge1_g(const float* __restrict__ ef, const float* __restrict__ Y1,
                                                 const float* __restrict__ R1, const float* __restrict__ su1,
                                                 const int* __restrict__ row_r, const int2* __restrict__ list_r,
                                                 float* __restrict__ A0, float* __restrict__ A1) {
    __shared__ float RL[2048];
    for (int i = threadIdx.x; i < 2048; i += 256) RL[i] = R1[i];
    __syncthreads();
    int lane = threadIdx.x & 63;
    int n = blockIdx.x * 4 + (threadIdx.x >> 6);
    if (n >= NN) return;
    int c0 = lane, c1 = lane + 64;
    float a00 = 0.f, a01 = 0.f;
    float ax0 = 0.f, ax1 = 0.f, ay0 = 0.f, ay1 = 0.f, az0 = 0.f, az1 = 0.f;
    int beg = row_r[n], end = row_r[n + 1];
    for (int i = beg; i < end; i++) {
        int2 p = list_r[i];
        int e = p.x, sn = p.y;
        float4 efa = ((const float4*)ef)[e*2], efb4 = ((const float4*)ef)[e*2+1];
        float y0 = Y1[e*3+0], y1 = Y1[e*3+1], y2 = Y1[e*3+2];
        float wa0 = 0, wa1 = 0, wb0 = 0, wb1 = 0;
        const float* eb = (const float*)&efa;
#pragma unroll
        for (int b = 0; b < 8; b++) {
            if (b == 4) eb = (const float*)&efb4;
            float v = eb[b & 3];
            wa0 += v * RL[b*256 + c0];       wb0 += v * RL[b*256 + 128 + c0];
            wa1 += v * RL[b*256 + c1];       wb1 += v * RL[b*256 + 128 + c1];
        }
        float sj0 = su1[sn*KK + c0], sj1 = su1[sn*KK + c1];
        a00 += wa0 * sj0; a01 += wa1 * sj1;
        float mb0 = wb0 * sj0, mb1 = wb1 * sj1;
        ax0 += mb0*y0; ax1 += mb1*y0;
        ay0 += mb0*y1; ay1 += mb1*y1;
        az0 += mb0*y2; az1 += mb1*y2;
    }
    A0[(size_t)n*KK + c0] = a00;  A0[(size_t)n*KK + c1] = a01;
    float* A1r = A1 + (size_t)n * 384;
    A1r[c0] = ax0;        A1r[c1] = ax1;
    A1r[128 + c0] = ay0;  A1r[128 + c1] = ay1;
    A1r[256 + c0] = az0;  A1r[256 + c1] = az1;
}

// ---------------- edge pass 2 (rcv-centric gather): A2[n] ----------------
__global__ __launch_bounds__(256) void k_edge2_g(const float* __restrict__ ef, const float* __restrict__ Y1,
                                                 const float* __restrict__ R2, const float* __restrict__ s1u2,
                                                 const float* __restrict__ vup,
                                                 const int* __restrict__ row_r, const int2* __restrict__ list_r,
                                                 float* __restrict__ A2) {
    __shared__ float RL[2048];
    for (int i = threadIdx.x; i < 2048; i += 256) RL[i] = R2[(i >> 8) * 512 + (i & 255)];
    __syncthreads();
    int lane = threadIdx.x & 63;
    int n = blockIdx.x * 4 + (threadIdx.x >> 6);
    if (n >= NN) return;
    int c0 = lane, c1 = lane + 64;
    float a0 = 0.f, a1 = 0.f;
    int beg = row_r[n], end = row_r[n + 1];
    for (int i = beg; i < end; i++) {
        int2 p = list_r[i];
        int e = p.x, sn = p.y;
        float4 efa = ((const float4*)ef)[e*2], efb4 = ((const float4*)ef)[e*2+1];
        float y0 = Y1[e*3+0], y1 = Y1[e*3+1], y2 = Y1[e*3+2];
        float w00_0 = 0, w00_1 = 0, w110_0 = 0, w110_1 = 0;
        const float* eb = (const float*)&efa;
#pragma unroll
        for (int b = 0; b < 8; b++) {
            if (b == 4) eb = (const float*)&efb4;
            float v = eb[b & 3];
            w00_0  += v * RL[b*256 + c0];      w110_0 += v * RL[b*256 + 128 + c0];
            w00_1  += v * RL[b*256 + c1];      w110_1 += v * RL[b*256 + 128 + c1];
        }
        float sj0 = s1u2[sn*KK + c0], sj1 = s1u2[sn*KK + c1];
        const float* vu = vup + (size_t)sn * 384;
        float tt0 = (vu[c0]*y0 + vu[128 + c0]*y1 + vu[256 + c0]*y2) * INV_SQ3;
        float tt1 = (vu[c1]*y0 + vu[128 + c1]*y1 + vu[256 + c1]*y2) * INV_SQ3;
        a0 += w00_0 * sj0 + w110_0 * tt0;
        a1 += w00_1 * sj1 + w110_1 * tt1;
    }
    A2[(size_t)n*KK + c0] = a0;
    A2[(size_t)n*KK + c1] = a1;
}

// ---------------- MLP energy head + e1 + backward seed ----------------
__global__ __launch_bounds__(128) void k_mlp(const float* __restrict__ s2, const float* __restrict__ W_mlp,
                                             const float* __restrict__ w_out, const float* __restrict__ w_r1,
                                             const float* __restrict__ s1,
                                             float* __restrict__ g_s2, float* __restrict__ g_s1,
                                             float* __restrict__ e1n, float* __restrict__ e2n) {
    __shared__ float WmL[KK * 17];
    __shared__ float s2L[KK];
    __shared__ float part[128];
    __shared__ float ghL[16];
    __shared__ float eL[16];
    __shared__ float pw[2];
    int n = blockIdx.x, t = threadIdx.x;
    for (int i = t; i < KK * 16; i += 128) WmL[(i >> 4) * 17 + (i & 15)] = W_mlp[i];
    s2L[t] = s2[(size_t)n * KK + t];
    float wr = w_r1[t];
    float p = s1[(size_t)n * KK + t] * wr;
    p = waveRed(p);
    if ((t & 63) == 0) pw[t >> 6] = p;
    __syncthreads();
    // parallel hidden dot: thread t -> hidden j = t&15, segment seg = t>>4 (16 c each)
    {
        int j = t & 15, seg = t >> 4;
        float pr = 0.f;
#pragma unroll
        for (int c = 0; c < 16; c++) pr += s2L[seg*16 + c] * WmL[(seg*16 + c) * 17 + j];
        part[t] = pr;
    }
    __syncthreads();
    if (t < 16) {
        float h = 0.f;
#pragma unroll
        for (int s = 0; s < 8; s++) h += part[s*16 + t];
        float sg = 1.f / (1.f + expf(-h));
        eL[t]  = h * sg * w_out[t];
        ghL[t] = w_out[t] * sg * (1.f + h * (1.f - sg));
    }
    __syncthreads();
    if (t == 0) {
        float e = 0.f;
#pragma unroll
        for (int j = 0; j < 16; j++) e += eL[j];
        e2n[n] = e;
        e1n[n] = pw[0] + pw[1];
    }
    float g = 0.f;
#pragma unroll
    for (int j = 0; j < 16; j++) g += ghL[j] * WmL[t * 17 + j];
    g_s2[(size_t)n * KK + t] = g;
    g_s1[(size_t)n * KK + t] = wr;
}

// ---------------- energy reduction ----------------
__global__ __launch_bounds__(256) void k_energy(const int* __restrict__ z, const int* __restrict__ batch,
                                                const float* __restrict__ ae,
                                                const float* __restrict__ e1n, const float* __restrict__ e2n,
                                                float* __restrict__ out) {
    __shared__ float bins[GG * 4];
    for (int i = threadIdx.x; i < GG * 4; i += 256) bins[i] = 0.f;
    __syncthreads();
    int idx = blockIdx.x * 256 + threadIdx.x;
    int stride = gridDim.x * 256;
    for (int n = idx; n < NN; n += stride) {
        int b = batch[n];
        float v0 = ae[z[n]], v1 = e1n[n], v2 = e2n[n];
        atomicAdd(&bins[b*4+0], v0 + v1 + v2);
        atomicAdd(&bins[b*4+1], v0);
        atomicAdd(&bins[b*4+2], v1);
        atomicAdd(&bins[b*4+3], v2);
    }
    __syncthreads();
    for (int i = threadIdx.x; i < GG * 4; i += 256) {
        float v = bins[i];
        if (v != 0.f) {
            int b = i >> 2, k = i & 3;
            float* dst = (k == 0) ? &out[b] : &out[GG + b*3 + (k - 1)];
            atomAddF(dst, v);
        }
    }
}

// ---------------- backward layer2, per-edge outputs (thread = edge) ----------------
__global__ __launch_bounds__(256) void k_bwdA_e(const float* __restrict__ ef8, const float* __restrict__ Y1,
                                                const int2* __restrict__ cei, const int* __restrict__ nact,
                                                const float* __restrict__ R2,
                                                const float* __restrict__ gA2, const float* __restrict__ s1u2,
                                                const float* __restrict__ vup, const int2* __restrict__ list_s,
                                                float* __restrict__ gefA, float* __restrict__ gyA) {
    int i = blockIdx.x * 256 + threadIdx.x;
    if (i >= *nact) return;
    int2 p = list_s[i];
    int e = p.x, rv = p.y;
    int sn = cei[e].x;
    float y0 = Y1[e*3+0], y1 = Y1[e*3+1], y2 = Y1[e*3+2];
    float4 efa = ((const float4*)ef8)[e*2], efb = ((const float4*)ef8)[e*2+1];
    float efv[8] = {efa.x, efa.y, efa.z, efa.w, efb.x, efb.y, efb.z, efb.w};
    float acc[8] = {0,0,0,0,0,0,0,0};
    float g0 = 0.f, g1 = 0.f, g2 = 0.f;
    const float4* gaR = (const float4*)(gA2 + (size_t)rv * KK);
    const float4* sjR = (const float4*)(s1u2 + (size_t)sn * KK);
    const float4* vxR = (const float4*)(vup + (size_t)sn * 384);
    const float4* vyR = vxR + 32;
    const float4* vzR = vxR + 64;
    for (int cc = 0; cc < 32; cc++) {
        float4 ga = gaR[cc], sj = sjR[cc], vx = vxR[cc], vy = vyR[cc], vz = vzR[cc];
#pragma unroll
        for (int k = 0; k < 4; k++) {
            float gaE = ((const float*)&ga)[k];
            float sjE = ((const float*)&sj)[k];
            float vxE = ((const float*)&vx)[k];
            float vyE = ((const float*)&vy)[k];
            float vzE = ((const float*)&vz)[k];
            float tt = (vxE*y0 + vyE*y1 + vzE*y2) * INV_SQ3;
            float gw00 = gaE * sjE;
            float gw110 = gaE * tt;
            float w110 = 0.f;
            int c = cc*4 + k;
#pragma unroll
            for (int b = 0; b < 8; b++) {
                float r2a = R2[b*512 + c];
                float r2b = R2[b*512 + 128 + c];
                acc[b] += gw00 * r2a + gw110 * r2b;
                w110 += efv[b] * r2b;
            }
            float gt = gaE * w110;
            g0 += gt * vxE; g1 += gt * vyE; g2 += gt * vzE;
        }
    }
    float4 o0 = make_float4(acc[0], acc[1], acc[2], acc[3]);
    float4 o1 = make_float4(acc[4], acc[5], acc[6], acc[7]);
    ((float4*)gefA)[e*2] = o0; ((float4*)gefA)[e*2+1] = o1;
    gyA[e*3+0] = g0 * INV_SQ3; gyA[e*3+1] = g1 * INV_SQ3; gyA[e*3+2] = g2 * INV_SQ3;
}

// ---------------- backward layer2, node sums Gsj2/Gvj ----------------
__global__ __launch_bounds__(256) void k_bwdA_n(const float* __restrict__ ef, const float* __restrict__ Y1,
                                                const float* __restrict__ R2, const float* __restrict__ gA2,
                                                const int* __restrict__ row_s, const int2* __restrict__ list_s,
                                                float* __restrict__ Gsj2, float* __restrict__ Gvj) {
    __shared__ float RL[2048];
    for (int i = threadIdx.x; i < 2048; i += 256) RL[i] = R2[(i >> 8) * 512 + (i & 255)];
    __syncthreads();
    int lane = threadIdx.x & 63;
    int sn = blockIdx.x * 4 + (threadIdx.x >> 6);
    if (sn >= NN) return;
    int c0 = lane, c1 = lane + 64;
    float gs0 = 0.f, gs1 = 0.f;
    float gv00 = 0.f, gv01 = 0.f, gv10 = 0.f, gv11 = 0.f, gv20 = 0.f, gv21 = 0.f;
    int beg = row_s[sn], end = row_s[sn + 1];
    for (int i = beg; i < end; i++) {
        int2 p = list_s[i];
        int e = p.x, rv = p.y;
        float4 efa = ((const float4*)ef)[e*2], efb4 = ((const float4*)ef)[e*2+1];
        float y0 = Y1[e*3+0], y1 = Y1[e*3+1], y2 = Y1[e*3+2];
        float w00_0 = 0, w00_1 = 0, w110_0 = 0, w110_1 = 0;
        const float* eb = (const float*)&efa;
#pragma unroll
        for (int b = 0; b < 8; b++) {
            if (b == 4) eb = (const float*)&efb4;
            float v = eb[b & 3];
            w00_0  += v * RL[b*256 + c0];      w110_0 += v * RL[b*256 + 128 + c0];
            w00_1  += v * RL[b*256 + c1];      w110_1 += v * RL[b*256 + 128 + c1];
        }
        float ga0 = gA2[(size_t)rv*KK + c0], ga1 = gA2[(size_t)rv*KK + c1];
        gs0 += ga0 * w00_0;
        gs1 += ga1 * w00_1;
        float gts0 = ga0 * w110_0 * INV_SQ3, gts1 = ga1 * w110_1 * INV_SQ3;
        gv00 += gts0*y0; gv01 += gts1*y0;
        gv10 += gts0*y1; gv11 += gts1*y1;
        gv20 += gts0*y2; gv21 += gts1*y2;
    }
    Gsj2[(size_t)sn*KK + c0] = gs0; Gsj2[(size_t)sn*KK + c1] = gs1;
    float* Gv = Gvj + (size_t)sn * 384;
    Gv[c0] = gv00;        Gv[c1] = gv01;
    Gv[128 + c0] = gv10;  Gv[128 + c1] = gv11;
    Gv[256 + c0] = gv20;  Gv[256 + c1] = gv21;
}

// ---------------- backward layer1 per-edge + FUSED force (thread = edge) ----------------
__global__ __launch_bounds__(256) void k_bwdB_f(const float* __restrict__ ef8, const float* __restrict__ Y1,
                                                const int2* __restrict__ cei, const int* __restrict__ nact,
                                                const float* __restrict__ R1,
                                                const float* __restrict__ su1, const float* __restrict__ gA0,
                                                const float* __restrict__ gA1, const int2* __restrict__ list_r,
                                                const float* __restrict__ gefA, const float* __restrict__ gyA,
                                                const float* __restrict__ defdr, const float* __restrict__ rr,
                                                float* __restrict__ forces) {
    int i = blockIdx.x * 256 + threadIdx.x;
    if (i >= *nact) return;
    int2 p = list_r[i];
    int e = p.x, sn = p.y;
    int rv = cei[e].y;
    float y0 = Y1[e*3+0], y1 = Y1[e*3+1], y2 = Y1[e*3+2];
    float4 efa = ((const float4*)ef8)[e*2], efb = ((const float4*)ef8)[e*2+1];
    float efv[8] = {efa.x, efa.y, efa.z, efa.w, efb.x, efb.y, efb.z, efb.w};
    float acc[8] = {0,0,0,0,0,0,0,0};
    float gg0 = 0.f, gg1 = 0.f, gg2 = 0.f;
    const float4* gmR = (const float4*)(gA0 + (size_t)rv * KK);
    const float4* sjR = (const float4*)(su1 + (size_t)sn * KK);
    const float4* gxR = (const float4*)(gA1 + (size_t)rv * 384);
    const float4* gyR = gxR + 32;
    const float4* gzR = gxR + 64;
    for (int cc = 0; cc < 32; cc++) {
        float4 gm = gmR[cc], sj = sjR[cc], gx = gxR[cc], gy = gyR[cc], gz = gzR[cc];
#pragma unroll
        for (int k = 0; k < 4; k++) {
            float gmE = ((const float*)&gm)[k];
            float sjE = ((const float*)&sj)[k];
            float g1E = ((const float*)&gx)[k];
            float g2E = ((const float*)&gy)[k];
            float g3E = ((const float*)&gz)[k];
            float q = g1E*y0 + g2E*y1 + g3E*y2;
            float gwa = gmE * sjE;
            float gwb = q * sjE;
            float w = 0.f;
            int c = cc*4 + k;
#pragma unroll
            for (int b = 0; b < 8; b++) {
                float r1a = R1[b*256 + c];
                float r1b = R1[b*256 + 128 + c];
                acc[b] += gwa * r1a + gwb * r1b;
                w += efv[b] * r1b;
            }
            float ws = w * sjE;
            gg0 += g1E * ws; gg1 += g2E * ws; gg2 += g3E * ws;
        }
    }
    // fused force epilogue: combine with layer-2 per-edge grads
    float gr = 0.f;
#pragma unroll
    for (int b = 0; b < 8; b++) gr += (gefA[e*8+b] + acc[b]) * defdr[e*8+b];
    float g0 = gyA[e*3+0] + gg0;
    float g1 = gyA[e*3+1] + gg1;
    float g2 = gyA[e*3+2] + gg2;
    float ir = 1.f / rr[e];
    float dot = g0*y0 + g1*y1 + g2*y2;
    float a = gr * INV_SQ3;
    float b2 = SQ3F * ir;
    float c = b2 * dot * (1.f / 3.f);
    float gv0 = a*y0 + b2*g0 - c*y0;
    float gv1 = a*y1 + b2*g1 - c*y1;
    float gv2 = a*y2 + b2*g2 - c*y2;
    atomAddF(&forces[rv*3+0], -gv0); atomAddF(&forces[rv*3+1], -gv1); atomAddF(&forces[rv*3+2], -gv2);
    atomAddF(&forces[sn*3+0],  gv0); atomAddF(&forces[sn*3+1],  gv1); atomAddF(&forces[sn*3+2],  gv2);
}

extern "C" void kernel_launch(void* const* d_in, const int* in_sizes, int n_in,
                              void* d_out, int out_size, void* d_ws, size_t ws_size,
                              hipStream_t stream) {
    const float* positions  = (const float*)d_in[0];
    const float* shifts     = (const float*)d_in[1];
    const int*   edge_index = (const int*)d_in[2];
    const int*   node_z     = (const int*)d_in[3];
    const int*   batch      = (const int*)d_in[4];
    const float* atomic_e   = (const float*)d_in[5];
    const float* W_embed    = (const float*)d_in[6];
    const float* R1         = (const float*)d_in[7];
    const float* W_up1      = (const float*)d_in[8];
    const float* W_mix_s1   = (const float*)d_in[9];
    const float* W_mix_v1   = (const float*)d_in[10];
    const float* W_sk_s1    = (const float*)d_in[11];
    const float* w_r1       = (const float*)d_in[12];
    const float* R2         = (const float*)d_in[13];
    const float* W_up2s     = (const float*)d_in[14];
    const float* W_up2v     = (const float*)d_in[15];
    const float* W_mix_s2   = (const float*)d_in[16];
    const float* W_sk_s2    = (const float*)d_in[17];
    const float* W_mlp      = (const float*)d_in[18];
    const float* w_out      = (const float*)d_in[19];

    float* out = (float*)d_out;
    float* ws = (float*)d_ws;
    size_t off = 0;
    float* ef    = ws + off; off += (size_t)EE * 8;
    float* defdr = ws + off; off += (size_t)EE * 8;
    float* Y1    = ws + off; off += (size_t)EE * 3;
    float* rr    = ws + off; off += (size_t)EE;
    float* gefA  = ws + off; off += (size_t)EE * 8;
    float* gyA   = ws + off; off += (size_t)EE * 3;
    float* su1   = ws + off; off += (size_t)NN * KK;
    float* s1    = ws + off; off += (size_t)NN * KK;
    float* s1u2  = ws + off; off += (size_t)NN * KK;
    float* s2    = ws + off; off += (size_t)NN * KK;
    float* g_s2  = ws + off; off += (size_t)NN * KK;
    float* g_s1  = ws + off; off += (size_t)NN * KK;
    float* vup   = ws + off; off += (size_t)NN * KK * 3;
    float* A0    = ws + off; off += (size_t)NN * KK;       // later g_A0
    float* A2    = ws + off; off += (size_t)NN * KK;       // later g_A2
    float* Gsj2  = ws + off; off += (size_t)NN * KK;
    float* A1    = ws + off; off += (size_t)NN * KK * 3;   // later g_A1
    float* Gvj   = ws + off; off += (size_t)NN * KK * 3;
    float* E1    = ws + off; off += 10 * KK;
    float* T1    = ws + off; off += 10 * KK;
    float* Wc    = ws + off; off += KK * KK;
    float* e1n   = ws + off; off += NN;
    float* e2n   = ws + off; off += NN;
    // int region (8B aligned: off is even)
    int* ip = (int*)(ws + off);
    size_t ioff = 0;
    int* deg_r = ip + ioff; ioff += NN;
    int* deg_s = ip + ioff; ioff += NN;
    int* cur_r = ip + ioff; ioff += NN;
    int* cur_s = ip + ioff; ioff += NN;
    int* zcnt  = ip + ioff; ioff += 16;
    int* zcur  = ip + ioff; ioff += 16;
    int* nact  = ip + ioff; ioff += 16;     // zeroed region ends here
    int* row_r = ip + ioff; ioff += NN + 2;
    int* row_s = ip + ioff; ioff += NN + 2;
    int* zrow  = ip + ioff; ioff += 16;
    int* zlist = ip + ioff; ioff += NN;
    int2* cei    = (int2*)(ip + ioff); ioff += (size_t)EE * 2;
    int2* list_r = (int2*)(ip + ioff); ioff += (size_t)EE * 2;
    int2* list_s = (int2*)(ip + ioff); ioff += (size_t)EE * 2;

    hipMemsetAsync(out, 0, (size_t)out_size * sizeof(float), stream);
    hipMemsetAsync(deg_r, 0, ((size_t)4 * NN + 48) * sizeof(int), stream);  // deg_r..nact

    const int EG = (EE + 255) / 256;
    // ---- geometry + compaction(+hist) + buckets + scans + tables ----
    k_edge_geom<<<EG, 256, 0, stream>>>(positions, shifts, edge_index, ef, defdr, Y1, rr, cei, nact, deg_r, deg_s);
    k_zcount<<<(NN + 255) / 256, 256, 0, stream>>>(node_z, zcnt);
    k_scan<<<1, 1024, 0, stream>>>(deg_r, deg_s, zcnt, row_r, row_s, zrow);
    k_fill<<<EG, 256, 0, stream>>>(cei, nact, row_r, row_s, cur_r, cur_s, list_r, list_s);
    k_zfill<<<(NN + 255) / 256, 256, 0, stream>>>(node_z, zcur, zrow, zlist);
    k_tables<<<10, 128, 0, stream>>>(W_embed, W_up1, W_sk_s1, E1, T1);
    k_gemm<0><<<(KK + 63) / 64, 256, 0, stream>>>(W_mix_v1, W_up2v, Wc, KK, 1.f, 0);  // Wc = W_mix_v1 @ W_up2v
    // ---- forward ----
    k_zinit2<<<(NN * KK + 255) / 256, 256, 0, stream>>>(su1, E1, s1, T1, node_z);
    k_edge1_g<<<(NN + 3) / 4, 256, 0, stream>>>(ef, Y1, R1, su1, row_r, list_r, A0, A1);
    {
        int ba = (NN + 63) / 64, bb = (NN * 3 + 63) / 64;
        k_gemm2<<<ba + bb, 256, 0, stream>>>(A0, W_mix_s1, s1, NN, INV_AVG, 1, 0,
                                             A1, Wc, vup, NN * 3, INV_AVG, 0, 0, ba);
    }
    k_gemm<0><<<(NN + 63) / 64, 256, 0, stream>>>(s1, W_up2s, s1u2, NN, 1.f, 0);
    { dim3 g(10, 24); k_skip<0, 0><<<g, 256, 0, stream>>>(s1, W_sk_s2, zrow, zlist, s2); }
    k_edge2_g<<<(NN + 3) / 4, 256, 0, stream>>>(ef, Y1, R2, s1u2, vup, row_r, list_r, A2);
    k_gemm<0><<<(NN + 63) / 64, 256, 0, stream>>>(A2, W_mix_s2, s2, NN, INV_AVG, 1);
    // ---- energy head + backward seed ----
    k_mlp<<<NN, 128, 0, stream>>>(s2, W_mlp, w_out, w_r1, s1, g_s2, g_s1, e1n, e2n);
    k_energy<<<32, 256, 0, stream>>>(node_z, batch, atomic_e, e1n, e2n, out);
    // ---- backward ----
    k_gemm<1><<<(NN + 63) / 64, 256, 0, stream>>>(g_s2, W_mix_s2, A2, NN, INV_AVG, 0);   // g_A2 -> A2
    { dim3 g(10, 24); k_skip<1, 1><<<g, 256, 0, stream>>>(g_s2, W_sk_s2, zrow, zlist, g_s1); }
    k_bwdA_e<<<EG, 256, 0, stream>>>(ef, Y1, cei, nact, R2, A2, s1u2, vup, list_s, gefA, gyA);
    k_bwdA_n<<<(NN + 3) / 4, 256, 0, stream>>>(ef, Y1, R2, A2, row_s, list_s, Gsj2, Gvj);
    {
        int ba = (NN * 3 + 63) / 64, bb = (NN + 63) / 64;
        k_gemm2<<<ba + bb, 256, 0, stream>>>(Gvj, Wc, A1, NN * 3, INV_AVG, 0, 1,      // g_A1 -> A1
                                             Gsj2, W_up2s, g_s1, NN, 1.f, 1, 1, ba); // accum into g_s1
    }
    k_gemm<1><<<(NN + 63) / 64, 256, 0, stream>>>(g_s1, W_mix_s1, A0, NN, INV_AVG, 0);   // g_A0 -> A0
    k_bwdB_f<<<EG, 256, 0, stream>>>(ef, Y1, cei, nact, R1, su1, A0, A1, list_r,
                                     gefA, gyA, defdr, rr, out + GG + GG * 3);
}